// Round 3
// baseline (23720.769 us; speedup 1.0000x reference)
//
#include <hip/hip_runtime.h>
#include <math.h>

#define CNU 40000
#define CNN 80000
#define CD  128
#define CEMP 640000
#define CEUI 1600000
#define CB  8192

// workspace layout (float offsets). Total 32,736,448 floats ~= 125 MB.
#define OFF_HU   0LL
#define OFF_HI   5120000LL
#define OFF_X    10240000LL   // UI input; later overlaid as z0/z1, then ssl n1/n2 buffers
#define OFF_X2   20480000LL   // UI ping buffer; holds final UI result
#define OFF_RS   30720000LL   // 8 * 40000 : [u0o,u0i,u1o,u1i,i0o,i0i,i1o,i1i] deg -> rsqrt
#define OFF_DINV 31040000LL   // 80000
#define OFF_WUI  31120000LL   // 1600000
#define OFF_ALLS 32720000LL   // 2*CB
#define OFF_MISC 32736384LL   // 64: [0..11]=att scores, 12=pos_u,13=logs_u,14=pos_i,15=logs_i

__global__ void k_zero(float* __restrict__ p, long long n){
  long long i = (long long)blockIdx.x*256 + threadIdx.x;
  if (i < n) p[i] = 0.f;
}

__global__ void k_init(const float* __restrict__ fu, const float* __restrict__ fi,
                       float* __restrict__ h_u, float* __restrict__ h_i,
                       float* __restrict__ x){
  int idx = blockIdx.x*256 + threadIdx.x;
  if (idx >= CNN*CD) return;
  float v;
  if (idx < CNU*CD){ v = fu[idx]; h_u[idx] = v; }
  else { v = fi[idx - CNU*CD]; h_i[idx - CNU*CD] = v; }
  x[idx] = v;
}

__global__ void k_deg(const int* __restrict__ src, const int* __restrict__ dst,
                      float* __restrict__ dego, float* __restrict__ degi, int E){
  int e = blockIdx.x*256 + threadIdx.x;
  if (e >= E) return;
  atomicAdd(&dego[src[e]], 1.0f);
  atomicAdd(&degi[dst[e]], 1.0f);
}

__global__ void k_rs(float* __restrict__ d, int n){
  int i = blockIdx.x*256 + threadIdx.x;
  if (i >= n) return;
  float v = d[i];
  v = (v > 1.0f) ? v : 1.0f;
  d[i] = rsqrtf(v);
}

__global__ void k_degui(const int* __restrict__ row, float* __restrict__ deg, int E){
  int e = blockIdx.x*256 + threadIdx.x;
  if (e >= E) return;
  atomicAdd(&deg[row[e]], 1.0f);
}

__global__ void k_dinv(float* __restrict__ d, int n){
  int i = blockIdx.x*256 + threadIdx.x;
  if (i >= n) return;
  float v = d[i];
  d[i] = (v > 0.f) ? rsqrtf(v) : 0.f;
}

__global__ void k_wui(const int* __restrict__ row, const int* __restrict__ col,
                      const float* __restrict__ dinv, float* __restrict__ w, int E){
  int e = blockIdx.x*256 + threadIdx.x;
  if (e >= E) return;
  w[e] = dinv[row[e]] * dinv[col[e]];
}

// z[dst] += h[src] * rso[src]   (32 lanes / edge, float4 per lane)
__global__ void k_scatter(const float* __restrict__ h, const int* __restrict__ src,
                          const int* __restrict__ dst, const float* __restrict__ rso,
                          float* __restrict__ z, int E){
  int gid = blockIdx.x*256 + threadIdx.x;
  if (gid >= E*32) return;
  int e = gid >> 5, c = (gid & 31) << 2;
  int s = src[e], d = dst[e];
  float sc = rso[s];
  float4 v = *(const float4*)(h + (long long)s*CD + c);
  float* zp = z + (long long)d*CD + c;
  atomicAdd(zp+0, v.x*sc); atomicAdd(zp+1, v.y*sc);
  atomicAdd(zp+2, v.z*sc); atomicAdd(zp+3, v.w*sc);
}

// xout[row] += w[e] * xin[col]
__global__ void k_scatter_ui(const float* __restrict__ xin, const int* __restrict__ col,
                             const int* __restrict__ row, const float* __restrict__ w,
                             float* __restrict__ xout, int E){
  int gid = blockIdx.x*256 + threadIdx.x;
  if (gid >= E*32) return;
  int e = gid >> 5, c = (gid & 31) << 2;
  int s = col[e], d = row[e];
  float sc = w[e];
  float4 v = *(const float4*)(xin + (long long)s*CD + c);
  float* zp = xout + (long long)d*CD + c;
  atomicAdd(zp+0, v.x*sc); atomicAdd(zp+1, v.y*sc);
  atomicAdd(zp+2, v.z*sc); atomicAdd(zp+3, v.w*sc);
}

// semantic attention scores: s_out[ch] += sum over rows of sum_j tanh(z_row@W1+b1)_j * W2_j
// virtual row space [0,2n): first n rows from z0 (scaled rsi0), rest from z1 (scaled rsi1)
__global__ void k_att(const float* __restrict__ z0, const float* __restrict__ z1,
                      const float* __restrict__ rsi0, const float* __restrict__ rsi1,
                      const float* __restrict__ W1, const float* __restrict__ b1,
                      const float* __restrict__ W2, float* __restrict__ s_out, int n){
  __shared__ float A[16][128];
  __shared__ float wr[2][2];
  int j = threadIdx.x;          // 0..127 = output column
  int r0 = blockIdx.x*16;
  for (int r = 0; r < 16; ++r){
    int rr = r0 + r;
    float v = 0.f;
    if (rr < n)        v = z0[(long long)rr*CD + j] * rsi0[rr];
    else if (rr < 2*n) v = z1[(long long)(rr-n)*CD + j] * rsi1[rr-n];
    A[r][j] = v;
  }
  __syncthreads();
  float acc[16];
  #pragma unroll
  for (int r = 0; r < 16; ++r) acc[r] = 0.f;
  for (int k = 0; k < 128; k += 4){
    float w0 = W1[(k+0)*128 + j];
    float w1 = W1[(k+1)*128 + j];
    float w2v= W1[(k+2)*128 + j];
    float w3 = W1[(k+3)*128 + j];
    #pragma unroll
    for (int r = 0; r < 16; ++r){
      float4 a = *(const float4*)&A[r][k];
      acc[r] += a.x*w0 + a.y*w1 + a.z*w2v + a.w*w3;
    }
  }
  float bb = b1[j];
  float w2 = W2[j];
  float pc0 = 0.f, pc1 = 0.f;
  #pragma unroll
  for (int r = 0; r < 16; ++r){
    int rr = r0 + r;
    if (rr < 2*n){
      float val = tanhf(acc[r] + bb) * w2;
      if (rr < n) pc0 += val; else pc1 += val;
    }
  }
  for (int off = 32; off > 0; off >>= 1){
    pc0 += __shfl_down(pc0, off);
    pc1 += __shfl_down(pc1, off);
  }
  if ((j & 63) == 0){ wr[0][j>>6] = pc0; wr[1][j>>6] = pc1; }
  __syncthreads();
  if (j == 0){
    atomicAdd(&s_out[0], wr[0][0] + wr[0][1]);
    atomicAdd(&s_out[1], wr[1][0] + wr[1][1]);
  }
}

// h = beta0 * z0*rsi0 + beta1 * z1*rsi1, beta = softmax(s/n)
__global__ void k_combine(const float* __restrict__ z0, const float* __restrict__ z1,
                          const float* __restrict__ rsi0, const float* __restrict__ rsi1,
                          const float* __restrict__ s, float* __restrict__ h, int n){
  int idx = blockIdx.x*256 + threadIdx.x;
  if (idx >= n*CD) return;
  int v = idx >> 7;
  float s0 = s[0]*(1.0f/n), s1 = s[1]*(1.0f/n);
  float m = fmaxf(s0, s1);
  float e0 = __expf(s0 - m), e1 = __expf(s1 - m);
  float r = 1.0f/(e0 + e1);
  h[idx] = (e0*r)*z0[idx]*rsi0[v] + (e1*r)*z1[idx]*rsi1[v];
}

// h := 0.5*h + 0.5*ui
__global__ void k_emb(const float* __restrict__ x2, float* __restrict__ h_u,
                      float* __restrict__ h_i){
  int idx = blockIdx.x*256 + threadIdx.x;
  if (idx >= CNN*CD) return;
  if (idx < CNU*CD) h_u[idx] = 0.5f*h_u[idx] + 0.5f*x2[idx];
  else { int k = idx - CNU*CD; h_i[k] = 0.5f*h_i[k] + 0.5f*x2[idx]; }
}

// normalize gathered rows + accumulate positive logits (dot/0.5). One wave per row.
__global__ void k_sslnorm(const float* __restrict__ xui, const float* __restrict__ hemb,
                          const int* __restrict__ idx, int rowoff,
                          float* __restrict__ n1, float* __restrict__ n2,
                          float* __restrict__ pos_acc){
  int r = blockIdx.x*4 + (threadIdx.x >> 6);
  int lane = threadIdx.x & 63;
  if (r >= CB) return;
  int g = idx[r];
  const float* e1 = xui + (long long)(g + rowoff)*CD;
  const float* e2 = hemb + (long long)g*CD;
  float a0 = e1[lane], a1 = e1[lane+64];
  float b0 = e2[lane], b1 = e2[lane+64];
  float s1 = a0*a0 + a1*a1, s2 = b0*b0 + b1*b1, s12 = a0*b0 + a1*b1;
  for (int off = 32; off > 0; off >>= 1){
    s1  += __shfl_down(s1, off);
    s2  += __shfl_down(s2, off);
    s12 += __shfl_down(s12, off);
  }
  s1 = __shfl(s1, 0); s2 = __shfl(s2, 0); s12 = __shfl(s12, 0);
  float i1 = 1.0f / fmaxf(sqrtf(s1), 1e-12f);
  float i2 = 1.0f / fmaxf(sqrtf(s2), 1e-12f);
  float* o1 = n1 + (long long)r*CD;
  float* o2 = n2 + (long long)r*CD;
  o1[lane] = a0*i1; o1[lane+64] = a1*i1;
  o2[lane] = b0*i2; o2[lane+64] = b1*i2;
  if (lane == 0) atomicAdd(pos_acc, s12*i1*i2*2.0f);
}

// alls[i] += sum_{j in block-y range} exp(2 * n1_i . n2_j). 64-row i-tile, 32-col j-tiles.
// LDS: 32KB (A) + 16KB (Bt) + 4KB (red) = 52KB.
__global__ void k_alls(const float* __restrict__ n1, const float* __restrict__ n2,
                       float* __restrict__ alls){
  __shared__ float A [128][64];   // [k][i]
  __shared__ float Bt[128][32];   // [k][j]
  __shared__ float red[64][16];
  int tid = threadIdx.x;
  int i0 = blockIdx.x*64;
  {
    int ii = tid >> 2, k0 = (tid & 3)*32;
    const float* sp = n1 + (long long)(i0+ii)*CD + k0;
    for (int u = 0; u < 32; u += 4){
      float4 v = *(const float4*)(sp + u);
      A[k0+u][ii] = v.x; A[k0+u+1][ii] = v.y; A[k0+u+2][ii] = v.z; A[k0+u+3][ii] = v.w;
    }
  }
  int ti = tid & 15, tj = tid >> 4;   // ti: i-quad, tj: j-pair
  float acc4[4] = {0.f, 0.f, 0.f, 0.f};
  int j0s = blockIdx.y * 1024;
  for (int j0 = j0s; j0 < j0s + 1024; j0 += 32){
    __syncthreads();
    {
      int jj = tid >> 3, k0 = (tid & 7)*16;
      const float* sp = n2 + (long long)(j0+jj)*CD + k0;
      for (int u = 0; u < 16; u += 4){
        float4 v = *(const float4*)(sp + u);
        Bt[k0+u][jj] = v.x; Bt[k0+u+1][jj] = v.y; Bt[k0+u+2][jj] = v.z; Bt[k0+u+3][jj] = v.w;
      }
    }
    __syncthreads();
    float dot[4][2];
    #pragma unroll
    for (int a = 0; a < 4; ++a){ dot[a][0] = 0.f; dot[a][1] = 0.f; }
    for (int k = 0; k < 128; ++k){
      float4 av = *(const float4*)&A[k][ti*4];
      float b0 = Bt[k][tj*2], b1v = Bt[k][tj*2+1];
      dot[0][0] += av.x*b0; dot[0][1] += av.x*b1v;
      dot[1][0] += av.y*b0; dot[1][1] += av.y*b1v;
      dot[2][0] += av.z*b0; dot[2][1] += av.z*b1v;
      dot[3][0] += av.w*b0; dot[3][1] += av.w*b1v;
    }
    #pragma unroll
    for (int a = 0; a < 4; ++a)
      acc4[a] += __expf(dot[a][0]*2.0f) + __expf(dot[a][1]*2.0f);
  }
  __syncthreads();
  #pragma unroll
  for (int a = 0; a < 4; ++a) red[ti*4 + a][tj] = acc4[a];
  __syncthreads();
  if (tid < 64){
    float s = 0.f;
    #pragma unroll
    for (int t = 0; t < 16; ++t) s += red[tid][t];
    atomicAdd(&alls[i0 + tid], s);
  }
}

__global__ void k_logsum(const float* __restrict__ alls, float* __restrict__ misc){
  int i = blockIdx.x*256 + threadIdx.x;   // 0..2*CB
  float v = logf(alls[i]);
  for (int off = 32; off > 0; off >>= 1) v += __shfl_down(v, off);
  if ((threadIdx.x & 63) == 0) atomicAdd(&misc[(i < CB) ? 13 : 15], v);
}

// out[r] = layernorm(relu(emb[idx[r]] @ W + b)). 8 rows/block, 128 threads.
__global__ void k_final(const float* __restrict__ emb, const int* __restrict__ idx,
                        const float* __restrict__ W, const float* __restrict__ bias,
                        const float* __restrict__ lg, const float* __restrict__ lb,
                        float* __restrict__ outp){
  __shared__ float A[8][128];
  __shared__ float red[8][4];
  int j = threadIdx.x;
  int r0 = blockIdx.x*8;
  for (int r = 0; r < 8; ++r){
    int g = idx[r0 + r];
    A[r][j] = emb[(long long)g*CD + j];
  }
  __syncthreads();
  float acc[8];
  #pragma unroll
  for (int r = 0; r < 8; ++r) acc[r] = 0.f;
  for (int k = 0; k < 128; k += 4){
    float w0 = W[(k+0)*128 + j];
    float w1 = W[(k+1)*128 + j];
    float w2 = W[(k+2)*128 + j];
    float w3 = W[(k+3)*128 + j];
    #pragma unroll
    for (int r = 0; r < 8; ++r){
      float4 a = *(const float4*)&A[r][k];
      acc[r] += a.x*w0 + a.y*w1 + a.z*w2 + a.w*w3;
    }
  }
  float bb = bias[j];
  #pragma unroll
  for (int r = 0; r < 8; ++r){
    float v = acc[r] + bb;
    acc[r] = (v < 0.f) ? 0.f : v;   // NaN-transparent relu: NaN stays NaN
  }
  int wid = j >> 6, lane = j & 63;
  #pragma unroll
  for (int r = 0; r < 8; ++r){
    float s = acc[r], q = acc[r]*acc[r];
    for (int off = 32; off > 0; off >>= 1){
      s += __shfl_down(s, off); q += __shfl_down(q, off);
    }
    if (lane == 0){ red[r][wid*2] = s; red[r][wid*2+1] = q; }
  }
  __syncthreads();
  float gg = lg[j], be = lb[j];
  #pragma unroll
  for (int r = 0; r < 8; ++r){
    float mu = (red[r][0] + red[r][2]) * (1.0f/128.0f);
    float ms = (red[r][1] + red[r][3]) * (1.0f/128.0f);
    float var = ms - mu*mu;
    float y = (acc[r] - mu) * rsqrtf(var + 1e-5f) * gg + be;
    outp[(long long)(r0 + r)*CD + j] = y;
  }
}

__global__ void k_loss(const float* __restrict__ misc, float* __restrict__ o){
  float lu = (misc[13] - misc[12]) * (1.0f/CB);
  float li = (misc[15] - misc[14]) * (1.0f/CB);
  o[0] = 0.4f*(lu + li);
}

extern "C" void kernel_launch(void* const* d_in, const int* in_sizes, int n_in,
                              void* d_out, int out_size, void* d_ws, size_t ws_size,
                              hipStream_t stream){
  (void)in_sizes; (void)n_in; (void)out_size; (void)ws_size;
  const float* feat_user = (const float*)d_in[0];
  const float* feat_item = (const float*)d_in[1];
  const float* u_W1 = (const float*)d_in[2];
  const float* u_b1 = (const float*)d_in[3];
  const float* u_W2 = (const float*)d_in[4];
  const float* i_W1 = (const float*)d_in[5];
  const float* i_b1 = (const float*)d_in[6];
  const float* i_W2 = (const float*)d_in[7];
  const float* user_W = (const float*)d_in[8];
  const float* user_b = (const float*)d_in[9];
  const float* item_W = (const float*)d_in[10];
  const float* item_b = (const float*)d_in[11];
  const float* ln_g = (const float*)d_in[12];
  const float* ln_b = (const float*)d_in[13];
  const int* ump0s = (const int*)d_in[14]; const int* ump0d = (const int*)d_in[15];
  const int* ump1s = (const int*)d_in[16]; const int* ump1d = (const int*)d_in[17];
  const int* imp0s = (const int*)d_in[18]; const int* imp0d = (const int*)d_in[19];
  const int* imp1s = (const int*)d_in[20]; const int* imp1d = (const int*)d_in[21];
  const int* ui_row = (const int*)d_in[22]; const int* ui_col = (const int*)d_in[23];
  const int* user_idx = (const int*)d_in[24]; const int* item_idx = (const int*)d_in[25];
  const int* neg_idx = (const int*)d_in[26];

  float* ws  = (float*)d_ws;
  float* h_u = ws + OFF_HU;
  float* h_i = ws + OFF_HI;
  float* x   = ws + OFF_X;
  float* x2  = ws + OFF_X2;
  float* z0  = ws + OFF_X;                 // overlay: x region free after UI prop
  float* z1  = ws + OFF_X + 5120000;
  float* rs  = ws + OFF_RS;
  float* dinv= ws + OFF_DINV;
  float* wui = ws + OFF_WUI;
  float* alls= ws + OFF_ALLS;
  float* misc= ws + OFF_MISC;
  float* n1u = x;                          // overlay: z region free after HAN
  float* n2u = x + (long long)CB*CD;
  float* n1i = x + 2LL*CB*CD;
  float* n2i = x + 3LL*CB*CD;
  float* out = (float*)d_out;

  // zero accumulators with plain kernels (ws re-poisoned 0xAA before every call)
  k_zero<<<(400000 + 255)/256, 256, 0, stream>>>(rs, 400000);       // rs + dinv
  k_zero<<<(16448 + 255)/256, 256, 0, stream>>>(alls, 16448);       // alls + misc

  k_init<<<40000, 256, 0, stream>>>(feat_user, feat_item, h_u, h_i, x);

  // degrees
  k_deg<<<2500, 256, 0, stream>>>(ump0s, ump0d, rs + 0,      rs + 40000,  CEMP);
  k_deg<<<2500, 256, 0, stream>>>(ump1s, ump1d, rs + 80000,  rs + 120000, CEMP);
  k_deg<<<2500, 256, 0, stream>>>(imp0s, imp0d, rs + 160000, rs + 200000, CEMP);
  k_deg<<<2500, 256, 0, stream>>>(imp1s, imp1d, rs + 240000, rs + 280000, CEMP);
  k_rs<<<1250, 256, 0, stream>>>(rs, 320000);
  k_degui<<<6250, 256, 0, stream>>>(ui_row, dinv, CEUI);
  k_dinv<<<(CNN + 255)/256, 256, 0, stream>>>(dinv, CNN);
  k_wui<<<6250, 256, 0, stream>>>(ui_row, ui_col, dinv, wui, CEUI);

  // UI propagation: x -> x2 -> x -> x2 (result in x2; x freed)
  k_zero<<<40000, 256, 0, stream>>>(x2, (long long)CNN*CD);
  k_scatter_ui<<<200000, 256, 0, stream>>>(x, ui_col, ui_row, wui, x2, CEUI);
  k_zero<<<40000, 256, 0, stream>>>(x, (long long)CNN*CD);
  k_scatter_ui<<<200000, 256, 0, stream>>>(x2, ui_col, ui_row, wui, x, CEUI);
  k_zero<<<40000, 256, 0, stream>>>(x2, (long long)CNN*CD);
  k_scatter_ui<<<200000, 256, 0, stream>>>(x, ui_col, ui_row, wui, x2, CEUI);

  // HAN user: 3 layers
  for (int L = 0; L < 3; ++L){
    k_zero<<<40000, 256, 0, stream>>>(z0, 2LL*CNU*CD);
    k_scatter<<<80000, 256, 0, stream>>>(h_u, ump0s, ump0d, rs + 0,     z0, CEMP);
    k_scatter<<<80000, 256, 0, stream>>>(h_u, ump1s, ump1d, rs + 80000, z1, CEMP);
    k_att<<<5000, 128, 0, stream>>>(z0, z1, rs + 40000, rs + 120000,
                                    u_W1, u_b1, u_W2, misc + 2*L, CNU);
    k_combine<<<20000, 256, 0, stream>>>(z0, z1, rs + 40000, rs + 120000,
                                         misc + 2*L, h_u, CNU);
  }
  // HAN item: 3 layers
  for (int L = 0; L < 3; ++L){
    k_zero<<<40000, 256, 0, stream>>>(z0, 2LL*CNU*CD);
    k_scatter<<<80000, 256, 0, stream>>>(h_i, imp0s, imp0d, rs + 160000, z0, CEMP);
    k_scatter<<<80000, 256, 0, stream>>>(h_i, imp1s, imp1d, rs + 240000, z1, CEMP);
    k_att<<<5000, 128, 0, stream>>>(z0, z1, rs + 200000, rs + 280000,
                                    i_W1, i_b1, i_W2, misc + 6 + 2*L, CNU);
    k_combine<<<20000, 256, 0, stream>>>(z0, z1, rs + 200000, rs + 280000,
                                         misc + 6 + 2*L, h_i, CNU);
  }

  // emb = 0.5*h + 0.5*ui  (in place into h_u/h_i)
  k_emb<<<40000, 256, 0, stream>>>(x2, h_u, h_i);

  // SSL
  k_sslnorm<<<CB/4, 256, 0, stream>>>(x2, h_u, user_idx, 0,   n1u, n2u, misc + 12);
  k_sslnorm<<<CB/4, 256, 0, stream>>>(x2, h_i, item_idx, CNU, n1i, n2i, misc + 14);
  k_alls<<<dim3(128, 8), 256, 0, stream>>>(n1u, n2u, alls);
  k_alls<<<dim3(128, 8), 256, 0, stream>>>(n1i, n2i, alls + CB);
  k_logsum<<<64, 256, 0, stream>>>(alls, misc);

  // final gathered matmul + relu + layernorm -> f32 outputs
  k_final<<<1024, 128, 0, stream>>>(h_u, user_idx, user_W, user_b, ln_g, ln_b, out);
  k_final<<<1024, 128, 0, stream>>>(h_i, item_idx, item_W, item_b, ln_g, ln_b, out + (long long)CB*CD);
  k_final<<<1024, 128, 0, stream>>>(h_i, neg_idx,  item_W, item_b, ln_g, ln_b, out + 2LL*CB*CD);
  k_loss<<<1, 1, 0, stream>>>(misc, out + 3LL*CB*CD);
}

// Round 4
// 4468.410 us; speedup vs baseline: 5.3085x; 5.3085x over previous
//
#include <hip/hip_runtime.h>
#include <math.h>

#define CNU 40000
#define CNN 80000
#define CD  128
#define CEMP 640000
#define CEUI 1600000
#define CB  8192

// workspace layout (float offsets). Total 32,736,448 floats ~= 131 MB (same as r3).
#define OFF_HU   0LL          // during UI phase: overlaid by UI CSR (ptr+cursor+src = 1.76M ints)
#define OFF_HI   5120000LL
#define OFF_X    10240000LL   // UI ping; later z0/z1, then ssl n1/n2 buffers
#define OFF_X2   20480000LL   // UI pong; holds final UI result
#define OFF_RS   30720000LL   // 8 * 40000 : [u0o,u0i,u1o,u1i,i0o,i0i,i1o,i1i] deg -> rsqrt
#define OFF_DINV 31040000LL   // 80000
#define OFF_MPCSR 31120000LL  // 1.6M words: ptr0(40001)+ptr1(40001)+cursor(40000)+src0(640k)+src1(640k)
#define OFF_ALLS 32720000LL   // 2*CB
#define OFF_MISC 32736384LL   // 64: [0..11]=att scores, 12=pos_u,13=logs_u,14=pos_i,15=logs_i

__global__ void k_zero(float* __restrict__ p, long long n){
  long long i = (long long)blockIdx.x*256 + threadIdx.x;
  if (i < n) p[i] = 0.f;
}

__global__ void k_izero(int* __restrict__ p, int n){
  int i = blockIdx.x*256 + threadIdx.x;
  if (i < n) p[i] = 0;
}

__global__ void k_init(const float* __restrict__ fu, const float* __restrict__ fi,
                       float* __restrict__ x){
  int idx = blockIdx.x*256 + threadIdx.x;
  if (idx >= CNN*CD) return;
  x[idx] = (idx < CNU*CD) ? fu[idx] : fi[idx - CNU*CD];
}

__global__ void k_deg(const int* __restrict__ src, const int* __restrict__ dst,
                      float* __restrict__ dego, float* __restrict__ degi, int E){
  int e = blockIdx.x*256 + threadIdx.x;
  if (e >= E) return;
  atomicAdd(&dego[src[e]], 1.0f);
  atomicAdd(&degi[dst[e]], 1.0f);
}

__global__ void k_rs(float* __restrict__ d, int n){
  int i = blockIdx.x*256 + threadIdx.x;
  if (i >= n) return;
  float v = d[i];
  v = (v > 1.0f) ? v : 1.0f;
  d[i] = rsqrtf(v);
}

__global__ void k_degui(const int* __restrict__ row, float* __restrict__ deg, int E){
  int e = blockIdx.x*256 + threadIdx.x;
  if (e >= E) return;
  atomicAdd(&deg[row[e]], 1.0f);
}

__global__ void k_dinv(float* __restrict__ d, int n){
  int i = blockIdx.x*256 + threadIdx.x;
  if (i >= n) return;
  float v = d[i];
  d[i] = (v > 0.f) ? rsqrtf(v) : 0.f;
}

// ---- CSR build: histogram -> 1-block scan -> cursor fill ----
__global__ void k_hist(const int* __restrict__ dst, int* __restrict__ hist, int E){
  int e = blockIdx.x*256 + threadIdx.x;
  if (e >= E) return;
  atomicAdd(&hist[dst[e]], 1);
}

// hist_cursor: in = histogram, out = running start offsets (cursor). ptr = exclusive prefix, ptr[n] = total.
__global__ void k_scan(int* __restrict__ hist_cursor, int* __restrict__ ptr, int n){
  __shared__ int part[1024];
  int t = threadIdx.x;
  int chunk = (n + 1023) >> 10;
  int beg = t*chunk, end = beg + chunk; if (end > n) end = n;
  int s = 0;
  for (int i = beg; i < end; ++i) s += hist_cursor[i];
  part[t] = s;
  __syncthreads();
  for (int off = 1; off < 1024; off <<= 1){
    int v = (t >= off) ? part[t-off] : 0;
    __syncthreads();
    part[t] += v;
    __syncthreads();
  }
  int run = (t == 0) ? 0 : part[t-1];
  if (t == 0) ptr[n] = part[1023];
  for (int i = beg; i < end; ++i){
    int h = hist_cursor[i];
    ptr[i] = run;
    hist_cursor[i] = run;
    run += h;
  }
}

__global__ void k_fill(const int* __restrict__ src, const int* __restrict__ dst,
                       int* __restrict__ cursor, int* __restrict__ csr_src, int E){
  int e = blockIdx.x*256 + threadIdx.x;
  if (e >= E) return;
  int p = atomicAdd(&cursor[dst[e]], 1);
  csr_src[p] = src[e];
}

// ---- gathers (no atomics): 8 rows/block, 32 lanes x float4 per row ----
// z[d] = sum_{s in N(d)} rso[s] * h[s]
__global__ void k_gather_mp(const float* __restrict__ h, const int* __restrict__ ptr,
                            const int* __restrict__ csr_src, const float* __restrict__ rso,
                            float* __restrict__ z, int n){
  int row = blockIdx.x*8 + (threadIdx.x >> 5);
  if (row >= n) return;
  int c = (threadIdx.x & 31) << 2;
  int p = ptr[row], pe = ptr[row+1];
  float4 acc = make_float4(0.f,0.f,0.f,0.f);
  for (; p + 1 < pe; p += 2){
    int s0 = csr_src[p], s1 = csr_src[p+1];
    float w0 = rso[s0], w1 = rso[s1];
    float4 v0 = *(const float4*)(h + (long long)s0*CD + c);
    float4 v1 = *(const float4*)(h + (long long)s1*CD + c);
    acc.x += v0.x*w0 + v1.x*w1; acc.y += v0.y*w0 + v1.y*w1;
    acc.z += v0.z*w0 + v1.z*w1; acc.w += v0.w*w0 + v1.w*w1;
  }
  if (p < pe){
    int s0 = csr_src[p];
    float w0 = rso[s0];
    float4 v0 = *(const float4*)(h + (long long)s0*CD + c);
    acc.x += v0.x*w0; acc.y += v0.y*w0; acc.z += v0.z*w0; acc.w += v0.w*w0;
  }
  *(float4*)(z + (long long)row*CD + c) = acc;
}

// xout[d] = dinv[d] * sum_{s in N(d)} dinv[s] * xin[s]
__global__ void k_gather_ui(const float* __restrict__ xin, const int* __restrict__ ptr,
                            const int* __restrict__ csr_src, const float* __restrict__ dinv,
                            float* __restrict__ xout, int n){
  int row = blockIdx.x*8 + (threadIdx.x >> 5);
  if (row >= n) return;
  int c = (threadIdx.x & 31) << 2;
  int p = ptr[row], pe = ptr[row+1];
  float4 acc = make_float4(0.f,0.f,0.f,0.f);
  for (; p + 1 < pe; p += 2){
    int s0 = csr_src[p], s1 = csr_src[p+1];
    float w0 = dinv[s0], w1 = dinv[s1];
    float4 v0 = *(const float4*)(xin + (long long)s0*CD + c);
    float4 v1 = *(const float4*)(xin + (long long)s1*CD + c);
    acc.x += v0.x*w0 + v1.x*w1; acc.y += v0.y*w0 + v1.y*w1;
    acc.z += v0.z*w0 + v1.z*w1; acc.w += v0.w*w0 + v1.w*w1;
  }
  if (p < pe){
    int s0 = csr_src[p];
    float w0 = dinv[s0];
    float4 v0 = *(const float4*)(xin + (long long)s0*CD + c);
    acc.x += v0.x*w0; acc.y += v0.y*w0; acc.z += v0.z*w0; acc.w += v0.w*w0;
  }
  float wd = dinv[row];
  acc.x *= wd; acc.y *= wd; acc.z *= wd; acc.w *= wd;
  *(float4*)(xout + (long long)row*CD + c) = acc;
}

// semantic attention scores (unchanged from r3)
__global__ void k_att(const float* __restrict__ z0, const float* __restrict__ z1,
                      const float* __restrict__ rsi0, const float* __restrict__ rsi1,
                      const float* __restrict__ W1, const float* __restrict__ b1,
                      const float* __restrict__ W2, float* __restrict__ s_out, int n){
  __shared__ float A[16][128];
  __shared__ float wr[2][2];
  int j = threadIdx.x;
  int r0 = blockIdx.x*16;
  for (int r = 0; r < 16; ++r){
    int rr = r0 + r;
    float v = 0.f;
    if (rr < n)        v = z0[(long long)rr*CD + j] * rsi0[rr];
    else if (rr < 2*n) v = z1[(long long)(rr-n)*CD + j] * rsi1[rr-n];
    A[r][j] = v;
  }
  __syncthreads();
  float acc[16];
  #pragma unroll
  for (int r = 0; r < 16; ++r) acc[r] = 0.f;
  for (int k = 0; k < 128; k += 4){
    float w0 = W1[(k+0)*128 + j];
    float w1 = W1[(k+1)*128 + j];
    float w2v= W1[(k+2)*128 + j];
    float w3 = W1[(k+3)*128 + j];
    #pragma unroll
    for (int r = 0; r < 16; ++r){
      float4 a = *(const float4*)&A[r][k];
      acc[r] += a.x*w0 + a.y*w1 + a.z*w2v + a.w*w3;
    }
  }
  float bb = b1[j];
  float w2 = W2[j];
  float pc0 = 0.f, pc1 = 0.f;
  #pragma unroll
  for (int r = 0; r < 16; ++r){
    int rr = r0 + r;
    if (rr < 2*n){
      float val = tanhf(acc[r] + bb) * w2;
      if (rr < n) pc0 += val; else pc1 += val;
    }
  }
  for (int off = 32; off > 0; off >>= 1){
    pc0 += __shfl_down(pc0, off);
    pc1 += __shfl_down(pc1, off);
  }
  if ((j & 63) == 0){ wr[0][j>>6] = pc0; wr[1][j>>6] = pc1; }
  __syncthreads();
  if (j == 0){
    atomicAdd(&s_out[0], wr[0][0] + wr[0][1]);
    atomicAdd(&s_out[1], wr[1][0] + wr[1][1]);
  }
}

__global__ void k_combine(const float* __restrict__ z0, const float* __restrict__ z1,
                          const float* __restrict__ rsi0, const float* __restrict__ rsi1,
                          const float* __restrict__ s, float* __restrict__ h, int n){
  int idx = blockIdx.x*256 + threadIdx.x;
  if (idx >= n*CD) return;
  int v = idx >> 7;
  float s0 = s[0]*(1.0f/n), s1 = s[1]*(1.0f/n);
  float m = fmaxf(s0, s1);
  float e0 = __expf(s0 - m), e1 = __expf(s1 - m);
  float r = 1.0f/(e0 + e1);
  h[idx] = (e0*r)*z0[idx]*rsi0[v] + (e1*r)*z1[idx]*rsi1[v];
}

__global__ void k_emb(const float* __restrict__ x2, float* __restrict__ h_u,
                      float* __restrict__ h_i){
  int idx = blockIdx.x*256 + threadIdx.x;
  if (idx >= CNN*CD) return;
  if (idx < CNU*CD) h_u[idx] = 0.5f*h_u[idx] + 0.5f*x2[idx];
  else { int k = idx - CNU*CD; h_i[k] = 0.5f*h_i[k] + 0.5f*x2[idx]; }
}

__global__ void k_sslnorm(const float* __restrict__ xui, const float* __restrict__ hemb,
                          const int* __restrict__ idx, int rowoff,
                          float* __restrict__ n1, float* __restrict__ n2,
                          float* __restrict__ pos_acc){
  int r = blockIdx.x*4 + (threadIdx.x >> 6);
  int lane = threadIdx.x & 63;
  if (r >= CB) return;
  int g = idx[r];
  const float* e1 = xui + (long long)(g + rowoff)*CD;
  const float* e2 = hemb + (long long)g*CD;
  float a0 = e1[lane], a1 = e1[lane+64];
  float b0 = e2[lane], b1 = e2[lane+64];
  float s1 = a0*a0 + a1*a1, s2 = b0*b0 + b1*b1, s12 = a0*b0 + a1*b1;
  for (int off = 32; off > 0; off >>= 1){
    s1  += __shfl_down(s1, off);
    s2  += __shfl_down(s2, off);
    s12 += __shfl_down(s12, off);
  }
  s1 = __shfl(s1, 0); s2 = __shfl(s2, 0); s12 = __shfl(s12, 0);
  float i1 = 1.0f / fmaxf(sqrtf(s1), 1e-12f);
  float i2 = 1.0f / fmaxf(sqrtf(s2), 1e-12f);
  float* o1 = n1 + (long long)r*CD;
  float* o2 = n2 + (long long)r*CD;
  o1[lane] = a0*i1; o1[lane+64] = a1*i1;
  o2[lane] = b0*i2; o2[lane+64] = b1*i2;
  if (lane == 0) atomicAdd(pos_acc, s12*i1*i2*2.0f);
}

// alls[i] += sum_j exp(2 * n1_i . n2_j). 64-row i-tile, 32-col j-tiles. LDS 52KB.
__global__ void k_alls(const float* __restrict__ n1, const float* __restrict__ n2,
                       float* __restrict__ alls){
  __shared__ float A [128][64];
  __shared__ float Bt[128][32];
  __shared__ float red[64][16];
  int tid = threadIdx.x;
  int i0 = blockIdx.x*64;
  {
    int ii = tid >> 2, k0 = (tid & 3)*32;
    const float* sp = n1 + (long long)(i0+ii)*CD + k0;
    for (int u = 0; u < 32; u += 4){
      float4 v = *(const float4*)(sp + u);
      A[k0+u][ii] = v.x; A[k0+u+1][ii] = v.y; A[k0+u+2][ii] = v.z; A[k0+u+3][ii] = v.w;
    }
  }
  int ti = tid & 15, tj = tid >> 4;
  float acc4[4] = {0.f, 0.f, 0.f, 0.f};
  int j0s = blockIdx.y * 1024;
  for (int j0 = j0s; j0 < j0s + 1024; j0 += 32){
    __syncthreads();
    {
      int jj = tid >> 3, k0 = (tid & 7)*16;
      const float* sp = n2 + (long long)(j0+jj)*CD + k0;
      for (int u = 0; u < 16; u += 4){
        float4 v = *(const float4*)(sp + u);
        Bt[k0+u][jj] = v.x; Bt[k0+u+1][jj] = v.y; Bt[k0+u+2][jj] = v.z; Bt[k0+u+3][jj] = v.w;
      }
    }
    __syncthreads();
    float dot[4][2];
    #pragma unroll
    for (int a = 0; a < 4; ++a){ dot[a][0] = 0.f; dot[a][1] = 0.f; }
    for (int k = 0; k < 128; ++k){
      float4 av = *(const float4*)&A[k][ti*4];
      float b0 = Bt[k][tj*2], b1v = Bt[k][tj*2+1];
      dot[0][0] += av.x*b0; dot[0][1] += av.x*b1v;
      dot[1][0] += av.y*b0; dot[1][1] += av.y*b1v;
      dot[2][0] += av.z*b0; dot[2][1] += av.z*b1v;
      dot[3][0] += av.w*b0; dot[3][1] += av.w*b1v;
    }
    #pragma unroll
    for (int a = 0; a < 4; ++a)
      acc4[a] += __expf(dot[a][0]*2.0f) + __expf(dot[a][1]*2.0f);
  }
  __syncthreads();
  #pragma unroll
  for (int a = 0; a < 4; ++a) red[ti*4 + a][tj] = acc4[a];
  __syncthreads();
  if (tid < 64){
    float s = 0.f;
    #pragma unroll
    for (int t = 0; t < 16; ++t) s += red[tid][t];
    atomicAdd(&alls[i0 + tid], s);
  }
}

__global__ void k_logsum(const float* __restrict__ alls, float* __restrict__ misc){
  int i = blockIdx.x*256 + threadIdx.x;
  float v = logf(alls[i]);
  for (int off = 32; off > 0; off >>= 1) v += __shfl_down(v, off);
  if ((threadIdx.x & 63) == 0) atomicAdd(&misc[(i < CB) ? 13 : 15], v);
}

__global__ void k_final(const float* __restrict__ emb, const int* __restrict__ idx,
                        const float* __restrict__ W, const float* __restrict__ bias,
                        const float* __restrict__ lg, const float* __restrict__ lb,
                        float* __restrict__ outp){
  __shared__ float A[8][128];
  __shared__ float red[8][4];
  int j = threadIdx.x;
  int r0 = blockIdx.x*8;
  for (int r = 0; r < 8; ++r){
    int g = idx[r0 + r];
    A[r][j] = emb[(long long)g*CD + j];
  }
  __syncthreads();
  float acc[8];
  #pragma unroll
  for (int r = 0; r < 8; ++r) acc[r] = 0.f;
  for (int k = 0; k < 128; k += 4){
    float w0 = W[(k+0)*128 + j];
    float w1 = W[(k+1)*128 + j];
    float w2 = W[(k+2)*128 + j];
    float w3 = W[(k+3)*128 + j];
    #pragma unroll
    for (int r = 0; r < 8; ++r){
      float4 a = *(const float4*)&A[r][k];
      acc[r] += a.x*w0 + a.y*w1 + a.z*w2 + a.w*w3;
    }
  }
  float bb = bias[j];
  #pragma unroll
  for (int r = 0; r < 8; ++r){
    float v = acc[r] + bb;
    acc[r] = (v < 0.f) ? 0.f : v;
  }
  int wid = j >> 6, lane = j & 63;
  #pragma unroll
  for (int r = 0; r < 8; ++r){
    float s = acc[r], q = acc[r]*acc[r];
    for (int off = 32; off > 0; off >>= 1){
      s += __shfl_down(s, off); q += __shfl_down(q, off);
    }
    if (lane == 0){ red[r][wid*2] = s; red[r][wid*2+1] = q; }
  }
  __syncthreads();
  float gg = lg[j], be = lb[j];
  #pragma unroll
  for (int r = 0; r < 8; ++r){
    float mu = (red[r][0] + red[r][2]) * (1.0f/128.0f);
    float ms = (red[r][1] + red[r][3]) * (1.0f/128.0f);
    float var = ms - mu*mu;
    float y = (acc[r] - mu) * rsqrtf(var + 1e-5f) * gg + be;
    outp[(long long)(r0 + r)*CD + j] = y;
  }
}

__global__ void k_loss(const float* __restrict__ misc, float* __restrict__ o){
  float lu = (misc[13] - misc[12]) * (1.0f/CB);
  float li = (misc[15] - misc[14]) * (1.0f/CB);
  o[0] = 0.4f*(lu + li);
}

extern "C" void kernel_launch(void* const* d_in, const int* in_sizes, int n_in,
                              void* d_out, int out_size, void* d_ws, size_t ws_size,
                              hipStream_t stream){
  (void)in_sizes; (void)n_in; (void)out_size; (void)ws_size;
  const float* feat_user = (const float*)d_in[0];
  const float* feat_item = (const float*)d_in[1];
  const float* u_W1 = (const float*)d_in[2];
  const float* u_b1 = (const float*)d_in[3];
  const float* u_W2 = (const float*)d_in[4];
  const float* i_W1 = (const float*)d_in[5];
  const float* i_b1 = (const float*)d_in[6];
  const float* i_W2 = (const float*)d_in[7];
  const float* user_W = (const float*)d_in[8];
  const float* user_b = (const float*)d_in[9];
  const float* item_W = (const float*)d_in[10];
  const float* item_b = (const float*)d_in[11];
  const float* ln_g = (const float*)d_in[12];
  const float* ln_b = (const float*)d_in[13];
  const int* ump0s = (const int*)d_in[14]; const int* ump0d = (const int*)d_in[15];
  const int* ump1s = (const int*)d_in[16]; const int* ump1d = (const int*)d_in[17];
  const int* imp0s = (const int*)d_in[18]; const int* imp0d = (const int*)d_in[19];
  const int* imp1s = (const int*)d_in[20]; const int* imp1d = (const int*)d_in[21];
  const int* ui_row = (const int*)d_in[22]; const int* ui_col = (const int*)d_in[23];
  const int* user_idx = (const int*)d_in[24]; const int* item_idx = (const int*)d_in[25];
  const int* neg_idx = (const int*)d_in[26];

  float* ws  = (float*)d_ws;
  float* h_u = ws + OFF_HU;
  float* h_i = ws + OFF_HI;
  float* x   = ws + OFF_X;
  float* x2  = ws + OFF_X2;
  float* z0  = ws + OFF_X;
  float* z1  = ws + OFF_X + 5120000;
  float* rs  = ws + OFF_RS;
  float* dinv= ws + OFF_DINV;
  float* alls= ws + OFF_ALLS;
  float* misc= ws + OFF_MISC;
  float* n1u = x;
  float* n2u = x + (long long)CB*CD;
  float* n1i = x + 2LL*CB*CD;
  float* n2i = x + 3LL*CB*CD;
  float* out = (float*)d_out;

  // UI CSR overlaid on h_u region (h_u not live until HAN-user combine L1)
  int* ui_ptr    = (int*)h_u;            // 80001
  int* ui_cursor = ui_ptr + 80001;       // 80000 (doubles as histogram)
  int* ui_csr    = ui_cursor + 80000;    // 1.6M
  // MP CSR region (old wui space): per HAN phase
  int* mp_base = (int*)(ws + OFF_MPCSR);
  int* mp_p0   = mp_base;                // 40001
  int* mp_p1   = mp_p0 + 40001;          // 40001
  int* mp_cur  = mp_p1 + 40001;          // 40000 (histogram+cursor, reused)
  int* mp_c0   = mp_cur + 40000;         // 640k
  int* mp_c1   = mp_c0 + CEMP;           // 640k

  // zero float accumulators
  k_zero<<<(400000 + 255)/256, 256, 0, stream>>>(rs, 400000);       // rs + dinv
  k_zero<<<(16448 + 255)/256, 256, 0, stream>>>(alls, 16448);       // alls + misc

  k_init<<<40000, 256, 0, stream>>>(feat_user, feat_item, x);

  // degrees (for rsqrt weights)
  k_deg<<<2500, 256, 0, stream>>>(ump0s, ump0d, rs + 0,      rs + 40000,  CEMP);
  k_deg<<<2500, 256, 0, stream>>>(ump1s, ump1d, rs + 80000,  rs + 120000, CEMP);
  k_deg<<<2500, 256, 0, stream>>>(imp0s, imp0d, rs + 160000, rs + 200000, CEMP);
  k_deg<<<2500, 256, 0, stream>>>(imp1s, imp1d, rs + 240000, rs + 280000, CEMP);
  k_rs<<<1250, 256, 0, stream>>>(rs, 320000);
  k_degui<<<6250, 256, 0, stream>>>(ui_row, dinv, CEUI);
  k_dinv<<<(CNN + 255)/256, 256, 0, stream>>>(dinv, CNN);

  // UI CSR build (dst = ui_row, src = ui_col)
  k_izero<<<(80000 + 255)/256, 256, 0, stream>>>(ui_cursor, 80000);
  k_hist<<<6250, 256, 0, stream>>>(ui_row, ui_cursor, CEUI);
  k_scan<<<1, 1024, 0, stream>>>(ui_cursor, ui_ptr, 80000);
  k_fill<<<6250, 256, 0, stream>>>(ui_col, ui_row, ui_cursor, ui_csr, CEUI);

  // UI propagation: x -> x2 -> x -> x2 (result in x2)
  k_gather_ui<<<10000, 256, 0, stream>>>(x,  ui_ptr, ui_csr, dinv, x2, CNN);
  k_gather_ui<<<10000, 256, 0, stream>>>(x2, ui_ptr, ui_csr, dinv, x,  CNN);
  k_gather_ui<<<10000, 256, 0, stream>>>(x,  ui_ptr, ui_csr, dinv, x2, CNN);

  // HAN user: build CSRs for u_mp0/u_mp1, then 3 layers
  k_izero<<<(40000 + 255)/256, 256, 0, stream>>>(mp_cur, 40000);
  k_hist<<<2500, 256, 0, stream>>>(ump0d, mp_cur, CEMP);
  k_scan<<<1, 1024, 0, stream>>>(mp_cur, mp_p0, 40000);
  k_fill<<<2500, 256, 0, stream>>>(ump0s, ump0d, mp_cur, mp_c0, CEMP);
  k_izero<<<(40000 + 255)/256, 256, 0, stream>>>(mp_cur, 40000);
  k_hist<<<2500, 256, 0, stream>>>(ump1d, mp_cur, CEMP);
  k_scan<<<1, 1024, 0, stream>>>(mp_cur, mp_p1, 40000);
  k_fill<<<2500, 256, 0, stream>>>(ump1s, ump1d, mp_cur, mp_c1, CEMP);
  for (int L = 0; L < 3; ++L){
    const float* hin = (L == 0) ? feat_user : h_u;
    k_gather_mp<<<5000, 256, 0, stream>>>(hin, mp_p0, mp_c0, rs + 0,     z0, CNU);
    k_gather_mp<<<5000, 256, 0, stream>>>(hin, mp_p1, mp_c1, rs + 80000, z1, CNU);
    k_att<<<5000, 128, 0, stream>>>(z0, z1, rs + 40000, rs + 120000,
                                    u_W1, u_b1, u_W2, misc + 2*L, CNU);
    k_combine<<<20000, 256, 0, stream>>>(z0, z1, rs + 40000, rs + 120000,
                                         misc + 2*L, h_u, CNU);
  }
  // HAN item
  k_izero<<<(40000 + 255)/256, 256, 0, stream>>>(mp_cur, 40000);
  k_hist<<<2500, 256, 0, stream>>>(imp0d, mp_cur, CEMP);
  k_scan<<<1, 1024, 0, stream>>>(mp_cur, mp_p0, 40000);
  k_fill<<<2500, 256, 0, stream>>>(imp0s, imp0d, mp_cur, mp_c0, CEMP);
  k_izero<<<(40000 + 255)/256, 256, 0, stream>>>(mp_cur, 40000);
  k_hist<<<2500, 256, 0, stream>>>(imp1d, mp_cur, CEMP);
  k_scan<<<1, 1024, 0, stream>>>(mp_cur, mp_p1, 40000);
  k_fill<<<2500, 256, 0, stream>>>(imp1s, imp1d, mp_cur, mp_c1, CEMP);
  for (int L = 0; L < 3; ++L){
    const float* hin = (L == 0) ? feat_item : h_i;
    k_gather_mp<<<5000, 256, 0, stream>>>(hin, mp_p0, mp_c0, rs + 160000, z0, CNU);
    k_gather_mp<<<5000, 256, 0, stream>>>(hin, mp_p1, mp_c1, rs + 240000, z1, CNU);
    k_att<<<5000, 128, 0, stream>>>(z0, z1, rs + 200000, rs + 280000,
                                    i_W1, i_b1, i_W2, misc + 6 + 2*L, CNU);
    k_combine<<<20000, 256, 0, stream>>>(z0, z1, rs + 200000, rs + 280000,
                                         misc + 6 + 2*L, h_i, CNU);
  }

  // emb = 0.5*h + 0.5*ui
  k_emb<<<40000, 256, 0, stream>>>(x2, h_u, h_i);

  // SSL
  k_sslnorm<<<CB/4, 256, 0, stream>>>(x2, h_u, user_idx, 0,   n1u, n2u, misc + 12);
  k_sslnorm<<<CB/4, 256, 0, stream>>>(x2, h_i, item_idx, CNU, n1i, n2i, misc + 14);
  k_alls<<<dim3(128, 8), 256, 0, stream>>>(n1u, n2u, alls);
  k_alls<<<dim3(128, 8), 256, 0, stream>>>(n1i, n2i, alls + CB);
  k_logsum<<<64, 256, 0, stream>>>(alls, misc);

  // final gathered matmul + relu + layernorm
  k_final<<<1024, 128, 0, stream>>>(h_u, user_idx, user_W, user_b, ln_g, ln_b, out);
  k_final<<<1024, 128, 0, stream>>>(h_i, item_idx, item_W, item_b, ln_g, ln_b, out + (long long)CB*CD);
  k_final<<<1024, 128, 0, stream>>>(h_i, neg_idx,  item_W, item_b, ln_g, ln_b, out + 2LL*CB*CD);
  k_loss<<<1, 1, 0, stream>>>(misc, out + 3LL*CB*CD);
}

// Round 5
// 4032.944 us; speedup vs baseline: 5.8818x; 1.1080x over previous
//
#include <hip/hip_runtime.h>
#include <math.h>

#define CNU 40000
#define CNN 80000
#define CD  128
#define CEMP 640000
#define CEUI 1600000
#define CB  8192

// workspace layout (float offsets). Total 32,736,448 floats ~= 131 MB.
#define OFF_HU   0LL          // during UI phase: overlaid by UI CSR (ptr+cursor+src)
#define OFF_HI   5120000LL
#define OFF_X    10240000LL   // UI ping; later z0/z1, then ssl n1/n2 buffers
#define OFF_X2   20480000LL   // UI pong; holds final UI result
#define OFF_RS   30720000LL   // 8 * 40000 deg -> rsqrt
#define OFF_DINV 31040000LL   // 80000
#define OFF_MPCSR 31120000LL  // ptr0(40001)+ptr1(40001)+cursor(40000)+src0(640k)+src1(640k)
#define OFF_ALLS 32720000LL   // 2*CB
#define OFF_MISC 32736384LL   // 64

__global__ void k_zero(float* __restrict__ p, long long n){
  long long i = (long long)blockIdx.x*256 + threadIdx.x;
  if (i < n) p[i] = 0.f;
}

__global__ void k_izero(int* __restrict__ p, int n){
  int i = blockIdx.x*256 + threadIdx.x;
  if (i < n) p[i] = 0;
}

__global__ void k_init(const float* __restrict__ fu, const float* __restrict__ fi,
                       float* __restrict__ x){
  int idx = blockIdx.x*256 + threadIdx.x;
  if (idx >= CNN*CD) return;
  x[idx] = (idx < CNU*CD) ? fu[idx] : fi[idx - CNU*CD];
}

__global__ void k_deg(const int* __restrict__ src, const int* __restrict__ dst,
                      float* __restrict__ dego, float* __restrict__ degi, int E){
  int e = blockIdx.x*256 + threadIdx.x;
  if (e >= E) return;
  atomicAdd(&dego[src[e]], 1.0f);
  atomicAdd(&degi[dst[e]], 1.0f);
}

__global__ void k_rs(float* __restrict__ d, int n){
  int i = blockIdx.x*256 + threadIdx.x;
  if (i >= n) return;
  float v = d[i];
  v = (v > 1.0f) ? v : 1.0f;
  d[i] = rsqrtf(v);
}

__global__ void k_degui(const int* __restrict__ row, float* __restrict__ deg, int E){
  int e = blockIdx.x*256 + threadIdx.x;
  if (e >= E) return;
  atomicAdd(&deg[row[e]], 1.0f);
}

__global__ void k_dinv(float* __restrict__ d, int n){
  int i = blockIdx.x*256 + threadIdx.x;
  if (i >= n) return;
  float v = d[i];
  d[i] = (v > 0.f) ? rsqrtf(v) : 0.f;
}

// ---- CSR build ----
__global__ void k_hist(const int* __restrict__ dst, int* __restrict__ hist, int E){
  int e = blockIdx.x*256 + threadIdx.x;
  if (e >= E) return;
  atomicAdd(&hist[dst[e]], 1);
}

__global__ void k_scan(int* __restrict__ hist_cursor, int* __restrict__ ptr, int n){
  __shared__ int part[1024];
  int t = threadIdx.x;
  int chunk = (n + 1023) >> 10;
  int beg = t*chunk, end = beg + chunk; if (end > n) end = n;
  int s = 0;
  for (int i = beg; i < end; ++i) s += hist_cursor[i];
  part[t] = s;
  __syncthreads();
  for (int off = 1; off < 1024; off <<= 1){
    int v = (t >= off) ? part[t-off] : 0;
    __syncthreads();
    part[t] += v;
    __syncthreads();
  }
  int run = (t == 0) ? 0 : part[t-1];
  if (t == 0) ptr[n] = part[1023];
  for (int i = beg; i < end; ++i){
    int h = hist_cursor[i];
    ptr[i] = run;
    hist_cursor[i] = run;
    run += h;
  }
}

__global__ void k_fill(const int* __restrict__ src, const int* __restrict__ dst,
                       int* __restrict__ cursor, int* __restrict__ csr_src, int E){
  int e = blockIdx.x*256 + threadIdx.x;
  if (e >= E) return;
  int p = atomicAdd(&cursor[dst[e]], 1);
  csr_src[p] = src[e];
}

// ---- gathers: 8 rows/block, 32 lanes/row, shfl-batched indices ----
__global__ void k_gather_mp(const float* __restrict__ h, const int* __restrict__ ptr,
                            const int* __restrict__ csr_src, const float* __restrict__ rso,
                            float* __restrict__ z, int n){
  int row = blockIdx.x*8 + (threadIdx.x >> 5);
  if (row >= n) return;
  int lane = threadIdx.x & 31;
  int c = lane << 2;
  int p = ptr[row], pe = ptr[row+1];
  float4 acc = make_float4(0.f,0.f,0.f,0.f);
  while (p < pe){
    int cnt = pe - p; if (cnt > 32) cnt = 32;
    int   sl = (lane < cnt) ? csr_src[p + lane] : 0;
    float wl = (lane < cnt) ? rso[sl] : 0.f;
    for (int e = 0; e < cnt; ++e){
      int s   = __shfl(sl, e, 32);
      float w = __shfl(wl, e, 32);
      float4 v = *(const float4*)(h + (long long)s*CD + c);
      acc.x += v.x*w; acc.y += v.y*w; acc.z += v.z*w; acc.w += v.w*w;
    }
    p += cnt;
  }
  *(float4*)(z + (long long)row*CD + c) = acc;
}

__global__ void k_gather_ui(const float* __restrict__ xin, const int* __restrict__ ptr,
                            const int* __restrict__ csr_src, const float* __restrict__ dinv,
                            float* __restrict__ xout, int n){
  int row = blockIdx.x*8 + (threadIdx.x >> 5);
  if (row >= n) return;
  int lane = threadIdx.x & 31;
  int c = lane << 2;
  int p = ptr[row], pe = ptr[row+1];
  float4 acc = make_float4(0.f,0.f,0.f,0.f);
  while (p < pe){
    int cnt = pe - p; if (cnt > 32) cnt = 32;
    int   sl = (lane < cnt) ? csr_src[p + lane] : 0;
    float wl = (lane < cnt) ? dinv[sl] : 0.f;
    for (int e = 0; e < cnt; ++e){
      int s   = __shfl(sl, e, 32);
      float w = __shfl(wl, e, 32);
      float4 v = *(const float4*)(xin + (long long)s*CD + c);
      acc.x += v.x*w; acc.y += v.y*w; acc.z += v.z*w; acc.w += v.w*w;
    }
    p += cnt;
  }
  float wd = dinv[row];
  acc.x *= wd; acc.y *= wd; acc.z *= wd; acc.w *= wd;
  *(float4*)(xout + (long long)row*CD + c) = acc;
}

// semantic attention scores
__global__ void k_att(const float* __restrict__ z0, const float* __restrict__ z1,
                      const float* __restrict__ rsi0, const float* __restrict__ rsi1,
                      const float* __restrict__ W1, const float* __restrict__ b1,
                      const float* __restrict__ W2, float* __restrict__ s_out, int n){
  __shared__ float A[16][128];
  __shared__ float wr[2][2];
  int j = threadIdx.x;
  int r0 = blockIdx.x*16;
  for (int r = 0; r < 16; ++r){
    int rr = r0 + r;
    float v = 0.f;
    if (rr < n)        v = z0[(long long)rr*CD + j] * rsi0[rr];
    else if (rr < 2*n) v = z1[(long long)(rr-n)*CD + j] * rsi1[rr-n];
    A[r][j] = v;
  }
  __syncthreads();
  float acc[16];
  #pragma unroll
  for (int r = 0; r < 16; ++r) acc[r] = 0.f;
  for (int k = 0; k < 128; k += 4){
    float w0 = W1[(k+0)*128 + j];
    float w1 = W1[(k+1)*128 + j];
    float w2v= W1[(k+2)*128 + j];
    float w3 = W1[(k+3)*128 + j];
    #pragma unroll
    for (int r = 0; r < 16; ++r){
      float4 a = *(const float4*)&A[r][k];
      acc[r] += a.x*w0 + a.y*w1 + a.z*w2v + a.w*w3;
    }
  }
  float bb = b1[j];
  float w2 = W2[j];
  float pc0 = 0.f, pc1 = 0.f;
  #pragma unroll
  for (int r = 0; r < 16; ++r){
    int rr = r0 + r;
    if (rr < 2*n){
      float val = tanhf(acc[r] + bb) * w2;
      if (rr < n) pc0 += val; else pc1 += val;
    }
  }
  for (int off = 32; off > 0; off >>= 1){
    pc0 += __shfl_down(pc0, off);
    pc1 += __shfl_down(pc1, off);
  }
  if ((j & 63) == 0){ wr[0][j>>6] = pc0; wr[1][j>>6] = pc1; }
  __syncthreads();
  if (j == 0){
    atomicAdd(&s_out[0], wr[0][0] + wr[0][1]);
    atomicAdd(&s_out[1], wr[1][0] + wr[1][1]);
  }
}

__global__ void k_combine(const float* __restrict__ z0, const float* __restrict__ z1,
                          const float* __restrict__ rsi0, const float* __restrict__ rsi1,
                          const float* __restrict__ s, float* __restrict__ h, int n){
  int idx = blockIdx.x*256 + threadIdx.x;
  if (idx >= n*CD) return;
  int v = idx >> 7;
  float s0 = s[0]*(1.0f/n), s1 = s[1]*(1.0f/n);
  float m = fmaxf(s0, s1);
  float e0 = __expf(s0 - m), e1 = __expf(s1 - m);
  float r = 1.0f/(e0 + e1);
  h[idx] = (e0*r)*z0[idx]*rsi0[v] + (e1*r)*z1[idx]*rsi1[v];
}

__global__ void k_emb(const float* __restrict__ x2, float* __restrict__ h_u,
                      float* __restrict__ h_i){
  int idx = blockIdx.x*256 + threadIdx.x;
  if (idx >= CNN*CD) return;
  if (idx < CNU*CD) h_u[idx] = 0.5f*h_u[idx] + 0.5f*x2[idx];
  else { int k = idx - CNU*CD; h_i[k] = 0.5f*h_i[k] + 0.5f*x2[idx]; }
}

__global__ void k_sslnorm(const float* __restrict__ xui, const float* __restrict__ hemb,
                          const int* __restrict__ idx, int rowoff,
                          float* __restrict__ n1, float* __restrict__ n2,
                          float* __restrict__ pos_acc){
  int r = blockIdx.x*4 + (threadIdx.x >> 6);
  int lane = threadIdx.x & 63;
  if (r >= CB) return;
  int g = idx[r];
  const float* e1 = xui + (long long)(g + rowoff)*CD;
  const float* e2 = hemb + (long long)g*CD;
  float a0 = e1[lane], a1 = e1[lane+64];
  float b0 = e2[lane], b1 = e2[lane+64];
  float s1 = a0*a0 + a1*a1, s2 = b0*b0 + b1*b1, s12 = a0*b0 + a1*b1;
  for (int off = 32; off > 0; off >>= 1){
    s1  += __shfl_down(s1, off);
    s2  += __shfl_down(s2, off);
    s12 += __shfl_down(s12, off);
  }
  s1 = __shfl(s1, 0); s2 = __shfl(s2, 0); s12 = __shfl(s12, 0);
  float i1 = 1.0f / fmaxf(sqrtf(s1), 1e-12f);
  float i2 = 1.0f / fmaxf(sqrtf(s2), 1e-12f);
  float* o1 = n1 + (long long)r*CD;
  float* o2 = n2 + (long long)r*CD;
  o1[lane] = a0*i1; o1[lane+64] = a1*i1;
  o2[lane] = b0*i2; o2[lane+64] = b1*i2;
  if (lane == 0) atomicAdd(pos_acc, s12*i1*i2*2.0f);
}

// alls[i] += sum_j exp(2 * n1_i . n2_j).
// 128x128 block tile, 256 threads, 8x8 per thread. A_s staged once (64KB, [k][i]);
// B_s per 32-k chunk (16KB). Final tx-reduction aliases B_s. LDS 80KB -> 2 blocks/CU.
__global__ void k_alls(const float* __restrict__ n1, const float* __restrict__ n2,
                       float* __restrict__ alls){
  __shared__ float A_s[128][128];
  __shared__ float B_s[32][128];
  int tid = threadIdx.x;
  int tx = tid & 15, ty = tid >> 4;
  int i0 = blockIdx.x*128;
  // stage A transposed: A_s[k][i]. thread: row i = tid>>1, k-half = (tid&1)*64.
  {
    int r = tid >> 1, c0 = (tid & 1)*64;
    const float* sp = n1 + (long long)(i0 + r)*CD + c0;
    #pragma unroll
    for (int u = 0; u < 64; u += 4){
      float4 v = *(const float4*)(sp + u);
      A_s[c0+u  ][r] = v.x; A_s[c0+u+1][r] = v.y;
      A_s[c0+u+2][r] = v.z; A_s[c0+u+3][r] = v.w;
    }
  }
  float esum[8];
  #pragma unroll
  for (int a = 0; a < 8; ++a) esum[a] = 0.f;
  int j0s = blockIdx.y * 1024;
  for (int jt = 0; jt < 8; ++jt){
    int j0 = j0s + jt*128;
    float dot[8][8];
    #pragma unroll
    for (int a = 0; a < 8; ++a)
      #pragma unroll
      for (int b = 0; b < 8; ++b) dot[a][b] = 0.f;
    for (int kc = 0; kc < 128; kc += 32){
      __syncthreads();
      // stage B chunk: B_s[k][j], j = tid>>1, k-half = (tid&1)*16
      {
        int jj = tid >> 1, kh = (tid & 1)*16;
        const float* sp = n2 + (long long)(j0 + jj)*CD + kc + kh;
        #pragma unroll
        for (int u = 0; u < 16; u += 4){
          float4 v = *(const float4*)(sp + u);
          B_s[kh+u  ][jj] = v.x; B_s[kh+u+1][jj] = v.y;
          B_s[kh+u+2][jj] = v.z; B_s[kh+u+3][jj] = v.w;
        }
      }
      __syncthreads();
      #pragma unroll 4
      for (int k = 0; k < 32; ++k){
        float4 a0 = *(const float4*)&A_s[kc+k][ty*8];
        float4 a1 = *(const float4*)&A_s[kc+k][ty*8+4];
        float4 b0 = *(const float4*)&B_s[k][tx*8];
        float4 b1 = *(const float4*)&B_s[k][tx*8+4];
        float av[8] = {a0.x,a0.y,a0.z,a0.w,a1.x,a1.y,a1.z,a1.w};
        float bv[8] = {b0.x,b0.y,b0.z,b0.w,b1.x,b1.y,b1.z,b1.w};
        #pragma unroll
        for (int a = 0; a < 8; ++a)
          #pragma unroll
          for (int b = 0; b < 8; ++b) dot[a][b] += av[a]*bv[b];
      }
    }
    #pragma unroll
    for (int a = 0; a < 8; ++a){
      float s = 0.f;
      #pragma unroll
      for (int b = 0; b < 8; ++b) s += __expf(dot[a][b]*2.0f);
      esum[a] += s;
    }
  }
  // reduce over tx (16 threads per row). red aliased onto B_s (needs 128*17 <= 4096 floats).
  __syncthreads();
  float* red = &B_s[0][0];
  #pragma unroll
  for (int a = 0; a < 8; ++a) red[(ty*8 + a)*17 + tx] = esum[a];
  __syncthreads();
  if (tid < 128){
    float s = 0.f;
    #pragma unroll
    for (int t = 0; t < 16; ++t) s += red[tid*17 + t];
    atomicAdd(&alls[i0 + tid], s);
  }
}

__global__ void k_logsum(const float* __restrict__ alls, float* __restrict__ misc){
  int i = blockIdx.x*256 + threadIdx.x;
  float v = logf(alls[i]);
  for (int off = 32; off > 0; off >>= 1) v += __shfl_down(v, off);
  if ((threadIdx.x & 63) == 0) atomicAdd(&misc[(i < CB) ? 13 : 15], v);
}

__global__ void k_final(const float* __restrict__ emb, const int* __restrict__ idx,
                        const float* __restrict__ W, const float* __restrict__ bias,
                        const float* __restrict__ lg, const float* __restrict__ lb,
                        float* __restrict__ outp){
  __shared__ float A[8][128];
  __shared__ float red[8][4];
  int j = threadIdx.x;
  int r0 = blockIdx.x*8;
  for (int r = 0; r < 8; ++r){
    int g = idx[r0 + r];
    A[r][j] = emb[(long long)g*CD + j];
  }
  __syncthreads();
  float acc[8];
  #pragma unroll
  for (int r = 0; r < 8; ++r) acc[r] = 0.f;
  for (int k = 0; k < 128; k += 4){
    float w0 = W[(k+0)*128 + j];
    float w1 = W[(k+1)*128 + j];
    float w2 = W[(k+2)*128 + j];
    float w3 = W[(k+3)*128 + j];
    #pragma unroll
    for (int r = 0; r < 8; ++r){
      float4 a = *(const float4*)&A[r][k];
      acc[r] += a.x*w0 + a.y*w1 + a.z*w2 + a.w*w3;
    }
  }
  float bb = bias[j];
  #pragma unroll
  for (int r = 0; r < 8; ++r){
    float v = acc[r] + bb;
    acc[r] = (v < 0.f) ? 0.f : v;
  }
  int wid = j >> 6, lane = j & 63;
  #pragma unroll
  for (int r = 0; r < 8; ++r){
    float s = acc[r], q = acc[r]*acc[r];
    for (int off = 32; off > 0; off >>= 1){
      s += __shfl_down(s, off); q += __shfl_down(q, off);
    }
    if (lane == 0){ red[r][wid*2] = s; red[r][wid*2+1] = q; }
  }
  __syncthreads();
  float gg = lg[j], be = lb[j];
  #pragma unroll
  for (int r = 0; r < 8; ++r){
    float mu = (red[r][0] + red[r][2]) * (1.0f/128.0f);
    float ms = (red[r][1] + red[r][3]) * (1.0f/128.0f);
    float var = ms - mu*mu;
    float y = (acc[r] - mu) * rsqrtf(var + 1e-5f) * gg + be;
    outp[(long long)(r0 + r)*CD + j] = y;
  }
}

__global__ void k_loss(const float* __restrict__ misc, float* __restrict__ o){
  float lu = (misc[13] - misc[12]) * (1.0f/CB);
  float li = (misc[15] - misc[14]) * (1.0f/CB);
  o[0] = 0.4f*(lu + li);
}

extern "C" void kernel_launch(void* const* d_in, const int* in_sizes, int n_in,
                              void* d_out, int out_size, void* d_ws, size_t ws_size,
                              hipStream_t stream){
  (void)in_sizes; (void)n_in; (void)out_size; (void)ws_size;
  const float* feat_user = (const float*)d_in[0];
  const float* feat_item = (const float*)d_in[1];
  const float* u_W1 = (const float*)d_in[2];
  const float* u_b1 = (const float*)d_in[3];
  const float* u_W2 = (const float*)d_in[4];
  const float* i_W1 = (const float*)d_in[5];
  const float* i_b1 = (const float*)d_in[6];
  const float* i_W2 = (const float*)d_in[7];
  const float* user_W = (const float*)d_in[8];
  const float* user_b = (const float*)d_in[9];
  const float* item_W = (const float*)d_in[10];
  const float* item_b = (const float*)d_in[11];
  const float* ln_g = (const float*)d_in[12];
  const float* ln_b = (const float*)d_in[13];
  const int* ump0s = (const int*)d_in[14]; const int* ump0d = (const int*)d_in[15];
  const int* ump1s = (const int*)d_in[16]; const int* ump1d = (const int*)d_in[17];
  const int* imp0s = (const int*)d_in[18]; const int* imp0d = (const int*)d_in[19];
  const int* imp1s = (const int*)d_in[20]; const int* imp1d = (const int*)d_in[21];
  const int* ui_row = (const int*)d_in[22]; const int* ui_col = (const int*)d_in[23];
  const int* user_idx = (const int*)d_in[24]; const int* item_idx = (const int*)d_in[25];
  const int* neg_idx = (const int*)d_in[26];

  float* ws  = (float*)d_ws;
  float* h_u = ws + OFF_HU;
  float* h_i = ws + OFF_HI;
  float* x   = ws + OFF_X;
  float* x2  = ws + OFF_X2;
  float* z0  = ws + OFF_X;
  float* z1  = ws + OFF_X + 5120000;
  float* rs  = ws + OFF_RS;
  float* dinv= ws + OFF_DINV;
  float* alls= ws + OFF_ALLS;
  float* misc= ws + OFF_MISC;
  float* n1u = x;
  float* n2u = x + (long long)CB*CD;
  float* n1i = x + 2LL*CB*CD;
  float* n2i = x + 3LL*CB*CD;
  float* out = (float*)d_out;

  int* ui_ptr    = (int*)h_u;            // 80001
  int* ui_cursor = ui_ptr + 80001;       // 80000
  int* ui_csr    = ui_cursor + 80000;    // 1.6M
  int* mp_base = (int*)(ws + OFF_MPCSR);
  int* mp_p0   = mp_base;                // 40001
  int* mp_p1   = mp_p0 + 40001;          // 40001
  int* mp_cur  = mp_p1 + 40001;          // 40000
  int* mp_c0   = mp_cur + 40000;         // 640k
  int* mp_c1   = mp_c0 + CEMP;           // 640k

  k_zero<<<(400000 + 255)/256, 256, 0, stream>>>(rs, 400000);
  k_zero<<<(16448 + 255)/256, 256, 0, stream>>>(alls, 16448);

  k_init<<<40000, 256, 0, stream>>>(feat_user, feat_item, x);

  k_deg<<<2500, 256, 0, stream>>>(ump0s, ump0d, rs + 0,      rs + 40000,  CEMP);
  k_deg<<<2500, 256, 0, stream>>>(ump1s, ump1d, rs + 80000,  rs + 120000, CEMP);
  k_deg<<<2500, 256, 0, stream>>>(imp0s, imp0d, rs + 160000, rs + 200000, CEMP);
  k_deg<<<2500, 256, 0, stream>>>(imp1s, imp1d, rs + 240000, rs + 280000, CEMP);
  k_rs<<<1250, 256, 0, stream>>>(rs, 320000);
  k_degui<<<6250, 256, 0, stream>>>(ui_row, dinv, CEUI);
  k_dinv<<<(CNN + 255)/256, 256, 0, stream>>>(dinv, CNN);

  // UI CSR build
  k_izero<<<(80000 + 255)/256, 256, 0, stream>>>(ui_cursor, 80000);
  k_hist<<<6250, 256, 0, stream>>>(ui_row, ui_cursor, CEUI);
  k_scan<<<1, 1024, 0, stream>>>(ui_cursor, ui_ptr, 80000);
  k_fill<<<6250, 256, 0, stream>>>(ui_col, ui_row, ui_cursor, ui_csr, CEUI);

  // UI propagation
  k_gather_ui<<<10000, 256, 0, stream>>>(x,  ui_ptr, ui_csr, dinv, x2, CNN);
  k_gather_ui<<<10000, 256, 0, stream>>>(x2, ui_ptr, ui_csr, dinv, x,  CNN);
  k_gather_ui<<<10000, 256, 0, stream>>>(x,  ui_ptr, ui_csr, dinv, x2, CNN);

  // HAN user
  k_izero<<<(40000 + 255)/256, 256, 0, stream>>>(mp_cur, 40000);
  k_hist<<<2500, 256, 0, stream>>>(ump0d, mp_cur, CEMP);
  k_scan<<<1, 1024, 0, stream>>>(mp_cur, mp_p0, 40000);
  k_fill<<<2500, 256, 0, stream>>>(ump0s, ump0d, mp_cur, mp_c0, CEMP);
  k_izero<<<(40000 + 255)/256, 256, 0, stream>>>(mp_cur, 40000);
  k_hist<<<2500, 256, 0, stream>>>(ump1d, mp_cur, CEMP);
  k_scan<<<1, 1024, 0, stream>>>(mp_cur, mp_p1, 40000);
  k_fill<<<2500, 256, 0, stream>>>(ump1s, ump1d, mp_cur, mp_c1, CEMP);
  for (int L = 0; L < 3; ++L){
    const float* hin = (L == 0) ? feat_user : h_u;
    k_gather_mp<<<5000, 256, 0, stream>>>(hin, mp_p0, mp_c0, rs + 0,     z0, CNU);
    k_gather_mp<<<5000, 256, 0, stream>>>(hin, mp_p1, mp_c1, rs + 80000, z1, CNU);
    k_att<<<5000, 128, 0, stream>>>(z0, z1, rs + 40000, rs + 120000,
                                    u_W1, u_b1, u_W2, misc + 2*L, CNU);
    k_combine<<<20000, 256, 0, stream>>>(z0, z1, rs + 40000, rs + 120000,
                                         misc + 2*L, h_u, CNU);
  }
  // HAN item
  k_izero<<<(40000 + 255)/256, 256, 0, stream>>>(mp_cur, 40000);
  k_hist<<<2500, 256, 0, stream>>>(imp0d, mp_cur, CEMP);
  k_scan<<<1, 1024, 0, stream>>>(mp_cur, mp_p0, 40000);
  k_fill<<<2500, 256, 0, stream>>>(imp0s, imp0d, mp_cur, mp_c0, CEMP);
  k_izero<<<(40000 + 255)/256, 256, 0, stream>>>(mp_cur, 40000);
  k_hist<<<2500, 256, 0, stream>>>(imp1d, mp_cur, CEMP);
  k_scan<<<1, 1024, 0, stream>>>(mp_cur, mp_p1, 40000);
  k_fill<<<2500, 256, 0, stream>>>(imp1s, imp1d, mp_cur, mp_c1, CEMP);
  for (int L = 0; L < 3; ++L){
    const float* hin = (L == 0) ? feat_item : h_i;
    k_gather_mp<<<5000, 256, 0, stream>>>(hin, mp_p0, mp_c0, rs + 160000, z0, CNU);
    k_gather_mp<<<5000, 256, 0, stream>>>(hin, mp_p1, mp_c1, rs + 240000, z1, CNU);
    k_att<<<5000, 128, 0, stream>>>(z0, z1, rs + 200000, rs + 280000,
                                    i_W1, i_b1, i_W2, misc + 6 + 2*L, CNU);
    k_combine<<<20000, 256, 0, stream>>>(z0, z1, rs + 200000, rs + 280000,
                                         misc + 6 + 2*L, h_i, CNU);
  }

  k_emb<<<40000, 256, 0, stream>>>(x2, h_u, h_i);

  // SSL
  k_sslnorm<<<CB/4, 256, 0, stream>>>(x2, h_u, user_idx, 0,   n1u, n2u, misc + 12);
  k_sslnorm<<<CB/4, 256, 0, stream>>>(x2, h_i, item_idx, CNU, n1i, n2i, misc + 14);
  k_alls<<<dim3(64, 8), 256, 0, stream>>>(n1u, n2u, alls);
  k_alls<<<dim3(64, 8), 256, 0, stream>>>(n1i, n2i, alls + CB);
  k_logsum<<<64, 256, 0, stream>>>(alls, misc);

  k_final<<<1024, 128, 0, stream>>>(h_u, user_idx, user_W, user_b, ln_g, ln_b, out);
  k_final<<<1024, 128, 0, stream>>>(h_i, item_idx, item_W, item_b, ln_g, ln_b, out + (long long)CB*CD);
  k_final<<<1024, 128, 0, stream>>>(h_i, neg_idx,  item_W, item_b, ln_g, ln_b, out + 2LL*CB*CD);
  k_loss<<<1, 1, 0, stream>>>(misc, out + 3LL*CB*CD);
}

// Round 6
// 3711.329 us; speedup vs baseline: 6.3914x; 1.0867x over previous
//
#include <hip/hip_runtime.h>
#include <math.h>

typedef unsigned short u16;
typedef unsigned int u32;

#define CNU 40000
#define CNN 80000
#define CD  128
#define CEMP 640000
#define CEUI 1600000
#define CB  8192

// workspace layout (u16 units for bf16 buffers). Total ~110MB of the >=131MB ws.
// FB 0 (10.24M) | HU 10.24M (5.12M) | HI 15.36M (5.12M) | X 20.48M (10.24M)
// X2 30.72M (10.24M) | Z0 40.96M (5.12M) | Z1 46.08M (5.12M) | f32/int region at 51.2M
// overlays: UI-CSR on HU/HI region (dead until first combine); n1..n2 (f32) on X (dead after hop3)

__device__ __forceinline__ float bf2f(u16 b){
  union { u32 u; float f; } v; v.u = ((u32)b) << 16; return v.f;
}
__device__ __forceinline__ u16 f2bf(float f){
  union { float f; u32 u; } v; v.f = f;
  u32 u = v.u + 0x7FFFu + ((v.u >> 16) & 1u);
  return (u16)(u >> 16);
}
__device__ __forceinline__ float lo16f(u32 q){ union { u32 u; float f; } v; v.u = q << 16; return v.f; }
__device__ __forceinline__ float hi16f(u32 q){ union { u32 u; float f; } v; v.u = q & 0xFFFF0000u; return v.f; }

__global__ void k_zero(float* __restrict__ p, long long n){
  long long i = (long long)blockIdx.x*256 + threadIdx.x;
  if (i < n) p[i] = 0.f;
}

__global__ void k_izero(int* __restrict__ p, int n){
  int i = blockIdx.x*256 + threadIdx.x;
  if (i < n) p[i] = 0;
}

// f32 feats -> bf16 concat table
__global__ void k_initb(const float* __restrict__ fu, const float* __restrict__ fi,
                        u16* __restrict__ fb){
  int idx = blockIdx.x*256 + threadIdx.x;
  if (idx >= CNN*CD) return;
  float v = (idx < CNU*CD) ? fu[idx] : fi[idx - CNU*CD];
  fb[idx] = f2bf(v);
}

__global__ void k_deg(const int* __restrict__ src, const int* __restrict__ dst,
                      float* __restrict__ dego, float* __restrict__ degi, int E){
  int e = blockIdx.x*256 + threadIdx.x;
  if (e >= E) return;
  atomicAdd(&dego[src[e]], 1.0f);
  atomicAdd(&degi[dst[e]], 1.0f);
}

__global__ void k_rs(float* __restrict__ d, int n){
  int i = blockIdx.x*256 + threadIdx.x;
  if (i >= n) return;
  float v = d[i];
  v = (v > 1.0f) ? v : 1.0f;
  d[i] = rsqrtf(v);
}

__global__ void k_degui(const int* __restrict__ row, float* __restrict__ deg, int E){
  int e = blockIdx.x*256 + threadIdx.x;
  if (e >= E) return;
  atomicAdd(&deg[row[e]], 1.0f);
}

__global__ void k_dinv(float* __restrict__ d, int n){
  int i = blockIdx.x*256 + threadIdx.x;
  if (i >= n) return;
  float v = d[i];
  d[i] = (v > 0.f) ? rsqrtf(v) : 0.f;
}

// ---- CSR build ----
__global__ void k_hist(const int* __restrict__ dst, int* __restrict__ hist, int E){
  int e = blockIdx.x*256 + threadIdx.x;
  if (e >= E) return;
  atomicAdd(&hist[dst[e]], 1);
}

__global__ void k_scan(int* __restrict__ hist_cursor, int* __restrict__ ptr, int n){
  __shared__ int part[1024];
  int t = threadIdx.x;
  int chunk = (n + 1023) >> 10;
  int beg = t*chunk, end = beg + chunk; if (end > n) end = n;
  int s = 0;
  for (int i = beg; i < end; ++i) s += hist_cursor[i];
  part[t] = s;
  __syncthreads();
  for (int off = 1; off < 1024; off <<= 1){
    int v = (t >= off) ? part[t-off] : 0;
    __syncthreads();
    part[t] += v;
    __syncthreads();
  }
  int run = (t == 0) ? 0 : part[t-1];
  if (t == 0) ptr[n] = part[1023];
  for (int i = beg; i < end; ++i){
    int h = hist_cursor[i];
    ptr[i] = run;
    hist_cursor[i] = run;
    run += h;
  }
}

__global__ void k_fill(const int* __restrict__ src, const int* __restrict__ dst,
                       int* __restrict__ cursor, int* __restrict__ csr_src, int E){
  int e = blockIdx.x*256 + threadIdx.x;
  if (e >= E) return;
  int p = atomicAdd(&cursor[dst[e]], 1);
  csr_src[p] = src[e];
}

// ---- bf16 gathers: 8 rows/block, 32 lanes/row, lane covers 4 cols (uint2 = 4 bf16) ----
__global__ void k_gather_mp(const u16* __restrict__ h, const int* __restrict__ ptr,
                            const int* __restrict__ csr_src, const float* __restrict__ rso,
                            u16* __restrict__ z, int n){
  int row = blockIdx.x*8 + (threadIdx.x >> 5);
  if (row >= n) return;
  int lane = threadIdx.x & 31;
  int c = lane << 2;
  int p = ptr[row], pe = ptr[row+1];
  float4 acc = make_float4(0.f,0.f,0.f,0.f);
  while (p < pe){
    int cnt = pe - p; if (cnt > 32) cnt = 32;
    int   sl = (lane < cnt) ? csr_src[p + lane] : 0;
    float wl = (lane < cnt) ? rso[sl] : 0.f;
    for (int e = 0; e < cnt; ++e){
      int s   = __shfl(sl, e, 32);
      float w = __shfl(wl, e, 32);
      uint2 q = *(const uint2*)(h + (long long)s*CD + c);
      acc.x += lo16f(q.x)*w; acc.y += hi16f(q.x)*w;
      acc.z += lo16f(q.y)*w; acc.w += hi16f(q.y)*w;
    }
    p += cnt;
  }
  uint2 o;
  o.x = (u32)f2bf(acc.x) | ((u32)f2bf(acc.y) << 16);
  o.y = (u32)f2bf(acc.z) | ((u32)f2bf(acc.w) << 16);
  *(uint2*)(z + (long long)row*CD + c) = o;
}

__global__ void k_gather_ui(const u16* __restrict__ xin, const int* __restrict__ ptr,
                            const int* __restrict__ csr_src, const float* __restrict__ dinv,
                            u16* __restrict__ xout, int n){
  int row = blockIdx.x*8 + (threadIdx.x >> 5);
  if (row >= n) return;
  int lane = threadIdx.x & 31;
  int c = lane << 2;
  int p = ptr[row], pe = ptr[row+1];
  float4 acc = make_float4(0.f,0.f,0.f,0.f);
  while (p < pe){
    int cnt = pe - p; if (cnt > 32) cnt = 32;
    int   sl = (lane < cnt) ? csr_src[p + lane] : 0;
    float wl = (lane < cnt) ? dinv[sl] : 0.f;
    for (int e = 0; e < cnt; ++e){
      int s   = __shfl(sl, e, 32);
      float w = __shfl(wl, e, 32);
      uint2 q = *(const uint2*)(xin + (long long)s*CD + c);
      acc.x += lo16f(q.x)*w; acc.y += hi16f(q.x)*w;
      acc.z += lo16f(q.y)*w; acc.w += hi16f(q.y)*w;
    }
    p += cnt;
  }
  float wd = dinv[row];
  uint2 o;
  o.x = (u32)f2bf(acc.x*wd) | ((u32)f2bf(acc.y*wd) << 16);
  o.y = (u32)f2bf(acc.z*wd) | ((u32)f2bf(acc.w*wd) << 16);
  *(uint2*)(xout + (long long)row*CD + c) = o;
}

// semantic attention scores (z in bf16)
__global__ void k_att(const u16* __restrict__ z0, const u16* __restrict__ z1,
                      const float* __restrict__ rsi0, const float* __restrict__ rsi1,
                      const float* __restrict__ W1, const float* __restrict__ b1,
                      const float* __restrict__ W2, float* __restrict__ s_out, int n){
  __shared__ float A[16][128];
  __shared__ float wr[2][2];
  int j = threadIdx.x;
  int r0 = blockIdx.x*16;
  for (int r = 0; r < 16; ++r){
    int rr = r0 + r;
    float v = 0.f;
    if (rr < n)        v = bf2f(z0[(long long)rr*CD + j]) * rsi0[rr];
    else if (rr < 2*n) v = bf2f(z1[(long long)(rr-n)*CD + j]) * rsi1[rr-n];
    A[r][j] = v;
  }
  __syncthreads();
  float acc[16];
  #pragma unroll
  for (int r = 0; r < 16; ++r) acc[r] = 0.f;
  for (int k = 0; k < 128; k += 4){
    float w0 = W1[(k+0)*128 + j];
    float w1 = W1[(k+1)*128 + j];
    float w2v= W1[(k+2)*128 + j];
    float w3 = W1[(k+3)*128 + j];
    #pragma unroll
    for (int r = 0; r < 16; ++r){
      float4 a = *(const float4*)&A[r][k];
      acc[r] += a.x*w0 + a.y*w1 + a.z*w2v + a.w*w3;
    }
  }
  float bb = b1[j];
  float w2 = W2[j];
  float pc0 = 0.f, pc1 = 0.f;
  #pragma unroll
  for (int r = 0; r < 16; ++r){
    int rr = r0 + r;
    if (rr < 2*n){
      float val = tanhf(acc[r] + bb) * w2;
      if (rr < n) pc0 += val; else pc1 += val;
    }
  }
  for (int off = 32; off > 0; off >>= 1){
    pc0 += __shfl_down(pc0, off);
    pc1 += __shfl_down(pc1, off);
  }
  if ((j & 63) == 0){ wr[0][j>>6] = pc0; wr[1][j>>6] = pc1; }
  __syncthreads();
  if (j == 0){
    atomicAdd(&s_out[0], wr[0][0] + wr[0][1]);
    atomicAdd(&s_out[1], wr[1][0] + wr[1][1]);
  }
}

__global__ void k_combine(const u16* __restrict__ z0, const u16* __restrict__ z1,
                          const float* __restrict__ rsi0, const float* __restrict__ rsi1,
                          const float* __restrict__ s, u16* __restrict__ h, int n){
  int idx = blockIdx.x*256 + threadIdx.x;
  if (idx >= n*CD) return;
  int v = idx >> 7;
  float s0 = s[0]*(1.0f/n), s1 = s[1]*(1.0f/n);
  float m = fmaxf(s0, s1);
  float e0 = __expf(s0 - m), e1 = __expf(s1 - m);
  float r = 1.0f/(e0 + e1);
  h[idx] = f2bf((e0*r)*bf2f(z0[idx])*rsi0[v] + (e1*r)*bf2f(z1[idx])*rsi1[v]);
}

__global__ void k_emb(const u16* __restrict__ x2, u16* __restrict__ h_u,
                      u16* __restrict__ h_i){
  int idx = blockIdx.x*256 + threadIdx.x;
  if (idx >= CNN*CD) return;
  if (idx < CNU*CD) h_u[idx] = f2bf(0.5f*bf2f(h_u[idx]) + 0.5f*bf2f(x2[idx]));
  else { int k = idx - CNU*CD; h_i[k] = f2bf(0.5f*bf2f(h_i[k]) + 0.5f*bf2f(x2[idx])); }
}

__global__ void k_sslnorm(const u16* __restrict__ xui, const u16* __restrict__ hemb,
                          const int* __restrict__ idx, int rowoff,
                          float* __restrict__ n1, float* __restrict__ n2,
                          float* __restrict__ pos_acc){
  int r = blockIdx.x*4 + (threadIdx.x >> 6);
  int lane = threadIdx.x & 63;
  if (r >= CB) return;
  int g = idx[r];
  const u16* e1 = xui + (long long)(g + rowoff)*CD;
  const u16* e2 = hemb + (long long)g*CD;
  float a0 = bf2f(e1[lane]), a1 = bf2f(e1[lane+64]);
  float b0 = bf2f(e2[lane]), b1 = bf2f(e2[lane+64]);
  float s1 = a0*a0 + a1*a1, s2 = b0*b0 + b1*b1, s12 = a0*b0 + a1*b1;
  for (int off = 32; off > 0; off >>= 1){
    s1  += __shfl_down(s1, off);
    s2  += __shfl_down(s2, off);
    s12 += __shfl_down(s12, off);
  }
  s1 = __shfl(s1, 0); s2 = __shfl(s2, 0); s12 = __shfl(s12, 0);
  float i1 = 1.0f / fmaxf(sqrtf(s1), 1e-12f);
  float i2 = 1.0f / fmaxf(sqrtf(s2), 1e-12f);
  float* o1 = n1 + (long long)r*CD;
  float* o2 = n2 + (long long)r*CD;
  o1[lane] = a0*i1; o1[lane+64] = a1*i1;
  o2[lane] = b0*i2; o2[lane+64] = b1*i2;
  if (lane == 0) atomicAdd(pos_acc, s12*i1*i2*2.0f);
}

// alls[i] += sum_j exp(2 * n1_i . n2_j). 128x128 tile, 8x8/thread as two float4
// groups 64 apart (bank-conflict-free: <=2-way aliasing on every LDS read).
__global__ void k_alls(const float* __restrict__ n1, const float* __restrict__ n2,
                       float* __restrict__ alls){
  __shared__ float A_s[128][128];
  __shared__ float B_s[32][128];
  int tid = threadIdx.x;
  int tx = tid & 15, ty = tid >> 4;
  int i0 = blockIdx.x*128;
  {
    int r = tid >> 1, c0 = (tid & 1)*64;
    const float* sp = n1 + (long long)(i0 + r)*CD + c0;
    #pragma unroll
    for (int u = 0; u < 64; u += 4){
      float4 v = *(const float4*)(sp + u);
      A_s[c0+u  ][r] = v.x; A_s[c0+u+1][r] = v.y;
      A_s[c0+u+2][r] = v.z; A_s[c0+u+3][r] = v.w;
    }
  }
  float esum[8];
  #pragma unroll
  for (int a = 0; a < 8; ++a) esum[a] = 0.f;
  int j0s = blockIdx.y * 1024;
  for (int jt = 0; jt < 8; ++jt){
    int j0 = j0s + jt*128;
    float dot[8][8];
    #pragma unroll
    for (int a = 0; a < 8; ++a)
      #pragma unroll
      for (int b = 0; b < 8; ++b) dot[a][b] = 0.f;
    for (int kc = 0; kc < 128; kc += 32){
      __syncthreads();
      {
        int jj = tid >> 1, kh = (tid & 1)*16;
        const float* sp = n2 + (long long)(j0 + jj)*CD + kc + kh;
        #pragma unroll
        for (int u = 0; u < 16; u += 4){
          float4 v = *(const float4*)(sp + u);
          B_s[kh+u  ][jj] = v.x; B_s[kh+u+1][jj] = v.y;
          B_s[kh+u+2][jj] = v.z; B_s[kh+u+3][jj] = v.w;
        }
      }
      __syncthreads();
      #pragma unroll 4
      for (int k = 0; k < 32; ++k){
        float4 a0 = *(const float4*)&A_s[kc+k][ty*4];
        float4 a1 = *(const float4*)&A_s[kc+k][64 + ty*4];
        float4 b0 = *(const float4*)&B_s[k][tx*4];
        float4 b1 = *(const float4*)&B_s[k][64 + tx*4];
        float av[8] = {a0.x,a0.y,a0.z,a0.w,a1.x,a1.y,a1.z,a1.w};
        float bv[8] = {b0.x,b0.y,b0.z,b0.w,b1.x,b1.y,b1.z,b1.w};
        #pragma unroll
        for (int a = 0; a < 8; ++a)
          #pragma unroll
          for (int b = 0; b < 8; ++b) dot[a][b] += av[a]*bv[b];
      }
    }
    #pragma unroll
    for (int a = 0; a < 8; ++a){
      float s = 0.f;
      #pragma unroll
      for (int b = 0; b < 8; ++b) s += __expf(dot[a][b]*2.0f);
      esum[a] += s;
    }
  }
  __syncthreads();
  float* red = &B_s[0][0];   // 128*17 = 2176 <= 4096 floats
  #pragma unroll
  for (int a = 0; a < 8; ++a){
    int rl = (a >> 2)*64 + ty*4 + (a & 3);
    red[rl*17 + tx] = esum[a];
  }
  __syncthreads();
  if (tid < 128){
    float s = 0.f;
    #pragma unroll
    for (int t = 0; t < 16; ++t) s += red[tid*17 + t];
    atomicAdd(&alls[i0 + tid], s);
  }
}

__global__ void k_logsum(const float* __restrict__ alls, float* __restrict__ misc){
  int i = blockIdx.x*256 + threadIdx.x;
  float v = logf(alls[i]);
  for (int off = 32; off > 0; off >>= 1) v += __shfl_down(v, off);
  if ((threadIdx.x & 63) == 0) atomicAdd(&misc[(i < CB) ? 13 : 15], v);
}

__global__ void k_final(const u16* __restrict__ emb, const int* __restrict__ idx,
                        const float* __restrict__ W, const float* __restrict__ bias,
                        const float* __restrict__ lg, const float* __restrict__ lb,
                        float* __restrict__ outp){
  __shared__ float A[8][128];
  __shared__ float red[8][4];
  int j = threadIdx.x;
  int r0 = blockIdx.x*8;
  for (int r = 0; r < 8; ++r){
    int g = idx[r0 + r];
    A[r][j] = bf2f(emb[(long long)g*CD + j]);
  }
  __syncthreads();
  float acc[8];
  #pragma unroll
  for (int r = 0; r < 8; ++r) acc[r] = 0.f;
  for (int k = 0; k < 128; k += 4){
    float w0 = W[(k+0)*128 + j];
    float w1 = W[(k+1)*128 + j];
    float w2 = W[(k+2)*128 + j];
    float w3 = W[(k+3)*128 + j];
    #pragma unroll
    for (int r = 0; r < 8; ++r){
      float4 a = *(const float4*)&A[r][k];
      acc[r] += a.x*w0 + a.y*w1 + a.z*w2 + a.w*w3;
    }
  }
  float bb = bias[j];
  #pragma unroll
  for (int r = 0; r < 8; ++r){
    float v = acc[r] + bb;
    acc[r] = (v < 0.f) ? 0.f : v;
  }
  int wid = j >> 6, lane = j & 63;
  #pragma unroll
  for (int r = 0; r < 8; ++r){
    float s = acc[r], q = acc[r]*acc[r];
    for (int off = 32; off > 0; off >>= 1){
      s += __shfl_down(s, off); q += __shfl_down(q, off);
    }
    if (lane == 0){ red[r][wid*2] = s; red[r][wid*2+1] = q; }
  }
  __syncthreads();
  float gg = lg[j], be = lb[j];
  #pragma unroll
  for (int r = 0; r < 8; ++r){
    float mu = (red[r][0] + red[r][2]) * (1.0f/128.0f);
    float ms = (red[r][1] + red[r][3]) * (1.0f/128.0f);
    float var = ms - mu*mu;
    float y = (acc[r] - mu) * rsqrtf(var + 1e-5f) * gg + be;
    outp[(long long)(r0 + r)*CD + j] = y;
  }
}

__global__ void k_loss(const float* __restrict__ misc, float* __restrict__ o){
  float lu = (misc[13] - misc[12]) * (1.0f/CB);
  float li = (misc[15] - misc[14]) * (1.0f/CB);
  o[0] = 0.4f*(lu + li);
}

extern "C" void kernel_launch(void* const* d_in, const int* in_sizes, int n_in,
                              void* d_out, int out_size, void* d_ws, size_t ws_size,
                              hipStream_t stream){
  (void)in_sizes; (void)n_in; (void)out_size; (void)ws_size;
  const float* feat_user = (const float*)d_in[0];
  const float* feat_item = (const float*)d_in[1];
  const float* u_W1 = (const float*)d_in[2];
  const float* u_b1 = (const float*)d_in[3];
  const float* u_W2 = (const float*)d_in[4];
  const float* i_W1 = (const float*)d_in[5];
  const float* i_b1 = (const float*)d_in[6];
  const float* i_W2 = (const float*)d_in[7];
  const float* user_W = (const float*)d_in[8];
  const float* user_b = (const float*)d_in[9];
  const float* item_W = (const float*)d_in[10];
  const float* item_b = (const float*)d_in[11];
  const float* ln_g = (const float*)d_in[12];
  const float* ln_b = (const float*)d_in[13];
  const int* ump0s = (const int*)d_in[14]; const int* ump0d = (const int*)d_in[15];
  const int* ump1s = (const int*)d_in[16]; const int* ump1d = (const int*)d_in[17];
  const int* imp0s = (const int*)d_in[18]; const int* imp0d = (const int*)d_in[19];
  const int* imp1s = (const int*)d_in[20]; const int* imp1d = (const int*)d_in[21];
  const int* ui_row = (const int*)d_in[22]; const int* ui_col = (const int*)d_in[23];
  const int* user_idx = (const int*)d_in[24]; const int* item_idx = (const int*)d_in[25];
  const int* neg_idx = (const int*)d_in[26];

  u16* W  = (u16*)d_ws;
  u16* fb = W;                      // 10,240,000 bf16: concat feats
  u16* hu = W + 10240000LL;         // 5,120,000
  u16* hi = W + 15360000LL;         // 5,120,000
  u16* xb = W + 20480000LL;         // 10,240,000 (UI ping)
  u16* x2 = W + 30720000LL;         // 10,240,000 (UI pong, final UI result)
  u16* z0 = W + 40960000LL;         // 5,120,000
  u16* z1 = W + 46080000LL;         // 5,120,000
  float* F   = (float*)(W + 51200000LL);
  float* rs  = F;                   // 320,000
  float* dinv= F + 320000;          // 80,000
  float* alls= F + 400000;          // 16,384
  float* misc= F + 416384;          // 64
  int* I     = (int*)(F + 416448);
  int* mp_p0 = I;                   // 40,001
  int* mp_p1 = I + 40001;           // 40,001
  int* mp_cur= I + 80002;           // 40,000
  int* mp_c0 = I + 120002;          // 640,000
  int* mp_c1 = I + 760002;          // 640,000
  // overlays
  int* ui_ptr    = (int*)hu;        // 80,001  (hu/hi region dead until first combine)
  int* ui_cursor = ui_ptr + 80001;  // 80,000
  int* ui_csr    = ui_cursor + 80000; // 1,600,000
  float* n1u = (float*)xb;          // x region dead after UI hop 3
  float* n2u = n1u + (long long)CB*CD;
  float* n1i = n1u + 2LL*CB*CD;
  float* n2i = n1u + 3LL*CB*CD;
  float* out = (float*)d_out;

  k_zero<<<(400000 + 255)/256, 256, 0, stream>>>(rs, 400000);   // rs + dinv
  k_zero<<<(16448 + 255)/256, 256, 0, stream>>>(alls, 16448);   // alls + misc

  k_initb<<<40000, 256, 0, stream>>>(feat_user, feat_item, fb);

  k_deg<<<2500, 256, 0, stream>>>(ump0s, ump0d, rs + 0,      rs + 40000,  CEMP);
  k_deg<<<2500, 256, 0, stream>>>(ump1s, ump1d, rs + 80000,  rs + 120000, CEMP);
  k_deg<<<2500, 256, 0, stream>>>(imp0s, imp0d, rs + 160000, rs + 200000, CEMP);
  k_deg<<<2500, 256, 0, stream>>>(imp1s, imp1d, rs + 240000, rs + 280000, CEMP);
  k_rs<<<1250, 256, 0, stream>>>(rs, 320000);
  k_degui<<<6250, 256, 0, stream>>>(ui_row, dinv, CEUI);
  k_dinv<<<(CNN + 255)/256, 256, 0, stream>>>(dinv, CNN);

  // UI CSR build (dst = ui_row, src = ui_col)
  k_izero<<<(80000 + 255)/256, 256, 0, stream>>>(ui_cursor, 80000);
  k_hist<<<6250, 256, 0, stream>>>(ui_row, ui_cursor, CEUI);
  k_scan<<<1, 1024, 0, stream>>>(ui_cursor, ui_ptr, 80000);
  k_fill<<<6250, 256, 0, stream>>>(ui_col, ui_row, ui_cursor, ui_csr, CEUI);

  // UI propagation: fb -> x2 -> xb -> x2
  k_gather_ui<<<10000, 256, 0, stream>>>(fb, ui_ptr, ui_csr, dinv, x2, CNN);
  k_gather_ui<<<10000, 256, 0, stream>>>(x2, ui_ptr, ui_csr, dinv, xb, CNN);
  k_gather_ui<<<10000, 256, 0, stream>>>(xb, ui_ptr, ui_csr, dinv, x2, CNN);

  // HAN user
  k_izero<<<(40000 + 255)/256, 256, 0, stream>>>(mp_cur, 40000);
  k_hist<<<2500, 256, 0, stream>>>(ump0d, mp_cur, CEMP);
  k_scan<<<1, 1024, 0, stream>>>(mp_cur, mp_p0, 40000);
  k_fill<<<2500, 256, 0, stream>>>(ump0s, ump0d, mp_cur, mp_c0, CEMP);
  k_izero<<<(40000 + 255)/256, 256, 0, stream>>>(mp_cur, 40000);
  k_hist<<<2500, 256, 0, stream>>>(ump1d, mp_cur, CEMP);
  k_scan<<<1, 1024, 0, stream>>>(mp_cur, mp_p1, 40000);
  k_fill<<<2500, 256, 0, stream>>>(ump1s, ump1d, mp_cur, mp_c1, CEMP);
  for (int L = 0; L < 3; ++L){
    const u16* hin = (L == 0) ? fb : hu;
    k_gather_mp<<<5000, 256, 0, stream>>>(hin, mp_p0, mp_c0, rs + 0,     z0, CNU);
    k_gather_mp<<<5000, 256, 0, stream>>>(hin, mp_p1, mp_c1, rs + 80000, z1, CNU);
    k_att<<<5000, 128, 0, stream>>>(z0, z1, rs + 40000, rs + 120000,
                                    u_W1, u_b1, u_W2, misc + 2*L, CNU);
    k_combine<<<20000, 256, 0, stream>>>(z0, z1, rs + 40000, rs + 120000,
                                         misc + 2*L, hu, CNU);
  }
  // HAN item
  k_izero<<<(40000 + 255)/256, 256, 0, stream>>>(mp_cur, 40000);
  k_hist<<<2500, 256, 0, stream>>>(imp0d, mp_cur, CEMP);
  k_scan<<<1, 1024, 0, stream>>>(mp_cur, mp_p0, 40000);
  k_fill<<<2500, 256, 0, stream>>>(imp0s, imp0d, mp_cur, mp_c0, CEMP);
  k_izero<<<(40000 + 255)/256, 256, 0, stream>>>(mp_cur, 40000);
  k_hist<<<2500, 256, 0, stream>>>(imp1d, mp_cur, CEMP);
  k_scan<<<1, 1024, 0, stream>>>(mp_cur, mp_p1, 40000);
  k_fill<<<2500, 256, 0, stream>>>(imp1s, imp1d, mp_cur, mp_c1, CEMP);
  for (int L = 0; L < 3; ++L){
    const u16* hin = (L == 0) ? (fb + (long long)CNU*CD) : hi;
    k_gather_mp<<<5000, 256, 0, stream>>>(hin, mp_p0, mp_c0, rs + 160000, z0, CNU);
    k_gather_mp<<<5000, 256, 0, stream>>>(hin, mp_p1, mp_c1, rs + 240000, z1, CNU);
    k_att<<<5000, 128, 0, stream>>>(z0, z1, rs + 200000, rs + 280000,
                                    i_W1, i_b1, i_W2, misc + 6 + 2*L, CNU);
    k_combine<<<20000, 256, 0, stream>>>(z0, z1, rs + 200000, rs + 280000,
                                         misc + 6 + 2*L, hi, CNU);
  }

  k_emb<<<40000, 256, 0, stream>>>(x2, hu, hi);

  // SSL
  k_sslnorm<<<CB/4, 256, 0, stream>>>(x2, hu, user_idx, 0,   n1u, n2u, misc + 12);
  k_sslnorm<<<CB/4, 256, 0, stream>>>(x2, hi, item_idx, CNU, n1i, n2i, misc + 14);
  k_alls<<<dim3(64, 8), 256, 0, stream>>>(n1u, n2u, alls);
  k_alls<<<dim3(64, 8), 256, 0, stream>>>(n1i, n2i, alls + CB);
  k_logsum<<<64, 256, 0, stream>>>(alls, misc);

  k_final<<<1024, 128, 0, stream>>>(hu, user_idx, user_W, user_b, ln_g, ln_b, out);
  k_final<<<1024, 128, 0, stream>>>(hi, item_idx, item_W, item_b, ln_g, ln_b, out + (long long)CB*CD);
  k_final<<<1024, 128, 0, stream>>>(hi, neg_idx,  item_W, item_b, ln_g, ln_b, out + 2LL*CB*CD);
  k_loss<<<1, 1, 0, stream>>>(misc, out + 3LL*CB*CD);
}

// Round 7
// 3588.395 us; speedup vs baseline: 6.6104x; 1.0343x over previous
//
#include <hip/hip_runtime.h>
#include <math.h>

typedef unsigned short u16;
typedef unsigned int u32;

#define CNU 40000
#define CNN 80000
#define CD  128
#define CEMP 640000
#define CEUI 1600000
#define CB  8192

__device__ __forceinline__ float bf2f(u16 b){
  union { u32 u; float f; } v; v.u = ((u32)b) << 16; return v.f;
}
__device__ __forceinline__ u16 f2bf(float f){
  union { float f; u32 u; } v; v.f = f;
  u32 u = v.u + 0x7FFFu + ((v.u >> 16) & 1u);
  return (u16)(u >> 16);
}
__device__ __forceinline__ float lo16f(u32 q){ union { u32 u; float f; } v; v.u = q << 16; return v.f; }
__device__ __forceinline__ float hi16f(u32 q){ union { u32 u; float f; } v; v.u = q & 0xFFFF0000u; return v.f; }

__global__ void k_zero(float* __restrict__ p, long long n){
  long long i = (long long)blockIdx.x*256 + threadIdx.x;
  if (i < n) p[i] = 0.f;
}

__global__ void k_izero(int* __restrict__ p, int n){
  int i = blockIdx.x*256 + threadIdx.x;
  if (i < n) p[i] = 0;
}

__global__ void k_initb(const float* __restrict__ fu, const float* __restrict__ fi,
                        u16* __restrict__ fb){
  int idx = blockIdx.x*256 + threadIdx.x;
  if (idx >= CNN*CD) return;
  float v = (idx < CNU*CD) ? fu[idx] : fi[idx - CNU*CD];
  fb[idx] = f2bf(v);
}

__global__ void k_deg(const int* __restrict__ src, const int* __restrict__ dst,
                      float* __restrict__ dego, float* __restrict__ degi, int E){
  int e = blockIdx.x*256 + threadIdx.x;
  if (e >= E) return;
  atomicAdd(&dego[src[e]], 1.0f);
  atomicAdd(&degi[dst[e]], 1.0f);
}

__global__ void k_rs(float* __restrict__ d, int n){
  int i = blockIdx.x*256 + threadIdx.x;
  if (i >= n) return;
  float v = d[i];
  v = (v > 1.0f) ? v : 1.0f;
  d[i] = rsqrtf(v);
}

__global__ void k_degui(const int* __restrict__ row, float* __restrict__ deg, int E){
  int e = blockIdx.x*256 + threadIdx.x;
  if (e >= E) return;
  atomicAdd(&deg[row[e]], 1.0f);
}

__global__ void k_dinv(float* __restrict__ d, int n){
  int i = blockIdx.x*256 + threadIdx.x;
  if (i >= n) return;
  float v = d[i];
  d[i] = (v > 0.f) ? rsqrtf(v) : 0.f;
}

// ---- CSR build ----
__global__ void k_hist(const int* __restrict__ dst, int* __restrict__ hist, int E){
  int e = blockIdx.x*256 + threadIdx.x;
  if (e >= E) return;
  atomicAdd(&hist[dst[e]], 1);
}

__global__ void k_scan(int* __restrict__ hist_cursor, int* __restrict__ ptr, int n){
  __shared__ int part[1024];
  int t = threadIdx.x;
  int chunk = (n + 1023) >> 10;
  int beg = t*chunk, end = beg + chunk; if (end > n) end = n;
  int s = 0;
  for (int i = beg; i < end; ++i) s += hist_cursor[i];
  part[t] = s;
  __syncthreads();
  for (int off = 1; off < 1024; off <<= 1){
    int v = (t >= off) ? part[t-off] : 0;
    __syncthreads();
    part[t] += v;
    __syncthreads();
  }
  int run = (t == 0) ? 0 : part[t-1];
  if (t == 0) ptr[n] = part[1023];
  for (int i = beg; i < end; ++i){
    int h = hist_cursor[i];
    ptr[i] = run;
    hist_cursor[i] = run;
    run += h;
  }
}

__global__ void k_fill(const int* __restrict__ src, const int* __restrict__ dst,
                       int* __restrict__ cursor, int* __restrict__ csr_src, int E){
  int e = blockIdx.x*256 + threadIdx.x;
  if (e >= E) return;
  int p = atomicAdd(&cursor[dst[e]], 1);
  csr_src[p] = src[e];
}

// ---- bf16 gathers, 8-deep MLP unroll: 8 rows/block, 32 lanes/row ----
__global__ void k_gather_mp(const u16* __restrict__ h, const int* __restrict__ ptr,
                            const int* __restrict__ csr_src, const float* __restrict__ rso,
                            u16* __restrict__ z, int n){
  int row = blockIdx.x*8 + (threadIdx.x >> 5);
  if (row >= n) return;
  int lane = threadIdx.x & 31;
  int c = lane << 2;
  int p = ptr[row], pe = ptr[row+1];
  float4 acc = make_float4(0.f,0.f,0.f,0.f);
  while (p < pe){
    int cnt = pe - p; if (cnt > 32) cnt = 32;
    int   sl = (lane < cnt) ? csr_src[p + lane] : 0;
    float wl = (lane < cnt) ? rso[sl] : 0.f;
    int e = 0;
    for (; e + 8 <= cnt; e += 8){
      uint2 q[8]; float w[8];
      #pragma unroll
      for (int t = 0; t < 8; ++t){
        int s = __shfl(sl, e + t, 32);
        w[t]  = __shfl(wl, e + t, 32);
        q[t]  = *(const uint2*)(h + (long long)s*CD + c);
      }
      #pragma unroll
      for (int t = 0; t < 8; ++t){
        acc.x += lo16f(q[t].x)*w[t]; acc.y += hi16f(q[t].x)*w[t];
        acc.z += lo16f(q[t].y)*w[t]; acc.w += hi16f(q[t].y)*w[t];
      }
    }
    for (; e < cnt; ++e){
      int s   = __shfl(sl, e, 32);
      float w = __shfl(wl, e, 32);
      uint2 q = *(const uint2*)(h + (long long)s*CD + c);
      acc.x += lo16f(q.x)*w; acc.y += hi16f(q.x)*w;
      acc.z += lo16f(q.y)*w; acc.w += hi16f(q.y)*w;
    }
    p += cnt;
  }
  uint2 o;
  o.x = (u32)f2bf(acc.x) | ((u32)f2bf(acc.y) << 16);
  o.y = (u32)f2bf(acc.z) | ((u32)f2bf(acc.w) << 16);
  *(uint2*)(z + (long long)row*CD + c) = o;
}

__global__ void k_gather_ui(const u16* __restrict__ xin, const int* __restrict__ ptr,
                            const int* __restrict__ csr_src, const float* __restrict__ dinv,
                            u16* __restrict__ xout, int n){
  int row = blockIdx.x*8 + (threadIdx.x >> 5);
  if (row >= n) return;
  int lane = threadIdx.x & 31;
  int c = lane << 2;
  int p = ptr[row], pe = ptr[row+1];
  float4 acc = make_float4(0.f,0.f,0.f,0.f);
  while (p < pe){
    int cnt = pe - p; if (cnt > 32) cnt = 32;
    int   sl = (lane < cnt) ? csr_src[p + lane] : 0;
    float wl = (lane < cnt) ? dinv[sl] : 0.f;
    int e = 0;
    for (; e + 8 <= cnt; e += 8){
      uint2 q[8]; float w[8];
      #pragma unroll
      for (int t = 0; t < 8; ++t){
        int s = __shfl(sl, e + t, 32);
        w[t]  = __shfl(wl, e + t, 32);
        q[t]  = *(const uint2*)(xin + (long long)s*CD + c);
      }
      #pragma unroll
      for (int t = 0; t < 8; ++t){
        acc.x += lo16f(q[t].x)*w[t]; acc.y += hi16f(q[t].x)*w[t];
        acc.z += lo16f(q[t].y)*w[t]; acc.w += hi16f(q[t].y)*w[t];
      }
    }
    for (; e < cnt; ++e){
      int s   = __shfl(sl, e, 32);
      float w = __shfl(wl, e, 32);
      uint2 q = *(const uint2*)(xin + (long long)s*CD + c);
      acc.x += lo16f(q.x)*w; acc.y += hi16f(q.x)*w;
      acc.z += lo16f(q.y)*w; acc.w += hi16f(q.y)*w;
    }
    p += cnt;
  }
  float wd = dinv[row];
  uint2 o;
  o.x = (u32)f2bf(acc.x*wd) | ((u32)f2bf(acc.y*wd) << 16);
  o.y = (u32)f2bf(acc.z*wd) | ((u32)f2bf(acc.w*wd) << 16);
  *(uint2*)(xout + (long long)row*CD + c) = o;
}

// semantic attention scores (z in bf16)
__global__ void k_att(const u16* __restrict__ z0, const u16* __restrict__ z1,
                      const float* __restrict__ rsi0, const float* __restrict__ rsi1,
                      const float* __restrict__ W1, const float* __restrict__ b1,
                      const float* __restrict__ W2, float* __restrict__ s_out, int n){
  __shared__ float A[16][128];
  __shared__ float wr[2][2];
  int j = threadIdx.x;
  int r0 = blockIdx.x*16;
  for (int r = 0; r < 16; ++r){
    int rr = r0 + r;
    float v = 0.f;
    if (rr < n)        v = bf2f(z0[(long long)rr*CD + j]) * rsi0[rr];
    else if (rr < 2*n) v = bf2f(z1[(long long)(rr-n)*CD + j]) * rsi1[rr-n];
    A[r][j] = v;
  }
  __syncthreads();
  float acc[16];
  #pragma unroll
  for (int r = 0; r < 16; ++r) acc[r] = 0.f;
  for (int k = 0; k < 128; k += 4){
    float w0 = W1[(k+0)*128 + j];
    float w1 = W1[(k+1)*128 + j];
    float w2v= W1[(k+2)*128 + j];
    float w3 = W1[(k+3)*128 + j];
    #pragma unroll
    for (int r = 0; r < 16; ++r){
      float4 a = *(const float4*)&A[r][k];
      acc[r] += a.x*w0 + a.y*w1 + a.z*w2v + a.w*w3;
    }
  }
  float bb = b1[j];
  float w2 = W2[j];
  float pc0 = 0.f, pc1 = 0.f;
  #pragma unroll
  for (int r = 0; r < 16; ++r){
    int rr = r0 + r;
    if (rr < 2*n){
      float val = tanhf(acc[r] + bb) * w2;
      if (rr < n) pc0 += val; else pc1 += val;
    }
  }
  for (int off = 32; off > 0; off >>= 1){
    pc0 += __shfl_down(pc0, off);
    pc1 += __shfl_down(pc1, off);
  }
  if ((j & 63) == 0){ wr[0][j>>6] = pc0; wr[1][j>>6] = pc1; }
  __syncthreads();
  if (j == 0){
    atomicAdd(&s_out[0], wr[0][0] + wr[0][1]);
    atomicAdd(&s_out[1], wr[1][0] + wr[1][1]);
  }
}

__global__ void k_combine(const u16* __restrict__ z0, const u16* __restrict__ z1,
                          const float* __restrict__ rsi0, const float* __restrict__ rsi1,
                          const float* __restrict__ s, u16* __restrict__ h, int n){
  int idx = blockIdx.x*256 + threadIdx.x;
  if (idx >= n*CD) return;
  int v = idx >> 7;
  float s0 = s[0]*(1.0f/n), s1 = s[1]*(1.0f/n);
  float m = fmaxf(s0, s1);
  float e0 = __expf(s0 - m), e1 = __expf(s1 - m);
  float r = 1.0f/(e0 + e1);
  h[idx] = f2bf((e0*r)*bf2f(z0[idx])*rsi0[v] + (e1*r)*bf2f(z1[idx])*rsi1[v]);
}

__global__ void k_emb(const u16* __restrict__ x2, u16* __restrict__ h_u,
                      u16* __restrict__ h_i){
  int idx = blockIdx.x*256 + threadIdx.x;
  if (idx >= CNN*CD) return;
  if (idx < CNU*CD) h_u[idx] = f2bf(0.5f*bf2f(h_u[idx]) + 0.5f*bf2f(x2[idx]));
  else { int k = idx - CNU*CD; h_i[k] = f2bf(0.5f*bf2f(h_i[k]) + 0.5f*bf2f(x2[idx])); }
}

__global__ void k_sslnorm(const u16* __restrict__ xui, const u16* __restrict__ hemb,
                          const int* __restrict__ idx, int rowoff,
                          float* __restrict__ n1, float* __restrict__ n2,
                          float* __restrict__ pos_acc){
  int r = blockIdx.x*4 + (threadIdx.x >> 6);
  int lane = threadIdx.x & 63;
  if (r >= CB) return;
  int g = idx[r];
  const u16* e1 = xui + (long long)(g + rowoff)*CD;
  const u16* e2 = hemb + (long long)g*CD;
  float a0 = bf2f(e1[lane]), a1 = bf2f(e1[lane+64]);
  float b0 = bf2f(e2[lane]), b1 = bf2f(e2[lane+64]);
  float s1 = a0*a0 + a1*a1, s2 = b0*b0 + b1*b1, s12 = a0*b0 + a1*b1;
  for (int off = 32; off > 0; off >>= 1){
    s1  += __shfl_down(s1, off);
    s2  += __shfl_down(s2, off);
    s12 += __shfl_down(s12, off);
  }
  s1 = __shfl(s1, 0); s2 = __shfl(s2, 0); s12 = __shfl(s12, 0);
  float i1 = 1.0f / fmaxf(sqrtf(s1), 1e-12f);
  float i2 = 1.0f / fmaxf(sqrtf(s2), 1e-12f);
  float* o1 = n1 + (long long)r*CD;
  float* o2 = n2 + (long long)r*CD;
  o1[lane] = a0*i1; o1[lane+64] = a1*i1;
  o2[lane] = b0*i2; o2[lane+64] = b1*i2;
  if (lane == 0) atomicAdd(pos_acc, s12*i1*i2*2.0f);
}

// alls[i] += sum_j exp(2 * n1_i . n2_j). 128x128 tile, 8x8/thread, two float4 groups 64 apart.
__global__ void k_alls(const float* __restrict__ n1, const float* __restrict__ n2,
                       float* __restrict__ alls){
  __shared__ float A_s[128][128];
  __shared__ float B_s[32][128];
  int tid = threadIdx.x;
  int tx = tid & 15, ty = tid >> 4;
  int i0 = blockIdx.x*128;
  {
    int r = tid >> 1, c0 = (tid & 1)*64;
    const float* sp = n1 + (long long)(i0 + r)*CD + c0;
    #pragma unroll
    for (int u = 0; u < 64; u += 4){
      float4 v = *(const float4*)(sp + u);
      A_s[c0+u  ][r] = v.x; A_s[c0+u+1][r] = v.y;
      A_s[c0+u+2][r] = v.z; A_s[c0+u+3][r] = v.w;
    }
  }
  float esum[8];
  #pragma unroll
  for (int a = 0; a < 8; ++a) esum[a] = 0.f;
  int j0s = blockIdx.y * 1024;
  for (int jt = 0; jt < 8; ++jt){
    int j0 = j0s + jt*128;
    float dot[8][8];
    #pragma unroll
    for (int a = 0; a < 8; ++a)
      #pragma unroll
      for (int b = 0; b < 8; ++b) dot[a][b] = 0.f;
    for (int kc = 0; kc < 128; kc += 32){
      __syncthreads();
      {
        int jj = tid >> 1, kh = (tid & 1)*16;
        const float* sp = n2 + (long long)(j0 + jj)*CD + kc + kh;
        #pragma unroll
        for (int u = 0; u < 16; u += 4){
          float4 v = *(const float4*)(sp + u);
          B_s[kh+u  ][jj] = v.x; B_s[kh+u+1][jj] = v.y;
          B_s[kh+u+2][jj] = v.z; B_s[kh+u+3][jj] = v.w;
        }
      }
      __syncthreads();
      #pragma unroll 4
      for (int k = 0; k < 32; ++k){
        float4 a0 = *(const float4*)&A_s[kc+k][ty*4];
        float4 a1 = *(const float4*)&A_s[kc+k][64 + ty*4];
        float4 b0 = *(const float4*)&B_s[k][tx*4];
        float4 b1 = *(const float4*)&B_s[k][64 + tx*4];
        float av[8] = {a0.x,a0.y,a0.z,a0.w,a1.x,a1.y,a1.z,a1.w};
        float bv[8] = {b0.x,b0.y,b0.z,b0.w,b1.x,b1.y,b1.z,b1.w};
        #pragma unroll
        for (int a = 0; a < 8; ++a)
          #pragma unroll
          for (int b = 0; b < 8; ++b) dot[a][b] += av[a]*bv[b];
      }
    }
    #pragma unroll
    for (int a = 0; a < 8; ++a){
      float s = 0.f;
      #pragma unroll
      for (int b = 0; b < 8; ++b) s += __expf(dot[a][b]*2.0f);
      esum[a] += s;
    }
  }
  __syncthreads();
  float* red = &B_s[0][0];
  #pragma unroll
  for (int a = 0; a < 8; ++a){
    int rl = (a >> 2)*64 + ty*4 + (a & 3);
    red[rl*17 + tx] = esum[a];
  }
  __syncthreads();
  if (tid < 128){
    float s = 0.f;
    #pragma unroll
    for (int t = 0; t < 16; ++t) s += red[tid*17 + t];
    atomicAdd(&alls[i0 + tid], s);
  }
}

__global__ void k_logsum(const float* __restrict__ alls, float* __restrict__ misc){
  int i = blockIdx.x*256 + threadIdx.x;
  float v = logf(alls[i]);
  for (int off = 32; off > 0; off >>= 1) v += __shfl_down(v, off);
  if ((threadIdx.x & 63) == 0) atomicAdd(&misc[(i < CB) ? 13 : 15], v);
}

__global__ void k_final(const u16* __restrict__ emb, const int* __restrict__ idx,
                        const float* __restrict__ W, const float* __restrict__ bias,
                        const float* __restrict__ lg, const float* __restrict__ lb,
                        float* __restrict__ outp){
  __shared__ float A[8][128];
  __shared__ float red[8][4];
  int j = threadIdx.x;
  int r0 = blockIdx.x*8;
  for (int r = 0; r < 8; ++r){
    int g = idx[r0 + r];
    A[r][j] = bf2f(emb[(long long)g*CD + j]);
  }
  __syncthreads();
  float acc[8];
  #pragma unroll
  for (int r = 0; r < 8; ++r) acc[r] = 0.f;
  for (int k = 0; k < 128; k += 4){
    float w0 = W[(k+0)*128 + j];
    float w1 = W[(k+1)*128 + j];
    float w2 = W[(k+2)*128 + j];
    float w3 = W[(k+3)*128 + j];
    #pragma unroll
    for (int r = 0; r < 8; ++r){
      float4 a = *(const float4*)&A[r][k];
      acc[r] += a.x*w0 + a.y*w1 + a.z*w2 + a.w*w3;
    }
  }
  float bb = bias[j];
  #pragma unroll
  for (int r = 0; r < 8; ++r){
    float v = acc[r] + bb;
    acc[r] = (v < 0.f) ? 0.f : v;
  }
  int wid = j >> 6, lane = j & 63;
  #pragma unroll
  for (int r = 0; r < 8; ++r){
    float s = acc[r], q = acc[r]*acc[r];
    for (int off = 32; off > 0; off >>= 1){
      s += __shfl_down(s, off); q += __shfl_down(q, off);
    }
    if (lane == 0){ red[r][wid*2] = s; red[r][wid*2+1] = q; }
  }
  __syncthreads();
  float gg = lg[j], be = lb[j];
  #pragma unroll
  for (int r = 0; r < 8; ++r){
    float mu = (red[r][0] + red[r][2]) * (1.0f/128.0f);
    float ms = (red[r][1] + red[r][3]) * (1.0f/128.0f);
    float var = ms - mu*mu;
    float y = (acc[r] - mu) * rsqrtf(var + 1e-5f) * gg + be;
    outp[(long long)(r0 + r)*CD + j] = y;
  }
}

__global__ void k_loss(const float* __restrict__ misc, float* __restrict__ o){
  float lu = (misc[13] - misc[12]) * (1.0f/CB);
  float li = (misc[15] - misc[14]) * (1.0f/CB);
  o[0] = 0.4f*(lu + li);
}

extern "C" void kernel_launch(void* const* d_in, const int* in_sizes, int n_in,
                              void* d_out, int out_size, void* d_ws, size_t ws_size,
                              hipStream_t stream){
  (void)in_sizes; (void)n_in; (void)out_size; (void)ws_size;
  const float* feat_user = (const float*)d_in[0];
  const float* feat_item = (const float*)d_in[1];
  const float* u_W1 = (const float*)d_in[2];
  const float* u_b1 = (const float*)d_in[3];
  const float* u_W2 = (const float*)d_in[4];
  const float* i_W1 = (const float*)d_in[5];
  const float* i_b1 = (const float*)d_in[6];
  const float* i_W2 = (const float*)d_in[7];
  const float* user_W = (const float*)d_in[8];
  const float* user_b = (const float*)d_in[9];
  const float* item_W = (const float*)d_in[10];
  const float* item_b = (const float*)d_in[11];
  const float* ln_g = (const float*)d_in[12];
  const float* ln_b = (const float*)d_in[13];
  const int* ump0s = (const int*)d_in[14]; const int* ump0d = (const int*)d_in[15];
  const int* ump1s = (const int*)d_in[16]; const int* ump1d = (const int*)d_in[17];
  const int* imp0s = (const int*)d_in[18]; const int* imp0d = (const int*)d_in[19];
  const int* imp1s = (const int*)d_in[20]; const int* imp1d = (const int*)d_in[21];
  const int* ui_row = (const int*)d_in[22]; const int* ui_col = (const int*)d_in[23];
  const int* user_idx = (const int*)d_in[24]; const int* item_idx = (const int*)d_in[25];
  const int* neg_idx = (const int*)d_in[26];

  u16* W  = (u16*)d_ws;
  u16* fb = W;                      // 10,240,000 bf16
  u16* hu = W + 10240000LL;         // 5,120,000
  u16* hi = W + 15360000LL;         // 5,120,000
  u16* xb = W + 20480000LL;         // 10,240,000
  u16* x2 = W + 30720000LL;         // 10,240,000
  u16* z0 = W + 40960000LL;         // 5,120,000
  u16* z1 = W + 46080000LL;         // 5,120,000
  float* F   = (float*)(W + 51200000LL);
  float* rs  = F;                   // 320,000
  float* dinv= F + 320000;          // 80,000
  float* alls= F + 400000;          // 16,384
  float* misc= F + 416384;          // 64
  int* I     = (int*)(F + 416448);
  int* mp_p0 = I;                   // 40,001
  int* mp_p1 = I + 40001;           // 40,001
  int* mp_cur= I + 80002;           // 40,000
  int* mp_c0 = I + 120002;          // 640,000
  int* mp_c1 = I + 760002;          // 640,000
  int* ui_ptr    = (int*)hu;        // overlay
  int* ui_cursor = ui_ptr + 80001;
  int* ui_csr    = ui_cursor + 80000;
  float* n1u = (float*)xb;          // overlay
  float* n2u = n1u + (long long)CB*CD;
  float* n1i = n1u + 2LL*CB*CD;
  float* n2i = n1u + 3LL*CB*CD;
  float* out = (float*)d_out;

  k_zero<<<(400000 + 255)/256, 256, 0, stream>>>(rs, 400000);
  k_zero<<<(16448 + 255)/256, 256, 0, stream>>>(alls, 16448);

  k_initb<<<40000, 256, 0, stream>>>(feat_user, feat_item, fb);

  k_deg<<<2500, 256, 0, stream>>>(ump0s, ump0d, rs + 0,      rs + 40000,  CEMP);
  k_deg<<<2500, 256, 0, stream>>>(ump1s, ump1d, rs + 80000,  rs + 120000, CEMP);
  k_deg<<<2500, 256, 0, stream>>>(imp0s, imp0d, rs + 160000, rs + 200000, CEMP);
  k_deg<<<2500, 256, 0, stream>>>(imp1s, imp1d, rs + 240000, rs + 280000, CEMP);
  k_rs<<<1250, 256, 0, stream>>>(rs, 320000);
  k_degui<<<6250, 256, 0, stream>>>(ui_row, dinv, CEUI);
  k_dinv<<<(CNN + 255)/256, 256, 0, stream>>>(dinv, CNN);

  // UI CSR build
  k_izero<<<(80000 + 255)/256, 256, 0, stream>>>(ui_cursor, 80000);
  k_hist<<<6250, 256, 0, stream>>>(ui_row, ui_cursor, CEUI);
  k_scan<<<1, 1024, 0, stream>>>(ui_cursor, ui_ptr, 80000);
  k_fill<<<6250, 256, 0, stream>>>(ui_col, ui_row, ui_cursor, ui_csr, CEUI);

  // UI propagation: fb -> x2 -> xb -> x2
  k_gather_ui<<<10000, 256, 0, stream>>>(fb, ui_ptr, ui_csr, dinv, x2, CNN);
  k_gather_ui<<<10000, 256, 0, stream>>>(x2, ui_ptr, ui_csr, dinv, xb, CNN);
  k_gather_ui<<<10000, 256, 0, stream>>>(xb, ui_ptr, ui_csr, dinv, x2, CNN);

  // HAN user
  k_izero<<<(40000 + 255)/256, 256, 0, stream>>>(mp_cur, 40000);
  k_hist<<<2500, 256, 0, stream>>>(ump0d, mp_cur, CEMP);
  k_scan<<<1, 1024, 0, stream>>>(mp_cur, mp_p0, 40000);
  k_fill<<<2500, 256, 0, stream>>>(ump0s, ump0d, mp_cur, mp_c0, CEMP);
  k_izero<<<(40000 + 255)/256, 256, 0, stream>>>(mp_cur, 40000);
  k_hist<<<2500, 256, 0, stream>>>(ump1d, mp_cur, CEMP);
  k_scan<<<1, 1024, 0, stream>>>(mp_cur, mp_p1, 40000);
  k_fill<<<2500, 256, 0, stream>>>(ump1s, ump1d, mp_cur, mp_c1, CEMP);
  for (int L = 0; L < 3; ++L){
    const u16* hin = (L == 0) ? fb : hu;
    k_gather_mp<<<5000, 256, 0, stream>>>(hin, mp_p0, mp_c0, rs + 0,     z0, CNU);
    k_gather_mp<<<5000, 256, 0, stream>>>(hin, mp_p1, mp_c1, rs + 80000, z1, CNU);
    k_att<<<5000, 128, 0, stream>>>(z0, z1, rs + 40000, rs + 120000,
                                    u_W1, u_b1, u_W2, misc + 2*L, CNU);
    k_combine<<<20000, 256, 0, stream>>>(z0, z1, rs + 40000, rs + 120000,
                                         misc + 2*L, hu, CNU);
  }
  // HAN item
  k_izero<<<(40000 + 255)/256, 256, 0, stream>>>(mp_cur, 40000);
  k_hist<<<2500, 256, 0, stream>>>(imp0d, mp_cur, CEMP);
  k_scan<<<1, 1024, 0, stream>>>(mp_cur, mp_p0, 40000);
  k_fill<<<2500, 256, 0, stream>>>(imp0s, imp0d, mp_cur, mp_c0, CEMP);
  k_izero<<<(40000 + 255)/256, 256, 0, stream>>>(mp_cur, 40000);
  k_hist<<<2500, 256, 0, stream>>>(imp1d, mp_cur, CEMP);
  k_scan<<<1, 1024, 0, stream>>>(mp_cur, mp_p1, 40000);
  k_fill<<<2500, 256, 0, stream>>>(imp1s, imp1d, mp_cur, mp_c1, CEMP);
  for (int L = 0; L < 3; ++L){
    const u16* hin = (L == 0) ? (fb + (long long)CNU*CD) : hi;
    k_gather_mp<<<5000, 256, 0, stream>>>(hin, mp_p0, mp_c0, rs + 160000, z0, CNU);
    k_gather_mp<<<5000, 256, 0, stream>>>(hin, mp_p1, mp_c1, rs + 240000, z1, CNU);
    k_att<<<5000, 128, 0, stream>>>(z0, z1, rs + 200000, rs + 280000,
                                    i_W1, i_b1, i_W2, misc + 6 + 2*L, CNU);
    k_combine<<<20000, 256, 0, stream>>>(z0, z1, rs + 200000, rs + 280000,
                                         misc + 6 + 2*L, hi, CNU);
  }

  k_emb<<<40000, 256, 0, stream>>>(x2, hu, hi);

  // SSL
  k_sslnorm<<<CB/4, 256, 0, stream>>>(x2, hu, user_idx, 0,   n1u, n2u, misc + 12);
  k_sslnorm<<<CB/4, 256, 0, stream>>>(x2, hi, item_idx, CNU, n1i, n2i, misc + 14);
  k_alls<<<dim3(64, 8), 256, 0, stream>>>(n1u, n2u, alls);
  k_alls<<<dim3(64, 8), 256, 0, stream>>>(n1i, n2i, alls + CB);
  k_logsum<<<64, 256, 0, stream>>>(alls, misc);

  k_final<<<1024, 128, 0, stream>>>(hu, user_idx, user_W, user_b, ln_g, ln_b, out);
  k_final<<<1024, 128, 0, stream>>>(hi, item_idx, item_W, item_b, ln_g, ln_b, out + (long long)CB*CD);
  k_final<<<1024, 128, 0, stream>>>(hi, neg_idx,  item_W, item_b, ln_g, ln_b, out + 2LL*CB*CD);
  k_loss<<<1, 1, 0, stream>>>(misc, out + 3LL*CB*CD);
}

// Round 8
// 3411.428 us; speedup vs baseline: 6.9533x; 1.0519x over previous
//
#include <hip/hip_runtime.h>
#include <math.h>

typedef unsigned short u16;
typedef unsigned int u32;
typedef __attribute__((ext_vector_type(8))) short bf16x8;
typedef __attribute__((ext_vector_type(4))) float f32x4;

#define CNU 40000
#define CNN 80000
#define CD  128
#define CEMP 640000
#define CEUI 1600000
#define CB  8192

__device__ __forceinline__ float bf2f(u16 b){
  union { u32 u; float f; } v; v.u = ((u32)b) << 16; return v.f;
}
__device__ __forceinline__ u16 f2bf(float f){
  union { float f; u32 u; } v; v.f = f;
  u32 u = v.u + 0x7FFFu + ((v.u >> 16) & 1u);
  return (u16)(u >> 16);
}
__device__ __forceinline__ float lo16f(u32 q){ union { u32 u; float f; } v; v.u = q << 16; return v.f; }
__device__ __forceinline__ float hi16f(u32 q){ union { u32 u; float f; } v; v.u = q & 0xFFFF0000u; return v.f; }

__global__ void k_zero(float* __restrict__ p, long long n){
  long long i = (long long)blockIdx.x*256 + threadIdx.x;
  if (i < n) p[i] = 0.f;
}

__global__ void k_izero(int* __restrict__ p, int n){
  int i = blockIdx.x*256 + threadIdx.x;
  if (i < n) p[i] = 0;
}

__global__ void k_initb(const float* __restrict__ fu, const float* __restrict__ fi,
                        u16* __restrict__ fb){
  int idx = blockIdx.x*256 + threadIdx.x;
  if (idx >= CNN*CD) return;
  float v = (idx < CNU*CD) ? fu[idx] : fi[idx - CNU*CD];
  fb[idx] = f2bf(v);
}

__global__ void k_deg(const int* __restrict__ src, const int* __restrict__ dst,
                      float* __restrict__ dego, float* __restrict__ degi, int E){
  int e = blockIdx.x*256 + threadIdx.x;
  if (e >= E) return;
  atomicAdd(&dego[src[e]], 1.0f);
  atomicAdd(&degi[dst[e]], 1.0f);
}

__global__ void k_rs(float* __restrict__ d, int n){
  int i = blockIdx.x*256 + threadIdx.x;
  if (i >= n) return;
  float v = d[i];
  v = (v > 1.0f) ? v : 1.0f;
  d[i] = rsqrtf(v);
}

__global__ void k_degui(const int* __restrict__ row, float* __restrict__ deg, int E){
  int e = blockIdx.x*256 + threadIdx.x;
  if (e >= E) return;
  atomicAdd(&deg[row[e]], 1.0f);
}

__global__ void k_dinv(float* __restrict__ d, int n){
  int i = blockIdx.x*256 + threadIdx.x;
  if (i >= n) return;
  float v = d[i];
  d[i] = (v > 0.f) ? rsqrtf(v) : 0.f;
}

// ---- CSR build ----
__global__ void k_hist(const int* __restrict__ dst, int* __restrict__ hist, int E){
  int e = blockIdx.x*256 + threadIdx.x;
  if (e >= E) return;
  atomicAdd(&hist[dst[e]], 1);
}

__global__ void k_scan(int* __restrict__ hist_cursor, int* __restrict__ ptr, int n){
  __shared__ int part[1024];
  int t = threadIdx.x;
  int chunk = (n + 1023) >> 10;
  int beg = t*chunk, end = beg + chunk; if (end > n) end = n;
  int s = 0;
  for (int i = beg; i < end; ++i) s += hist_cursor[i];
  part[t] = s;
  __syncthreads();
  for (int off = 1; off < 1024; off <<= 1){
    int v = (t >= off) ? part[t-off] : 0;
    __syncthreads();
    part[t] += v;
    __syncthreads();
  }
  int run = (t == 0) ? 0 : part[t-1];
  if (t == 0) ptr[n] = part[1023];
  for (int i = beg; i < end; ++i){
    int h = hist_cursor[i];
    ptr[i] = run;
    hist_cursor[i] = run;
    run += h;
  }
}

__global__ void k_fill(const int* __restrict__ src, const int* __restrict__ dst,
                       int* __restrict__ cursor, int* __restrict__ csr_src, int E){
  int e = blockIdx.x*256 + threadIdx.x;
  if (e >= E) return;
  int p = atomicAdd(&cursor[dst[e]], 1);
  csr_src[p] = src[e];
}

// ---- gather: 1 wave/row, lane=(g=edge-slot 0..3, c=16B-chunk 0..15), 16 edges in flight ----
__global__ void k_gather_mp(const u16* __restrict__ h, const int* __restrict__ ptr,
                            const int* __restrict__ csr_src, const float* __restrict__ rso,
                            u16* __restrict__ z, int n){
  int row = (blockIdx.x*256 + threadIdx.x) >> 6;
  if (row >= n) return;
  int lane = threadIdx.x & 63;
  int g = lane >> 4, c = lane & 15;
  int p = ptr[row], pe = ptr[row+1];
  float a0=0,a1=0,a2=0,a3=0,a4=0,a5=0,a6=0,a7=0;
  const u16* hb = h + (long long)c*8;
  while (p < pe){
    uint4 q[4]; float w[4];
    #pragma unroll
    for (int u = 0; u < 4; ++u){
      int ei = p + u*4 + g;
      int s  = (ei < pe) ? csr_src[ei] : 0;
      w[u]   = (ei < pe) ? rso[s] : 0.f;
      q[u]   = *(const uint4*)(hb + (long long)s*CD);
    }
    #pragma unroll
    for (int u = 0; u < 4; ++u){
      a0 += lo16f(q[u].x)*w[u]; a1 += hi16f(q[u].x)*w[u];
      a2 += lo16f(q[u].y)*w[u]; a3 += hi16f(q[u].y)*w[u];
      a4 += lo16f(q[u].z)*w[u]; a5 += hi16f(q[u].z)*w[u];
      a6 += lo16f(q[u].w)*w[u]; a7 += hi16f(q[u].w)*w[u];
    }
    p += 16;
  }
  #pragma unroll
  for (int m = 16; m <= 32; m <<= 1){
    a0 += __shfl_xor(a0, m); a1 += __shfl_xor(a1, m);
    a2 += __shfl_xor(a2, m); a3 += __shfl_xor(a3, m);
    a4 += __shfl_xor(a4, m); a5 += __shfl_xor(a5, m);
    a6 += __shfl_xor(a6, m); a7 += __shfl_xor(a7, m);
  }
  if (g == 0){
    uint4 o;
    o.x = (u32)f2bf(a0) | ((u32)f2bf(a1) << 16);
    o.y = (u32)f2bf(a2) | ((u32)f2bf(a3) << 16);
    o.z = (u32)f2bf(a4) | ((u32)f2bf(a5) << 16);
    o.w = (u32)f2bf(a6) | ((u32)f2bf(a7) << 16);
    *(uint4*)(z + (long long)row*CD + c*8) = o;
  }
}

__global__ void k_gather_ui(const u16* __restrict__ xin, const int* __restrict__ ptr,
                            const int* __restrict__ csr_src, const float* __restrict__ dinv,
                            u16* __restrict__ xout, int n){
  int row = (blockIdx.x*256 + threadIdx.x) >> 6;
  if (row >= n) return;
  int lane = threadIdx.x & 63;
  int g = lane >> 4, c = lane & 15;
  int p = ptr[row], pe = ptr[row+1];
  float a0=0,a1=0,a2=0,a3=0,a4=0,a5=0,a6=0,a7=0;
  const u16* hb = xin + (long long)c*8;
  while (p < pe){
    uint4 q[4]; float w[4];
    #pragma unroll
    for (int u = 0; u < 4; ++u){
      int ei = p + u*4 + g;
      int s  = (ei < pe) ? csr_src[ei] : 0;
      w[u]   = (ei < pe) ? dinv[s] : 0.f;
      q[u]   = *(const uint4*)(hb + (long long)s*CD);
    }
    #pragma unroll
    for (int u = 0; u < 4; ++u){
      a0 += lo16f(q[u].x)*w[u]; a1 += hi16f(q[u].x)*w[u];
      a2 += lo16f(q[u].y)*w[u]; a3 += hi16f(q[u].y)*w[u];
      a4 += lo16f(q[u].z)*w[u]; a5 += hi16f(q[u].z)*w[u];
      a6 += lo16f(q[u].w)*w[u]; a7 += hi16f(q[u].w)*w[u];
    }
    p += 16;
  }
  #pragma unroll
  for (int m = 16; m <= 32; m <<= 1){
    a0 += __shfl_xor(a0, m); a1 += __shfl_xor(a1, m);
    a2 += __shfl_xor(a2, m); a3 += __shfl_xor(a3, m);
    a4 += __shfl_xor(a4, m); a5 += __shfl_xor(a5, m);
    a6 += __shfl_xor(a6, m); a7 += __shfl_xor(a7, m);
  }
  if (g == 0){
    float wd = dinv[row];
    uint4 o;
    o.x = (u32)f2bf(a0*wd) | ((u32)f2bf(a1*wd) << 16);
    o.y = (u32)f2bf(a2*wd) | ((u32)f2bf(a3*wd) << 16);
    o.z = (u32)f2bf(a4*wd) | ((u32)f2bf(a5*wd) << 16);
    o.w = (u32)f2bf(a6*wd) | ((u32)f2bf(a7*wd) << 16);
    *(uint4*)(xout + (long long)row*CD + c*8) = o;
  }
}

// semantic attention scores (z in bf16)
__global__ void k_att(const u16* __restrict__ z0, const u16* __restrict__ z1,
                      const float* __restrict__ rsi0, const float* __restrict__ rsi1,
                      const float* __restrict__ W1, const float* __restrict__ b1,
                      const float* __restrict__ W2, float* __restrict__ s_out, int n){
  __shared__ float A[16][128];
  __shared__ float wr[2][2];
  int j = threadIdx.x;
  int r0 = blockIdx.x*16;
  for (int r = 0; r < 16; ++r){
    int rr = r0 + r;
    float v = 0.f;
    if (rr < n)        v = bf2f(z0[(long long)rr*CD + j]) * rsi0[rr];
    else if (rr < 2*n) v = bf2f(z1[(long long)(rr-n)*CD + j]) * rsi1[rr-n];
    A[r][j] = v;
  }
  __syncthreads();
  float acc[16];
  #pragma unroll
  for (int r = 0; r < 16; ++r) acc[r] = 0.f;
  for (int k = 0; k < 128; k += 4){
    float w0 = W1[(k+0)*128 + j];
    float w1 = W1[(k+1)*128 + j];
    float w2v= W1[(k+2)*128 + j];
    float w3 = W1[(k+3)*128 + j];
    #pragma unroll
    for (int r = 0; r < 16; ++r){
      float4 a = *(const float4*)&A[r][k];
      acc[r] += a.x*w0 + a.y*w1 + a.z*w2v + a.w*w3;
    }
  }
  float bb = b1[j];
  float w2 = W2[j];
  float pc0 = 0.f, pc1 = 0.f;
  #pragma unroll
  for (int r = 0; r < 16; ++r){
    int rr = r0 + r;
    if (rr < 2*n){
      float val = tanhf(acc[r] + bb) * w2;
      if (rr < n) pc0 += val; else pc1 += val;
    }
  }
  for (int off = 32; off > 0; off >>= 1){
    pc0 += __shfl_down(pc0, off);
    pc1 += __shfl_down(pc1, off);
  }
  if ((j & 63) == 0){ wr[0][j>>6] = pc0; wr[1][j>>6] = pc1; }
  __syncthreads();
  if (j == 0){
    atomicAdd(&s_out[0], wr[0][0] + wr[0][1]);
    atomicAdd(&s_out[1], wr[1][0] + wr[1][1]);
  }
}

__global__ void k_combine(const u16* __restrict__ z0, const u16* __restrict__ z1,
                          const float* __restrict__ rsi0, const float* __restrict__ rsi1,
                          const float* __restrict__ s, u16* __restrict__ h, int n){
  int idx = blockIdx.x*256 + threadIdx.x;
  if (idx >= n*CD) return;
  int v = idx >> 7;
  float s0 = s[0]*(1.0f/n), s1 = s[1]*(1.0f/n);
  float m = fmaxf(s0, s1);
  float e0 = __expf(s0 - m), e1 = __expf(s1 - m);
  float r = 1.0f/(e0 + e1);
  h[idx] = f2bf((e0*r)*bf2f(z0[idx])*rsi0[v] + (e1*r)*bf2f(z1[idx])*rsi1[v]);
}

__global__ void k_emb(const u16* __restrict__ x2, u16* __restrict__ h_u,
                      u16* __restrict__ h_i){
  int idx = blockIdx.x*256 + threadIdx.x;
  if (idx >= CNN*CD) return;
  if (idx < CNU*CD) h_u[idx] = f2bf(0.5f*bf2f(h_u[idx]) + 0.5f*bf2f(x2[idx]));
  else { int k = idx - CNU*CD; h_i[k] = f2bf(0.5f*bf2f(h_i[k]) + 0.5f*bf2f(x2[idx])); }
}

// normalize rows -> bf16 n1b/n2b for the MFMA alls kernel; accumulate positive logits.
__global__ void k_sslnorm(const u16* __restrict__ xui, const u16* __restrict__ hemb,
                          const int* __restrict__ idx, int rowoff,
                          u16* __restrict__ n1b, u16* __restrict__ n2b,
                          float* __restrict__ pos_acc){
  int r = blockIdx.x*4 + (threadIdx.x >> 6);
  int lane = threadIdx.x & 63;
  if (r >= CB) return;
  int g = idx[r];
  const u16* e1 = xui + (long long)(g + rowoff)*CD;
  const u16* e2 = hemb + (long long)g*CD;
  float a0 = bf2f(e1[lane]), a1 = bf2f(e1[lane+64]);
  float b0 = bf2f(e2[lane]), b1 = bf2f(e2[lane+64]);
  float s1 = a0*a0 + a1*a1, s2 = b0*b0 + b1*b1, s12 = a0*b0 + a1*b1;
  for (int off = 32; off > 0; off >>= 1){
    s1  += __shfl_down(s1, off);
    s2  += __shfl_down(s2, off);
    s12 += __shfl_down(s12, off);
  }
  s1 = __shfl(s1, 0); s2 = __shfl(s2, 0); s12 = __shfl(s12, 0);
  float i1 = 1.0f / fmaxf(sqrtf(s1), 1e-12f);
  float i2 = 1.0f / fmaxf(sqrtf(s2), 1e-12f);
  u16* o1 = n1b + (long long)r*CD;
  u16* o2 = n2b + (long long)r*CD;
  o1[lane] = f2bf(a0*i1); o1[lane+64] = f2bf(a1*i1);
  o2[lane] = f2bf(b0*i2); o2[lane+64] = f2bf(b1*i2);
  if (lane == 0) atomicAdd(pos_acc, s12*i1*i2*2.0f);
}

// alls[i] += sum_j exp(2 * n1_i . n2_j) via MFMA bf16 16x16x32.
// 1 wave per (i-tile, j-range): A-frags in regs, 64 j-tiles x (4 B-loads + 4 MFMA + 4 exp).
__global__ void k_alls(const u16* __restrict__ n1b, const u16* __restrict__ n2b,
                       float* __restrict__ alls){
  int wv = threadIdx.x >> 6;
  int lane = threadIdx.x & 63;
  int i0 = (blockIdx.x*4 + wv)*16;
  int m = lane & 15, kq = lane >> 4;
  bf16x8 a[4];
  #pragma unroll
  for (int t = 0; t < 4; ++t){
    uint4 q = *(const uint4*)(n1b + (long long)(i0+m)*CD + t*32 + kq*8);
    a[t] = *(bf16x8*)&q;
  }
  float es0=0.f, es1=0.f, es2=0.f, es3=0.f;
  int j0s = blockIdx.y*1024;
  for (int jt = 0; jt < 64; ++jt){
    int j0 = j0s + jt*16;
    f32x4 acc = {0.f,0.f,0.f,0.f};
    #pragma unroll
    for (int t = 0; t < 4; ++t){
      uint4 qb = *(const uint4*)(n2b + (long long)(j0+m)*CD + t*32 + kq*8);
      bf16x8 b = *(bf16x8*)&qb;
      acc = __builtin_amdgcn_mfma_f32_16x16x32_bf16(a[t], b, acc, 0, 0, 0);
    }
    es0 += __expf(acc[0]*2.0f);
    es1 += __expf(acc[1]*2.0f);
    es2 += __expf(acc[2]*2.0f);
    es3 += __expf(acc[3]*2.0f);
  }
  #pragma unroll
  for (int msk = 1; msk <= 8; msk <<= 1){
    es0 += __shfl_xor(es0, msk);
    es1 += __shfl_xor(es1, msk);
    es2 += __shfl_xor(es2, msk);
    es3 += __shfl_xor(es3, msk);
  }
  if (m == 0){
    int rb = i0 + kq*4;
    atomicAdd(&alls[rb+0], es0);
    atomicAdd(&alls[rb+1], es1);
    atomicAdd(&alls[rb+2], es2);
    atomicAdd(&alls[rb+3], es3);
  }
}

__global__ void k_logsum(const float* __restrict__ alls, float* __restrict__ misc){
  int i = blockIdx.x*256 + threadIdx.x;
  float v = logf(alls[i]);
  for (int off = 32; off > 0; off >>= 1) v += __shfl_down(v, off);
  if ((threadIdx.x & 63) == 0) atomicAdd(&misc[(i < CB) ? 13 : 15], v);
}

__global__ void k_final(const u16* __restrict__ emb, const int* __restrict__ idx,
                        const float* __restrict__ W, const float* __restrict__ bias,
                        const float* __restrict__ lg, const float* __restrict__ lb,
                        float* __restrict__ outp){
  __shared__ float A[8][128];
  __shared__ float red[8][4];
  int j = threadIdx.x;
  int r0 = blockIdx.x*8;
  for (int r = 0; r < 8; ++r){
    int g = idx[r0 + r];
    A[r][j] = bf2f(emb[(long long)g*CD + j]);
  }
  __syncthreads();
  float acc[8];
  #pragma unroll
  for (int r = 0; r < 8; ++r) acc[r] = 0.f;
  for (int k = 0; k < 128; k += 4){
    float w0 = W[(k+0)*128 + j];
    float w1 = W[(k+1)*128 + j];
    float w2 = W[(k+2)*128 + j];
    float w3 = W[(k+3)*128 + j];
    #pragma unroll
    for (int r = 0; r < 8; ++r){
      float4 a = *(const float4*)&A[r][k];
      acc[r] += a.x*w0 + a.y*w1 + a.z*w2 + a.w*w3;
    }
  }
  float bb = bias[j];
  #pragma unroll
  for (int r = 0; r < 8; ++r){
    float v = acc[r] + bb;
    acc[r] = (v < 0.f) ? 0.f : v;
  }
  int wid = j >> 6, lane = j & 63;
  #pragma unroll
  for (int r = 0; r < 8; ++r){
    float s = acc[r], q = acc[r]*acc[r];
    for (int off = 32; off > 0; off >>= 1){
      s += __shfl_down(s, off); q += __shfl_down(q, off);
    }
    if (lane == 0){ red[r][wid*2] = s; red[r][wid*2+1] = q; }
  }
  __syncthreads();
  float gg = lg[j], be = lb[j];
  #pragma unroll
  for (int r = 0; r < 8; ++r){
    float mu = (red[r][0] + red[r][2]) * (1.0f/128.0f);
    float ms = (red[r][1] + red[r][3]) * (1.0f/128.0f);
    float var = ms - mu*mu;
    float y = (acc[r] - mu) * rsqrtf(var + 1e-5f) * gg + be;
    outp[(long long)(r0 + r)*CD + j] = y;
  }
}

__global__ void k_loss(const float* __restrict__ misc, float* __restrict__ o){
  float lu = (misc[13] - misc[12]) * (1.0f/CB);
  float li = (misc[15] - misc[14]) * (1.0f/CB);
  o[0] = 0.4f*(lu + li);
}

extern "C" void kernel_launch(void* const* d_in, const int* in_sizes, int n_in,
                              void* d_out, int out_size, void* d_ws, size_t ws_size,
                              hipStream_t stream){
  (void)in_sizes; (void)n_in; (void)out_size; (void)ws_size;
  const float* feat_user = (const float*)d_in[0];
  const float* feat_item = (const float*)d_in[1];
  const float* u_W1 = (const float*)d_in[2];
  const float* u_b1 = (const float*)d_in[3];
  const float* u_W2 = (const float*)d_in[4];
  const float* i_W1 = (const float*)d_in[5];
  const float* i_b1 = (const float*)d_in[6];
  const float* i_W2 = (const float*)d_in[7];
  const float* user_W = (const float*)d_in[8];
  const float* user_b = (const float*)d_in[9];
  const float* item_W = (const float*)d_in[10];
  const float* item_b = (const float*)d_in[11];
  const float* ln_g = (const float*)d_in[12];
  const float* ln_b = (const float*)d_in[13];
  const int* ump0s = (const int*)d_in[14]; const int* ump0d = (const int*)d_in[15];
  const int* ump1s = (const int*)d_in[16]; const int* ump1d = (const int*)d_in[17];
  const int* imp0s = (const int*)d_in[18]; const int* imp0d = (const int*)d_in[19];
  const int* imp1s = (const int*)d_in[20]; const int* imp1d = (const int*)d_in[21];
  const int* ui_row = (const int*)d_in[22]; const int* ui_col = (const int*)d_in[23];
  const int* user_idx = (const int*)d_in[24]; const int* item_idx = (const int*)d_in[25];
  const int* neg_idx = (const int*)d_in[26];

  u16* W  = (u16*)d_ws;
  u16* fb = W;                      // 10,240,000 bf16
  u16* hu = W + 10240000LL;         // 5,120,000
  u16* hi = W + 15360000LL;         // 5,120,000
  u16* xb = W + 20480000LL;         // 10,240,000
  u16* x2 = W + 30720000LL;         // 10,240,000
  u16* z0 = W + 40960000LL;         // 5,120,000
  u16* z1 = W + 46080000LL;         // 5,120,000
  float* F   = (float*)(W + 51200000LL);
  float* rs  = F;                   // 320,000
  float* dinv= F + 320000;          // 80,000
  float* alls= F + 400000;          // 16,384
  float* misc= F + 416384;          // 64
  int* I     = (int*)(F + 416448);
  int* mp_p0 = I;                   // 40,001
  int* mp_p1 = I + 40001;           // 40,001
  int* mp_cur= I + 80002;           // 40,000
  int* mp_c0 = I + 120002;          // 640,000
  int* mp_c1 = I + 760002;          // 640,000
  int* ui_ptr    = (int*)hu;        // overlay (hu/hi dead until first combine)
  int* ui_cursor = ui_ptr + 80001;
  int* ui_csr    = ui_cursor + 80000;
  u16* n1ub = xb;                   // overlay (xb dead after UI hop 3); bf16 SSL buffers
  u16* n2ub = xb + (long long)CB*CD;
  u16* n1ib = xb + 2LL*CB*CD;
  u16* n2ib = xb + 3LL*CB*CD;
  float* out = (float*)d_out;

  k_zero<<<(400000 + 255)/256, 256, 0, stream>>>(rs, 400000);
  k_zero<<<(16448 + 255)/256, 256, 0, stream>>>(alls, 16448);

  k_initb<<<40000, 256, 0, stream>>>(feat_user, feat_item, fb);

  k_deg<<<2500, 256, 0, stream>>>(ump0s, ump0d, rs + 0,      rs + 40000,  CEMP);
  k_deg<<<2500, 256, 0, stream>>>(ump1s, ump1d, rs + 80000,  rs + 120000, CEMP);
  k_deg<<<2500, 256, 0, stream>>>(imp0s, imp0d, rs + 160000, rs + 200000, CEMP);
  k_deg<<<2500, 256, 0, stream>>>(imp1s, imp1d, rs + 240000, rs + 280000, CEMP);
  k_rs<<<1250, 256, 0, stream>>>(rs, 320000);
  k_degui<<<6250, 256, 0, stream>>>(ui_row, dinv, CEUI);
  k_dinv<<<(CNN + 255)/256, 256, 0, stream>>>(dinv, CNN);

  // UI CSR build
  k_izero<<<(80000 + 255)/256, 256, 0, stream>>>(ui_cursor, 80000);
  k_hist<<<6250, 256, 0, stream>>>(ui_row, ui_cursor, CEUI);
  k_scan<<<1, 1024, 0, stream>>>(ui_cursor, ui_ptr, 80000);
  k_fill<<<6250, 256, 0, stream>>>(ui_col, ui_row, ui_cursor, ui_csr, CEUI);

  // UI propagation: fb -> x2 -> xb -> x2
  k_gather_ui<<<20000, 256, 0, stream>>>(fb, ui_ptr, ui_csr, dinv, x2, CNN);
  k_gather_ui<<<20000, 256, 0, stream>>>(x2, ui_ptr, ui_csr, dinv, xb, CNN);
  k_gather_ui<<<20000, 256, 0, stream>>>(xb, ui_ptr, ui_csr, dinv, x2, CNN);

  // HAN user
  k_izero<<<(40000 + 255)/256, 256, 0, stream>>>(mp_cur, 40000);
  k_hist<<<2500, 256, 0, stream>>>(ump0d, mp_cur, CEMP);
  k_scan<<<1, 1024, 0, stream>>>(mp_cur, mp_p0, 40000);
  k_fill<<<2500, 256, 0, stream>>>(ump0s, ump0d, mp_cur, mp_c0, CEMP);
  k_izero<<<(40000 + 255)/256, 256, 0, stream>>>(mp_cur, 40000);
  k_hist<<<2500, 256, 0, stream>>>(ump1d, mp_cur, CEMP);
  k_scan<<<1, 1024, 0, stream>>>(mp_cur, mp_p1, 40000);
  k_fill<<<2500, 256, 0, stream>>>(ump1s, ump1d, mp_cur, mp_c1, CEMP);
  for (int L = 0; L < 3; ++L){
    const u16* hin = (L == 0) ? fb : hu;
    k_gather_mp<<<10000, 256, 0, stream>>>(hin, mp_p0, mp_c0, rs + 0,     z0, CNU);
    k_gather_mp<<<10000, 256, 0, stream>>>(hin, mp_p1, mp_c1, rs + 80000, z1, CNU);
    k_att<<<5000, 128, 0, stream>>>(z0, z1, rs + 40000, rs + 120000,
                                    u_W1, u_b1, u_W2, misc + 2*L, CNU);
    k_combine<<<20000, 256, 0, stream>>>(z0, z1, rs + 40000, rs + 120000,
                                         misc + 2*L, hu, CNU);
  }
  // HAN item
  k_izero<<<(40000 + 255)/256, 256, 0, stream>>>(mp_cur, 40000);
  k_hist<<<2500, 256, 0, stream>>>(imp0d, mp_cur, CEMP);
  k_scan<<<1, 1024, 0, stream>>>(mp_cur, mp_p0, 40000);
  k_fill<<<2500, 256, 0, stream>>>(imp0s, imp0d, mp_cur, mp_c0, CEMP);
  k_izero<<<(40000 + 255)/256, 256, 0, stream>>>(mp_cur, 40000);
  k_hist<<<2500, 256, 0, stream>>>(imp1d, mp_cur, CEMP);
  k_scan<<<1, 1024, 0, stream>>>(mp_cur, mp_p1, 40000);
  k_fill<<<2500, 256, 0, stream>>>(imp1s, imp1d, mp_cur, mp_c1, CEMP);
  for (int L = 0; L < 3; ++L){
    const u16* hin = (L == 0) ? (fb + (long long)CNU*CD) : hi;
    k_gather_mp<<<10000, 256, 0, stream>>>(hin, mp_p0, mp_c0, rs + 160000, z0, CNU);
    k_gather_mp<<<10000, 256, 0, stream>>>(hin, mp_p1, mp_c1, rs + 240000, z1, CNU);
    k_att<<<5000, 128, 0, stream>>>(z0, z1, rs + 200000, rs + 280000,
                                    i_W1, i_b1, i_W2, misc + 6 + 2*L, CNU);
    k_combine<<<20000, 256, 0, stream>>>(z0, z1, rs + 200000, rs + 280000,
                                         misc + 6 + 2*L, hi, CNU);
  }

  k_emb<<<40000, 256, 0, stream>>>(x2, hu, hi);

  // SSL
  k_sslnorm<<<CB/4, 256, 0, stream>>>(x2, hu, user_idx, 0,   n1ub, n2ub, misc + 12);
  k_sslnorm<<<CB/4, 256, 0, stream>>>(x2, hi, item_idx, CNU, n1ib, n2ib, misc + 14);
  k_alls<<<dim3(128, 8), 256, 0, stream>>>(n1ub, n2ub, alls);
  k_alls<<<dim3(128, 8), 256, 0, stream>>>(n1ib, n2ib, alls + CB);
  k_logsum<<<64, 256, 0, stream>>>(alls, misc);

  k_final<<<1024, 128, 0, stream>>>(hu, user_idx, user_W, user_b, ln_g, ln_b, out);
  k_final<<<1024, 128, 0, stream>>>(hi, item_idx, item_W, item_b, ln_g, ln_b, out + (long long)CB*CD);
  k_final<<<1024, 128, 0, stream>>>(hi, neg_idx,  item_W, item_b, ln_g, ln_b, out + 2LL*CB*CD);
  k_loss<<<1, 1, 0, stream>>>(misc, out + 3LL*CB*CD);
}

// Round 9
// 2917.346 us; speedup vs baseline: 8.1309x; 1.1694x over previous
//
#include <hip/hip_runtime.h>
#include <math.h>

typedef unsigned short u16;
typedef unsigned int u32;
typedef __attribute__((ext_vector_type(8))) short bf16x8;
typedef __attribute__((ext_vector_type(4))) float f32x4;

#define CNU 40000
#define CNN 80000
#define CD  128
#define CEMP 640000
#define CEUI 1600000
#define CB  8192
#define STILE 2048

__device__ __forceinline__ float bf2f(u16 b){
  union { u32 u; float f; } v; v.u = ((u32)b) << 16; return v.f;
}
__device__ __forceinline__ u16 f2bf(float f){
  union { float f; u32 u; } v; v.f = f;
  u32 u = v.u + 0x7FFFu + ((v.u >> 16) & 1u);
  return (u16)(u >> 16);
}
__device__ __forceinline__ float lo16f(u32 q){ union { u32 u; float f; } v; v.u = q << 16; return v.f; }
__device__ __forceinline__ float hi16f(u32 q){ union { u32 u; float f; } v; v.u = q & 0xFFFF0000u; return v.f; }

__global__ void k_zero(float* __restrict__ p, long long n){
  long long i = (long long)blockIdx.x*256 + threadIdx.x;
  if (i < n) p[i] = 0.f;
}

__global__ void k_izero(int* __restrict__ p, int n){
  int i = blockIdx.x*256 + threadIdx.x;
  if (i < n) p[i] = 0;
}

__global__ void k_initb(const float* __restrict__ fu, const float* __restrict__ fi,
                        u16* __restrict__ fb){
  int idx = blockIdx.x*256 + threadIdx.x;
  if (idx >= CNN*CD) return;
  float v = (idx < CNU*CD) ? fu[idx] : fi[idx - CNU*CD];
  fb[idx] = f2bf(v);
}

__global__ void k_deg(const int* __restrict__ src, const int* __restrict__ dst,
                      float* __restrict__ dego, float* __restrict__ degi, int E){
  int e = blockIdx.x*256 + threadIdx.x;
  if (e >= E) return;
  atomicAdd(&dego[src[e]], 1.0f);
  atomicAdd(&degi[dst[e]], 1.0f);
}

__global__ void k_rs(float* __restrict__ d, int n){
  int i = blockIdx.x*256 + threadIdx.x;
  if (i >= n) return;
  float v = d[i];
  v = (v > 1.0f) ? v : 1.0f;
  d[i] = rsqrtf(v);
}

__global__ void k_degui(const int* __restrict__ row, float* __restrict__ deg, int E){
  int e = blockIdx.x*256 + threadIdx.x;
  if (e >= E) return;
  atomicAdd(&deg[row[e]], 1.0f);
}

__global__ void k_dinv(float* __restrict__ d, int n){
  int i = blockIdx.x*256 + threadIdx.x;
  if (i >= n) return;
  float v = d[i];
  d[i] = (v > 0.f) ? rsqrtf(v) : 0.f;
}

// ---- CSR build ----
__global__ void k_hist(const int* __restrict__ dst, int* __restrict__ hist, int E){
  int e = blockIdx.x*256 + threadIdx.x;
  if (e >= E) return;
  atomicAdd(&hist[dst[e]], 1);
}

// hierarchical scan, tile = 2048 (256 thr x 8)
__global__ void k_scan_part(const int* __restrict__ hist, int* __restrict__ part, int n){
  int base = blockIdx.x*STILE + threadIdx.x*8;
  int s = 0;
  #pragma unroll
  for (int u = 0; u < 8; ++u){
    int i = base + u;
    if (i < n) s += hist[i];
  }
  for (int off = 32; off > 0; off >>= 1) s += __shfl_down(s, off);
  __shared__ int wsum[4];
  if ((threadIdx.x & 63) == 0) wsum[threadIdx.x >> 6] = s;
  __syncthreads();
  if (threadIdx.x == 0) part[blockIdx.x] = wsum[0] + wsum[1] + wsum[2] + wsum[3];
}

__global__ void k_scan_top(int* __restrict__ part, int nb){
  int t = threadIdx.x;  // 64 lanes, nb <= 64
  int orig = (t < nb) ? part[t] : 0;
  int v = orig;
  #pragma unroll
  for (int off = 1; off < 64; off <<= 1){
    int u = __shfl_up(v, off);
    if (t >= off) v += u;
  }
  if (t < nb) part[t] = v - orig;   // exclusive
}

// in-place: hist doubles as cursor output. ptr gets the same offsets; ptr[n] = total.
__global__ void k_scan_down(int* __restrict__ hist_cursor, const int* __restrict__ part,
                            int* __restrict__ ptr, int n, int total){
  int b = blockIdx.x, t = threadIdx.x;
  int base = b*STILE + t*8;
  int v[8]; int s = 0;
  #pragma unroll
  for (int u = 0; u < 8; ++u){
    int i = base + u;
    v[u] = (i < n) ? hist_cursor[i] : 0;
    s += v[u];
  }
  int lane = t & 63, wv = t >> 6;
  int inc = s;
  #pragma unroll
  for (int off = 1; off < 64; off <<= 1){
    int u = __shfl_up(inc, off);
    if (lane >= off) inc += u;
  }
  __shared__ int wsum[4];
  if (lane == 63) wsum[wv] = inc;
  __syncthreads();
  int woff = 0;
  for (int wq = 0; wq < wv; ++wq) woff += wsum[wq];
  int excl = part[b] + woff + (inc - s);
  #pragma unroll
  for (int u = 0; u < 8; ++u){
    int i = base + u;
    if (i < n){ ptr[i] = excl; hist_cursor[i] = excl; excl += v[u]; }
  }
  if (b == 0 && t == 0) ptr[n] = total;
}

__global__ void k_fill(const int* __restrict__ src, const int* __restrict__ dst,
                       int* __restrict__ cursor, int* __restrict__ csr_src, int E){
  int e = blockIdx.x*256 + threadIdx.x;
  if (e >= E) return;
  int p = atomicAdd(&cursor[dst[e]], 1);
  csr_src[p] = src[e];
}

// ---- gather: 1 wave/row, lane=(g=edge-slot 0..3, c=16B-chunk 0..15), 16 edges in flight ----
__global__ void k_gather_mp(const u16* __restrict__ h, const int* __restrict__ ptr,
                            const int* __restrict__ csr_src, const float* __restrict__ rso,
                            u16* __restrict__ z, int n){
  int row = (blockIdx.x*256 + threadIdx.x) >> 6;
  if (row >= n) return;
  int lane = threadIdx.x & 63;
  int g = lane >> 4, c = lane & 15;
  int p = ptr[row], pe = ptr[row+1];
  float a0=0,a1=0,a2=0,a3=0,a4=0,a5=0,a6=0,a7=0;
  const u16* hb = h + (long long)c*8;
  while (p < pe){
    uint4 q[4]; float w[4];
    #pragma unroll
    for (int u = 0; u < 4; ++u){
      int ei = p + u*4 + g;
      int s  = (ei < pe) ? csr_src[ei] : 0;
      w[u]   = (ei < pe) ? rso[s] : 0.f;
      q[u]   = *(const uint4*)(hb + (long long)s*CD);
    }
    #pragma unroll
    for (int u = 0; u < 4; ++u){
      a0 += lo16f(q[u].x)*w[u]; a1 += hi16f(q[u].x)*w[u];
      a2 += lo16f(q[u].y)*w[u]; a3 += hi16f(q[u].y)*w[u];
      a4 += lo16f(q[u].z)*w[u]; a5 += hi16f(q[u].z)*w[u];
      a6 += lo16f(q[u].w)*w[u]; a7 += hi16f(q[u].w)*w[u];
    }
    p += 16;
  }
  #pragma unroll
  for (int m = 16; m <= 32; m <<= 1){
    a0 += __shfl_xor(a0, m); a1 += __shfl_xor(a1, m);
    a2 += __shfl_xor(a2, m); a3 += __shfl_xor(a3, m);
    a4 += __shfl_xor(a4, m); a5 += __shfl_xor(a5, m);
    a6 += __shfl_xor(a6, m); a7 += __shfl_xor(a7, m);
  }
  if (g == 0){
    uint4 o;
    o.x = (u32)f2bf(a0) | ((u32)f2bf(a1) << 16);
    o.y = (u32)f2bf(a2) | ((u32)f2bf(a3) << 16);
    o.z = (u32)f2bf(a4) | ((u32)f2bf(a5) << 16);
    o.w = (u32)f2bf(a6) | ((u32)f2bf(a7) << 16);
    *(uint4*)(z + (long long)row*CD + c*8) = o;
  }
}

__global__ void k_gather_ui(const u16* __restrict__ xin, const int* __restrict__ ptr,
                            const int* __restrict__ csr_src, const float* __restrict__ dinv,
                            u16* __restrict__ xout, int n){
  int row = (blockIdx.x*256 + threadIdx.x) >> 6;
  if (row >= n) return;
  int lane = threadIdx.x & 63;
  int g = lane >> 4, c = lane & 15;
  int p = ptr[row], pe = ptr[row+1];
  float a0=0,a1=0,a2=0,a3=0,a4=0,a5=0,a6=0,a7=0;
  const u16* hb = xin + (long long)c*8;
  while (p < pe){
    uint4 q[4]; float w[4];
    #pragma unroll
    for (int u = 0; u < 4; ++u){
      int ei = p + u*4 + g;
      int s  = (ei < pe) ? csr_src[ei] : 0;
      w[u]   = (ei < pe) ? dinv[s] : 0.f;
      q[u]   = *(const uint4*)(hb + (long long)s*CD);
    }
    #pragma unroll
    for (int u = 0; u < 4; ++u){
      a0 += lo16f(q[u].x)*w[u]; a1 += hi16f(q[u].x)*w[u];
      a2 += lo16f(q[u].y)*w[u]; a3 += hi16f(q[u].y)*w[u];
      a4 += lo16f(q[u].z)*w[u]; a5 += hi16f(q[u].z)*w[u];
      a6 += lo16f(q[u].w)*w[u]; a7 += hi16f(q[u].w)*w[u];
    }
    p += 16;
  }
  #pragma unroll
  for (int m = 16; m <= 32; m <<= 1){
    a0 += __shfl_xor(a0, m); a1 += __shfl_xor(a1, m);
    a2 += __shfl_xor(a2, m); a3 += __shfl_xor(a3, m);
    a4 += __shfl_xor(a4, m); a5 += __shfl_xor(a5, m);
    a6 += __shfl_xor(a6, m); a7 += __shfl_xor(a7, m);
  }
  if (g == 0){
    float wd = dinv[row];
    uint4 o;
    o.x = (u32)f2bf(a0*wd) | ((u32)f2bf(a1*wd) << 16);
    o.y = (u32)f2bf(a2*wd) | ((u32)f2bf(a3*wd) << 16);
    o.z = (u32)f2bf(a4*wd) | ((u32)f2bf(a5*wd) << 16);
    o.w = (u32)f2bf(a6*wd) | ((u32)f2bf(a7*wd) << 16);
    *(uint4*)(xout + (long long)row*CD + c*8) = o;
  }
}

// semantic attention scores (z in bf16)
__global__ void k_att(const u16* __restrict__ z0, const u16* __restrict__ z1,
                      const float* __restrict__ rsi0, const float* __restrict__ rsi1,
                      const float* __restrict__ W1, const float* __restrict__ b1,
                      const float* __restrict__ W2, float* __restrict__ s_out, int n){
  __shared__ float A[16][128];
  __shared__ float wr[2][2];
  int j = threadIdx.x;
  int r0 = blockIdx.x*16;
  for (int r = 0; r < 16; ++r){
    int rr = r0 + r;
    float v = 0.f;
    if (rr < n)        v = bf2f(z0[(long long)rr*CD + j]) * rsi0[rr];
    else if (rr < 2*n) v = bf2f(z1[(long long)(rr-n)*CD + j]) * rsi1[rr-n];
    A[r][j] = v;
  }
  __syncthreads();
  float acc[16];
  #pragma unroll
  for (int r = 0; r < 16; ++r) acc[r] = 0.f;
  for (int k = 0; k < 128; k += 4){
    float w0 = W1[(k+0)*128 + j];
    float w1 = W1[(k+1)*128 + j];
    float w2v= W1[(k+2)*128 + j];
    float w3 = W1[(k+3)*128 + j];
    #pragma unroll
    for (int r = 0; r < 16; ++r){
      float4 a = *(const float4*)&A[r][k];
      acc[r] += a.x*w0 + a.y*w1 + a.z*w2v + a.w*w3;
    }
  }
  float bb = b1[j];
  float w2 = W2[j];
  float pc0 = 0.f, pc1 = 0.f;
  #pragma unroll
  for (int r = 0; r < 16; ++r){
    int rr = r0 + r;
    if (rr < 2*n){
      float val = tanhf(acc[r] + bb) * w2;
      if (rr < n) pc0 += val; else pc1 += val;
    }
  }
  for (int off = 32; off > 0; off >>= 1){
    pc0 += __shfl_down(pc0, off);
    pc1 += __shfl_down(pc1, off);
  }
  if ((j & 63) == 0){ wr[0][j>>6] = pc0; wr[1][j>>6] = pc1; }
  __syncthreads();
  if (j == 0){
    atomicAdd(&s_out[0], wr[0][0] + wr[0][1]);
    atomicAdd(&s_out[1], wr[1][0] + wr[1][1]);
  }
}

__global__ void k_combine(const u16* __restrict__ z0, const u16* __restrict__ z1,
                          const float* __restrict__ rsi0, const float* __restrict__ rsi1,
                          const float* __restrict__ s, u16* __restrict__ h, int n){
  int idx = blockIdx.x*256 + threadIdx.x;
  if (idx >= n*CD) return;
  int v = idx >> 7;
  float s0 = s[0]*(1.0f/n), s1 = s[1]*(1.0f/n);
  float m = fmaxf(s0, s1);
  float e0 = __expf(s0 - m), e1 = __expf(s1 - m);
  float r = 1.0f/(e0 + e1);
  h[idx] = f2bf((e0*r)*bf2f(z0[idx])*rsi0[v] + (e1*r)*bf2f(z1[idx])*rsi1[v]);
}

__global__ void k_emb(const u16* __restrict__ x2, u16* __restrict__ h_u,
                      u16* __restrict__ h_i){
  int idx = blockIdx.x*256 + threadIdx.x;
  if (idx >= CNN*CD) return;
  if (idx < CNU*CD) h_u[idx] = f2bf(0.5f*bf2f(h_u[idx]) + 0.5f*bf2f(x2[idx]));
  else { int k = idx - CNU*CD; h_i[k] = f2bf(0.5f*bf2f(h_i[k]) + 0.5f*bf2f(x2[idx])); }
}

// normalize rows -> bf16 n1b/n2b for MFMA alls; accumulate positive logits.
__global__ void k_sslnorm(const u16* __restrict__ xui, const u16* __restrict__ hemb,
                          const int* __restrict__ idx, int rowoff,
                          u16* __restrict__ n1b, u16* __restrict__ n2b,
                          float* __restrict__ pos_acc){
  int r = blockIdx.x*4 + (threadIdx.x >> 6);
  int lane = threadIdx.x & 63;
  if (r >= CB) return;
  int g = idx[r];
  const u16* e1 = xui + (long long)(g + rowoff)*CD;
  const u16* e2 = hemb + (long long)g*CD;
  float a0 = bf2f(e1[lane]), a1 = bf2f(e1[lane+64]);
  float b0 = bf2f(e2[lane]), b1 = bf2f(e2[lane+64]);
  float s1 = a0*a0 + a1*a1, s2 = b0*b0 + b1*b1, s12 = a0*b0 + a1*b1;
  for (int off = 32; off > 0; off >>= 1){
    s1  += __shfl_down(s1, off);
    s2  += __shfl_down(s2, off);
    s12 += __shfl_down(s12, off);
  }
  s1 = __shfl(s1, 0); s2 = __shfl(s2, 0); s12 = __shfl(s12, 0);
  float i1 = 1.0f / fmaxf(sqrtf(s1), 1e-12f);
  float i2 = 1.0f / fmaxf(sqrtf(s2), 1e-12f);
  u16* o1 = n1b + (long long)r*CD;
  u16* o2 = n2b + (long long)r*CD;
  o1[lane] = f2bf(a0*i1); o1[lane+64] = f2bf(a1*i1);
  o2[lane] = f2bf(b0*i2); o2[lane+64] = f2bf(b1*i2);
  if (lane == 0) atomicAdd(pos_acc, s12*i1*i2*2.0f);
}

// alls[i] += sum_j exp(2 * n1_i . n2_j) via MFMA bf16 16x16x32.
__global__ void k_alls(const u16* __restrict__ n1b, const u16* __restrict__ n2b,
                       float* __restrict__ alls){
  int wv = threadIdx.x >> 6;
  int lane = threadIdx.x & 63;
  int i0 = (blockIdx.x*4 + wv)*16;
  int m = lane & 15, kq = lane >> 4;
  bf16x8 a[4];
  #pragma unroll
  for (int t = 0; t < 4; ++t){
    uint4 q = *(const uint4*)(n1b + (long long)(i0+m)*CD + t*32 + kq*8);
    a[t] = *(bf16x8*)&q;
  }
  float es0=0.f, es1=0.f, es2=0.f, es3=0.f;
  int j0s = blockIdx.y*1024;
  for (int jt = 0; jt < 64; ++jt){
    int j0 = j0s + jt*16;
    f32x4 acc = {0.f,0.f,0.f,0.f};
    #pragma unroll
    for (int t = 0; t < 4; ++t){
      uint4 qb = *(const uint4*)(n2b + (long long)(j0+m)*CD + t*32 + kq*8);
      bf16x8 b = *(bf16x8*)&qb;
      acc = __builtin_amdgcn_mfma_f32_16x16x32_bf16(a[t], b, acc, 0, 0, 0);
    }
    es0 += __expf(acc[0]*2.0f);
    es1 += __expf(acc[1]*2.0f);
    es2 += __expf(acc[2]*2.0f);
    es3 += __expf(acc[3]*2.0f);
  }
  #pragma unroll
  for (int msk = 1; msk <= 8; msk <<= 1){
    es0 += __shfl_xor(es0, msk);
    es1 += __shfl_xor(es1, msk);
    es2 += __shfl_xor(es2, msk);
    es3 += __shfl_xor(es3, msk);
  }
  if (m == 0){
    int rb = i0 + kq*4;
    atomicAdd(&alls[rb+0], es0);
    atomicAdd(&alls[rb+1], es1);
    atomicAdd(&alls[rb+2], es2);
    atomicAdd(&alls[rb+3], es3);
  }
}

__global__ void k_logsum(const float* __restrict__ alls, float* __restrict__ misc){
  int i = blockIdx.x*256 + threadIdx.x;
  float v = logf(alls[i]);
  for (int off = 32; off > 0; off >>= 1) v += __shfl_down(v, off);
  if ((threadIdx.x & 63) == 0) atomicAdd(&misc[(i < CB) ? 13 : 15], v);
}

__global__ void k_final(const u16* __restrict__ emb, const int* __restrict__ idx,
                        const float* __restrict__ W, const float* __restrict__ bias,
                        const float* __restrict__ lg, const float* __restrict__ lb,
                        float* __restrict__ outp){
  __shared__ float A[8][128];
  __shared__ float red[8][4];
  int j = threadIdx.x;
  int r0 = blockIdx.x*8;
  for (int r = 0; r < 8; ++r){
    int g = idx[r0 + r];
    A[r][j] = bf2f(emb[(long long)g*CD + j]);
  }
  __syncthreads();
  float acc[8];
  #pragma unroll
  for (int r = 0; r < 8; ++r) acc[r] = 0.f;
  for (int k = 0; k < 128; k += 4){
    float w0 = W[(k+0)*128 + j];
    float w1 = W[(k+1)*128 + j];
    float w2 = W[(k+2)*128 + j];
    float w3 = W[(k+3)*128 + j];
    #pragma unroll
    for (int r = 0; r < 8; ++r){
      float4 a = *(const float4*)&A[r][k];
      acc[r] += a.x*w0 + a.y*w1 + a.z*w2 + a.w*w3;
    }
  }
  float bb = bias[j];
  #pragma unroll
  for (int r = 0; r < 8; ++r){
    float v = acc[r] + bb;
    acc[r] = (v < 0.f) ? 0.f : v;
  }
  int wid = j >> 6, lane = j & 63;
  #pragma unroll
  for (int r = 0; r < 8; ++r){
    float s = acc[r], q = acc[r]*acc[r];
    for (int off = 32; off > 0; off >>= 1){
      s += __shfl_down(s, off); q += __shfl_down(q, off);
    }
    if (lane == 0){ red[r][wid*2] = s; red[r][wid*2+1] = q; }
  }
  __syncthreads();
  float gg = lg[j], be = lb[j];
  #pragma unroll
  for (int r = 0; r < 8; ++r){
    float mu = (red[r][0] + red[r][2]) * (1.0f/128.0f);
    float ms = (red[r][1] + red[r][3]) * (1.0f/128.0f);
    float var = ms - mu*mu;
    float y = (acc[r] - mu) * rsqrtf(var + 1e-5f) * gg + be;
    outp[(long long)(r0 + r)*CD + j] = y;
  }
}

__global__ void k_loss(const float* __restrict__ misc, float* __restrict__ o){
  float lu = (misc[13] - misc[12]) * (1.0f/CB);
  float li = (misc[15] - misc[14]) * (1.0f/CB);
  o[0] = 0.4f*(lu + li);
}

extern "C" void kernel_launch(void* const* d_in, const int* in_sizes, int n_in,
                              void* d_out, int out_size, void* d_ws, size_t ws_size,
                              hipStream_t stream){
  (void)in_sizes; (void)n_in; (void)out_size; (void)ws_size;
  const float* feat_user = (const float*)d_in[0];
  const float* feat_item = (const float*)d_in[1];
  const float* u_W1 = (const float*)d_in[2];
  const float* u_b1 = (const float*)d_in[3];
  const float* u_W2 = (const float*)d_in[4];
  const float* i_W1 = (const float*)d_in[5];
  const float* i_b1 = (const float*)d_in[6];
  const float* i_W2 = (const float*)d_in[7];
  const float* user_W = (const float*)d_in[8];
  const float* user_b = (const float*)d_in[9];
  const float* item_W = (const float*)d_in[10];
  const float* item_b = (const float*)d_in[11];
  const float* ln_g = (const float*)d_in[12];
  const float* ln_b = (const float*)d_in[13];
  const int* ump0s = (const int*)d_in[14]; const int* ump0d = (const int*)d_in[15];
  const int* ump1s = (const int*)d_in[16]; const int* ump1d = (const int*)d_in[17];
  const int* imp0s = (const int*)d_in[18]; const int* imp0d = (const int*)d_in[19];
  const int* imp1s = (const int*)d_in[20]; const int* imp1d = (const int*)d_in[21];
  const int* ui_row = (const int*)d_in[22]; const int* ui_col = (const int*)d_in[23];
  const int* user_idx = (const int*)d_in[24]; const int* item_idx = (const int*)d_in[25];
  const int* neg_idx = (const int*)d_in[26];

  u16* W  = (u16*)d_ws;
  u16* fb = W;                      // 10,240,000 bf16
  u16* hu = W + 10240000LL;
  u16* hi = W + 15360000LL;
  u16* xb = W + 20480000LL;
  u16* x2 = W + 30720000LL;
  u16* z0 = W + 40960000LL;
  u16* z1 = W + 46080000LL;
  float* F   = (float*)(W + 51200000LL);
  float* rs  = F;                   // 320,000
  float* dinv= F + 320000;          // 80,000
  float* alls= F + 400000;          // 16,384
  float* misc= F + 416384;          // 64
  int* I     = (int*)(F + 416448);
  int* mp_p0 = I;                   // 40,001
  int* mp_p1 = I + 40001;           // 40,001
  int* mp_cur= I + 80002;           // 40,000
  int* mp_c0 = I + 120002;          // 640,000
  int* mp_c1 = I + 760002;          // 640,000
  int* scanb = I + 1400002;         // 64 (block partials)
  int* ui_ptr    = (int*)hu;        // overlay (hu/hi dead until first combine)
  int* ui_cursor = ui_ptr + 80001;
  int* ui_csr    = ui_cursor + 80000;
  u16* n1ub = xb;                   // overlay (xb dead after UI hop 3)
  u16* n2ub = xb + (long long)CB*CD;
  u16* n1ib = xb + 2LL*CB*CD;
  u16* n2ib = xb + 3LL*CB*CD;
  float* out = (float*)d_out;

  k_zero<<<(400000 + 255)/256, 256, 0, stream>>>(rs, 400000);
  k_zero<<<(16448 + 255)/256, 256, 0, stream>>>(alls, 16448);

  k_initb<<<40000, 256, 0, stream>>>(feat_user, feat_item, fb);

  k_deg<<<2500, 256, 0, stream>>>(ump0s, ump0d, rs + 0,      rs + 40000,  CEMP);
  k_deg<<<2500, 256, 0, stream>>>(ump1s, ump1d, rs + 80000,  rs + 120000, CEMP);
  k_deg<<<2500, 256, 0, stream>>>(imp0s, imp0d, rs + 160000, rs + 200000, CEMP);
  k_deg<<<2500, 256, 0, stream>>>(imp1s, imp1d, rs + 240000, rs + 280000, CEMP);
  k_rs<<<1250, 256, 0, stream>>>(rs, 320000);
  k_degui<<<6250, 256, 0, stream>>>(ui_row, dinv, CEUI);
  k_dinv<<<(CNN + 255)/256, 256, 0, stream>>>(dinv, CNN);

  // UI CSR build (hierarchical scan; 80000 -> 40 tiles)
  k_izero<<<(80000 + 255)/256, 256, 0, stream>>>(ui_cursor, 80000);
  k_hist<<<6250, 256, 0, stream>>>(ui_row, ui_cursor, CEUI);
  k_scan_part<<<40, 256, 0, stream>>>(ui_cursor, scanb, 80000);
  k_scan_top<<<1, 64, 0, stream>>>(scanb, 40);
  k_scan_down<<<40, 256, 0, stream>>>(ui_cursor, scanb, ui_ptr, 80000, CEUI);
  k_fill<<<6250, 256, 0, stream>>>(ui_col, ui_row, ui_cursor, ui_csr, CEUI);

  // UI propagation: fb -> x2 -> xb -> x2
  k_gather_ui<<<20000, 256, 0, stream>>>(fb, ui_ptr, ui_csr, dinv, x2, CNN);
  k_gather_ui<<<20000, 256, 0, stream>>>(x2, ui_ptr, ui_csr, dinv, xb, CNN);
  k_gather_ui<<<20000, 256, 0, stream>>>(xb, ui_ptr, ui_csr, dinv, x2, CNN);

  // HAN user CSRs (40000 -> 20 tiles)
  k_izero<<<(40000 + 255)/256, 256, 0, stream>>>(mp_cur, 40000);
  k_hist<<<2500, 256, 0, stream>>>(ump0d, mp_cur, CEMP);
  k_scan_part<<<20, 256, 0, stream>>>(mp_cur, scanb, 40000);
  k_scan_top<<<1, 64, 0, stream>>>(scanb, 20);
  k_scan_down<<<20, 256, 0, stream>>>(mp_cur, scanb, mp_p0, 40000, CEMP);
  k_fill<<<2500, 256, 0, stream>>>(ump0s, ump0d, mp_cur, mp_c0, CEMP);
  k_izero<<<(40000 + 255)/256, 256, 0, stream>>>(mp_cur, 40000);
  k_hist<<<2500, 256, 0, stream>>>(ump1d, mp_cur, CEMP);
  k_scan_part<<<20, 256, 0, stream>>>(mp_cur, scanb, 40000);
  k_scan_top<<<1, 64, 0, stream>>>(scanb, 20);
  k_scan_down<<<20, 256, 0, stream>>>(mp_cur, scanb, mp_p1, 40000, CEMP);
  k_fill<<<2500, 256, 0, stream>>>(ump1s, ump1d, mp_cur, mp_c1, CEMP);
  for (int L = 0; L < 3; ++L){
    const u16* hin = (L == 0) ? fb : hu;
    k_gather_mp<<<10000, 256, 0, stream>>>(hin, mp_p0, mp_c0, rs + 0,     z0, CNU);
    k_gather_mp<<<10000, 256, 0, stream>>>(hin, mp_p1, mp_c1, rs + 80000, z1, CNU);
    k_att<<<5000, 128, 0, stream>>>(z0, z1, rs + 40000, rs + 120000,
                                    u_W1, u_b1, u_W2, misc + 2*L, CNU);
    k_combine<<<20000, 256, 0, stream>>>(z0, z1, rs + 40000, rs + 120000,
                                         misc + 2*L, hu, CNU);
  }
  // HAN item CSRs
  k_izero<<<(40000 + 255)/256, 256, 0, stream>>>(mp_cur, 40000);
  k_hist<<<2500, 256, 0, stream>>>(imp0d, mp_cur, CEMP);
  k_scan_part<<<20, 256, 0, stream>>>(mp_cur, scanb, 40000);
  k_scan_top<<<1, 64, 0, stream>>>(scanb, 20);
  k_scan_down<<<20, 256, 0, stream>>>(mp_cur, scanb, mp_p0, 40000, CEMP);
  k_fill<<<2500, 256, 0, stream>>>(imp0s, imp0d, mp_cur, mp_c0, CEMP);
  k_izero<<<(40000 + 255)/256, 256, 0, stream>>>(mp_cur, 40000);
  k_hist<<<2500, 256, 0, stream>>>(imp1d, mp_cur, CEMP);
  k_scan_part<<<20, 256, 0, stream>>>(mp_cur, scanb, 40000);
  k_scan_top<<<1, 64, 0, stream>>>(scanb, 20);
  k_scan_down<<<20, 256, 0, stream>>>(mp_cur, scanb, mp_p1, 40000, CEMP);
  k_fill<<<2500, 256, 0, stream>>>(imp1s, imp1d, mp_cur, mp_c1, CEMP);
  for (int L = 0; L < 3; ++L){
    const u16* hin = (L == 0) ? (fb + (long long)CNU*CD) : hi;
    k_gather_mp<<<10000, 256, 0, stream>>>(hin, mp_p0, mp_c0, rs + 160000, z0, CNU);
    k_gather_mp<<<10000, 256, 0, stream>>>(hin, mp_p1, mp_c1, rs + 240000, z1, CNU);
    k_att<<<5000, 128, 0, stream>>>(z0, z1, rs + 200000, rs + 280000,
                                    i_W1, i_b1, i_W2, misc + 6 + 2*L, CNU);
    k_combine<<<20000, 256, 0, stream>>>(z0, z1, rs + 200000, rs + 280000,
                                         misc + 6 + 2*L, hi, CNU);
  }

  k_emb<<<40000, 256, 0, stream>>>(x2, hu, hi);

  // SSL
  k_sslnorm<<<CB/4, 256, 0, stream>>>(x2, hu, user_idx, 0,   n1ub, n2ub, misc + 12);
  k_sslnorm<<<CB/4, 256, 0, stream>>>(x2, hi, item_idx, CNU, n1ib, n2ib, misc + 14);
  k_alls<<<dim3(128, 8), 256, 0, stream>>>(n1ub, n2ub, alls);
  k_alls<<<dim3(128, 8), 256, 0, stream>>>(n1ib, n2ib, alls + CB);
  k_logsum<<<64, 256, 0, stream>>>(alls, misc);

  k_final<<<1024, 128, 0, stream>>>(hu, user_idx, user_W, user_b, ln_g, ln_b, out);
  k_final<<<1024, 128, 0, stream>>>(hi, item_idx, item_W, item_b, ln_g, ln_b, out + (long long)CB*CD);
  k_final<<<1024, 128, 0, stream>>>(hi, neg_idx,  item_W, item_b, ln_g, ln_b, out + 2LL*CB*CD);
  k_loss<<<1, 1, 0, stream>>>(misc, out + 3LL*CB*CD);
}

// Round 10
// 2520.676 us; speedup vs baseline: 9.4105x; 1.1574x over previous
//
#include <hip/hip_runtime.h>
#include <math.h>

typedef unsigned short u16;
typedef unsigned int u32;
typedef __attribute__((ext_vector_type(8))) short bf16x8;
typedef __attribute__((ext_vector_type(4))) float f32x4;

#define CNU 40000
#define CNN 80000
#define CD  128
#define CEMP 640000
#define CEUI 1600000
#define CB  8192
#define STILE 2048

__device__ __forceinline__ float bf2f(u16 b){
  union { u32 u; float f; } v; v.u = ((u32)b) << 16; return v.f;
}
__device__ __forceinline__ u16 f2bf(float f){
  union { float f; u32 u; } v; v.f = f;
  u32 u = v.u + 0x7FFFu + ((v.u >> 16) & 1u);
  return (u16)(u >> 16);
}
__device__ __forceinline__ float lo16f(u32 q){ union { u32 u; float f; } v; v.u = q << 16; return v.f; }
__device__ __forceinline__ float hi16f(u32 q){ union { u32 u; float f; } v; v.u = q & 0xFFFF0000u; return v.f; }

__global__ void k_zero(float* __restrict__ p, long long n){
  long long i = (long long)blockIdx.x*256 + threadIdx.x;
  if (i < n) p[i] = 0.f;
}

__global__ void k_izero(int* __restrict__ p, int n){
  int i = blockIdx.x*256 + threadIdx.x;
  if (i < n) p[i] = 0;
}

__global__ void k_initb(const float* __restrict__ fu, const float* __restrict__ fi,
                        u16* __restrict__ fb){
  int idx = blockIdx.x*256 + threadIdx.x;
  if (idx >= CNN*CD) return;
  float v = (idx < CNU*CD) ? fu[idx] : fi[idx - CNU*CD];
  fb[idx] = f2bf(v);
}

// transpose W1 (f32 [k][j]) -> bf16 [j][k] for MFMA B-operand loads
__global__ void k_w1t(const float* __restrict__ Wu, const float* __restrict__ Wi,
                      u16* __restrict__ Wut, u16* __restrict__ Wit){
  int idx = blockIdx.x*256 + threadIdx.x;
  if (idx >= 16384) return;
  int k = idx >> 7, j = idx & 127;
  Wut[j*128 + k] = f2bf(Wu[idx]);
  Wit[j*128 + k] = f2bf(Wi[idx]);
}

__global__ void k_deg(const int* __restrict__ src, const int* __restrict__ dst,
                      float* __restrict__ dego, float* __restrict__ degi, int E){
  int e = blockIdx.x*256 + threadIdx.x;
  if (e >= E) return;
  atomicAdd(&dego[src[e]], 1.0f);
  atomicAdd(&degi[dst[e]], 1.0f);
}

__global__ void k_rs(float* __restrict__ d, int n){
  int i = blockIdx.x*256 + threadIdx.x;
  if (i >= n) return;
  float v = d[i];
  v = (v > 1.0f) ? v : 1.0f;
  d[i] = rsqrtf(v);
}

__global__ void k_degui(const int* __restrict__ row, float* __restrict__ deg, int E){
  int e = blockIdx.x*256 + threadIdx.x;
  if (e >= E) return;
  atomicAdd(&deg[row[e]], 1.0f);
}

__global__ void k_dinv(float* __restrict__ d, int n){
  int i = blockIdx.x*256 + threadIdx.x;
  if (i >= n) return;
  float v = d[i];
  d[i] = (v > 0.f) ? rsqrtf(v) : 0.f;
}

// ---- CSR build ----
__global__ void k_hist(const int* __restrict__ dst, int* __restrict__ hist, int E){
  int e = blockIdx.x*256 + threadIdx.x;
  if (e >= E) return;
  atomicAdd(&hist[dst[e]], 1);
}

__global__ void k_scan_part(const int* __restrict__ hist, int* __restrict__ part, int n){
  int base = blockIdx.x*STILE + threadIdx.x*8;
  int s = 0;
  #pragma unroll
  for (int u = 0; u < 8; ++u){
    int i = base + u;
    if (i < n) s += hist[i];
  }
  for (int off = 32; off > 0; off >>= 1) s += __shfl_down(s, off);
  __shared__ int wsum[4];
  if ((threadIdx.x & 63) == 0) wsum[threadIdx.x >> 6] = s;
  __syncthreads();
  if (threadIdx.x == 0) part[blockIdx.x] = wsum[0] + wsum[1] + wsum[2] + wsum[3];
}

__global__ void k_scan_top(int* __restrict__ part, int nb){
  int t = threadIdx.x;
  int orig = (t < nb) ? part[t] : 0;
  int v = orig;
  #pragma unroll
  for (int off = 1; off < 64; off <<= 1){
    int u = __shfl_up(v, off);
    if (t >= off) v += u;
  }
  if (t < nb) part[t] = v - orig;
}

__global__ void k_scan_down(int* __restrict__ hist_cursor, const int* __restrict__ part,
                            int* __restrict__ ptr, int n, int total){
  int b = blockIdx.x, t = threadIdx.x;
  int base = b*STILE + t*8;
  int v[8]; int s = 0;
  #pragma unroll
  for (int u = 0; u < 8; ++u){
    int i = base + u;
    v[u] = (i < n) ? hist_cursor[i] : 0;
    s += v[u];
  }
  int lane = t & 63, wv = t >> 6;
  int inc = s;
  #pragma unroll
  for (int off = 1; off < 64; off <<= 1){
    int u = __shfl_up(inc, off);
    if (lane >= off) inc += u;
  }
  __shared__ int wsum[4];
  if (lane == 63) wsum[wv] = inc;
  __syncthreads();
  int woff = 0;
  for (int wq = 0; wq < wv; ++wq) woff += wsum[wq];
  int excl = part[b] + woff + (inc - s);
  #pragma unroll
  for (int u = 0; u < 8; ++u){
    int i = base + u;
    if (i < n){ ptr[i] = excl; hist_cursor[i] = excl; excl += v[u]; }
  }
  if (b == 0 && t == 0) ptr[n] = total;
}

__global__ void k_fill(const int* __restrict__ src, const int* __restrict__ dst,
                       int* __restrict__ cursor, int* __restrict__ csr_src, int E){
  int e = blockIdx.x*256 + threadIdx.x;
  if (e >= E) return;
  int p = atomicAdd(&cursor[dst[e]], 1);
  csr_src[p] = src[e];
}

// ---- gather: 1 wave/row, lane=(g=edge-slot 0..3, c=16B-chunk 0..15) ----
__global__ void k_gather_mp(const u16* __restrict__ h, const int* __restrict__ ptr,
                            const int* __restrict__ csr_src, const float* __restrict__ rso,
                            u16* __restrict__ z, int n){
  int row = (blockIdx.x*256 + threadIdx.x) >> 6;
  if (row >= n) return;
  int lane = threadIdx.x & 63;
  int g = lane >> 4, c = lane & 15;
  int p = ptr[row], pe = ptr[row+1];
  float a0=0,a1=0,a2=0,a3=0,a4=0,a5=0,a6=0,a7=0;
  const u16* hb = h + (long long)c*8;
  while (p < pe){
    uint4 q[4]; float w[4];
    #pragma unroll
    for (int u = 0; u < 4; ++u){
      int ei = p + u*4 + g;
      int s  = (ei < pe) ? csr_src[ei] : 0;
      w[u]   = (ei < pe) ? rso[s] : 0.f;
      q[u]   = *(const uint4*)(hb + (long long)s*CD);
    }
    #pragma unroll
    for (int u = 0; u < 4; ++u){
      a0 += lo16f(q[u].x)*w[u]; a1 += hi16f(q[u].x)*w[u];
      a2 += lo16f(q[u].y)*w[u]; a3 += hi16f(q[u].y)*w[u];
      a4 += lo16f(q[u].z)*w[u]; a5 += hi16f(q[u].z)*w[u];
      a6 += lo16f(q[u].w)*w[u]; a7 += hi16f(q[u].w)*w[u];
    }
    p += 16;
  }
  #pragma unroll
  for (int m = 16; m <= 32; m <<= 1){
    a0 += __shfl_xor(a0, m); a1 += __shfl_xor(a1, m);
    a2 += __shfl_xor(a2, m); a3 += __shfl_xor(a3, m);
    a4 += __shfl_xor(a4, m); a5 += __shfl_xor(a5, m);
    a6 += __shfl_xor(a6, m); a7 += __shfl_xor(a7, m);
  }
  if (g == 0){
    uint4 o;
    o.x = (u32)f2bf(a0) | ((u32)f2bf(a1) << 16);
    o.y = (u32)f2bf(a2) | ((u32)f2bf(a3) << 16);
    o.z = (u32)f2bf(a4) | ((u32)f2bf(a5) << 16);
    o.w = (u32)f2bf(a6) | ((u32)f2bf(a7) << 16);
    *(uint4*)(z + (long long)row*CD + c*8) = o;
  }
}

__global__ void k_gather_ui(const u16* __restrict__ xin, const int* __restrict__ ptr,
                            const int* __restrict__ csr_src, const float* __restrict__ dinv,
                            u16* __restrict__ xout, int n){
  int row = (blockIdx.x*256 + threadIdx.x) >> 6;
  if (row >= n) return;
  int lane = threadIdx.x & 63;
  int g = lane >> 4, c = lane & 15;
  int p = ptr[row], pe = ptr[row+1];
  float a0=0,a1=0,a2=0,a3=0,a4=0,a5=0,a6=0,a7=0;
  const u16* hb = xin + (long long)c*8;
  while (p < pe){
    uint4 q[4]; float w[4];
    #pragma unroll
    for (int u = 0; u < 4; ++u){
      int ei = p + u*4 + g;
      int s  = (ei < pe) ? csr_src[ei] : 0;
      w[u]   = (ei < pe) ? dinv[s] : 0.f;
      q[u]   = *(const uint4*)(hb + (long long)s*CD);
    }
    #pragma unroll
    for (int u = 0; u < 4; ++u){
      a0 += lo16f(q[u].x)*w[u]; a1 += hi16f(q[u].x)*w[u];
      a2 += lo16f(q[u].y)*w[u]; a3 += hi16f(q[u].y)*w[u];
      a4 += lo16f(q[u].z)*w[u]; a5 += hi16f(q[u].z)*w[u];
      a6 += lo16f(q[u].w)*w[u]; a7 += hi16f(q[u].w)*w[u];
    }
    p += 16;
  }
  #pragma unroll
  for (int m = 16; m <= 32; m <<= 1){
    a0 += __shfl_xor(a0, m); a1 += __shfl_xor(a1, m);
    a2 += __shfl_xor(a2, m); a3 += __shfl_xor(a3, m);
    a4 += __shfl_xor(a4, m); a5 += __shfl_xor(a5, m);
    a6 += __shfl_xor(a6, m); a7 += __shfl_xor(a7, m);
  }
  if (g == 0){
    float wd = dinv[row];
    uint4 o;
    o.x = (u32)f2bf(a0*wd) | ((u32)f2bf(a1*wd) << 16);
    o.y = (u32)f2bf(a2*wd) | ((u32)f2bf(a3*wd) << 16);
    o.z = (u32)f2bf(a4*wd) | ((u32)f2bf(a5*wd) << 16);
    o.w = (u32)f2bf(a6*wd) | ((u32)f2bf(a7*wd) << 16);
    *(uint4*)(xout + (long long)row*CD + c*8) = o;
  }
}

// semantic attention scores via MFMA: s_out[ch] += sum_rows sum_j tanh(rsi*(z@W1)+b1)_j * W2_j
// grid = 2*(n/64) blocks x 256 thr; first n/64 blocks = channel 0 (z0), rest channel 1.
__global__ void k_att(const u16* __restrict__ z0, const u16* __restrict__ z1,
                      const float* __restrict__ rsi0, const float* __restrict__ rsi1,
                      const u16* __restrict__ W1T, const float* __restrict__ b1,
                      const float* __restrict__ W2, float* __restrict__ s_out, int n){
  int nb = n >> 6;
  int blk = blockIdx.x;
  int ch = (blk >= nb) ? 1 : 0;
  int rb = (ch ? (blk - nb) : blk) * 64;
  const u16* z = ch ? z1 : z0;
  const float* rsi = ch ? rsi1 : rsi0;
  int wv = threadIdx.x >> 6, lane = threadIdx.x & 63;
  int i0 = rb + wv*16;
  int m = lane & 15, kq = lane >> 4;
  bf16x8 a[4];
  #pragma unroll
  for (int t = 0; t < 4; ++t){
    uint4 q = *(const uint4*)(z + (long long)(i0+m)*CD + t*32 + kq*8);
    a[t] = *(bf16x8*)&q;
  }
  float rsv[4];
  #pragma unroll
  for (int ri = 0; ri < 4; ++ri) rsv[ri] = rsi[i0 + kq*4 + ri];
  float psum = 0.f;
  #pragma unroll
  for (int jt = 0; jt < 8; ++jt){
    f32x4 acc = {0.f,0.f,0.f,0.f};
    #pragma unroll
    for (int t = 0; t < 4; ++t){
      uint4 qb = *(const uint4*)(W1T + (jt*16 + m)*CD + t*32 + kq*8);
      bf16x8 b = *(bf16x8*)&qb;
      acc = __builtin_amdgcn_mfma_f32_16x16x32_bf16(a[t], b, acc, 0, 0, 0);
    }
    int j = jt*16 + m;
    float bb = b1[j], w2 = W2[j];
    #pragma unroll
    for (int ri = 0; ri < 4; ++ri){
      float x = acc[ri]*rsv[ri] + bb;
      x = fminf(fmaxf(x, -15.f), 15.f);
      float t2 = __expf(2.f*x);
      psum += ((t2 - 1.f)/(t2 + 1.f))*w2;
    }
  }
  #pragma unroll
  for (int msk = 1; msk <= 32; msk <<= 1) psum += __shfl_xor(psum, msk);
  if (lane == 0) atomicAdd(&s_out[ch], psum);
}

__global__ void k_combine(const u16* __restrict__ z0, const u16* __restrict__ z1,
                          const float* __restrict__ rsi0, const float* __restrict__ rsi1,
                          const float* __restrict__ s, u16* __restrict__ h, int n){
  int idx = blockIdx.x*256 + threadIdx.x;
  if (idx >= n*CD) return;
  int v = idx >> 7;
  float s0 = s[0]*(1.0f/n), s1 = s[1]*(1.0f/n);
  float m = fmaxf(s0, s1);
  float e0 = __expf(s0 - m), e1 = __expf(s1 - m);
  float r = 1.0f/(e0 + e1);
  h[idx] = f2bf((e0*r)*bf2f(z0[idx])*rsi0[v] + (e1*r)*bf2f(z1[idx])*rsi1[v]);
}

__global__ void k_emb(const u16* __restrict__ x2, u16* __restrict__ h_u,
                      u16* __restrict__ h_i){
  int idx = blockIdx.x*256 + threadIdx.x;
  if (idx >= CNN*CD) return;
  if (idx < CNU*CD) h_u[idx] = f2bf(0.5f*bf2f(h_u[idx]) + 0.5f*bf2f(x2[idx]));
  else { int k = idx - CNU*CD; h_i[k] = f2bf(0.5f*bf2f(h_i[k]) + 0.5f*bf2f(x2[idx])); }
}

__global__ void k_sslnorm(const u16* __restrict__ xui, const u16* __restrict__ hemb,
                          const int* __restrict__ idx, int rowoff,
                          u16* __restrict__ n1b, u16* __restrict__ n2b,
                          float* __restrict__ pos_acc){
  int r = blockIdx.x*4 + (threadIdx.x >> 6);
  int lane = threadIdx.x & 63;
  if (r >= CB) return;
  int g = idx[r];
  const u16* e1 = xui + (long long)(g + rowoff)*CD;
  const u16* e2 = hemb + (long long)g*CD;
  float a0 = bf2f(e1[lane]), a1 = bf2f(e1[lane+64]);
  float b0 = bf2f(e2[lane]), b1 = bf2f(e2[lane+64]);
  float s1 = a0*a0 + a1*a1, s2 = b0*b0 + b1*b1, s12 = a0*b0 + a1*b1;
  for (int off = 32; off > 0; off >>= 1){
    s1  += __shfl_down(s1, off);
    s2  += __shfl_down(s2, off);
    s12 += __shfl_down(s12, off);
  }
  s1 = __shfl(s1, 0); s2 = __shfl(s2, 0); s12 = __shfl(s12, 0);
  float i1 = 1.0f / fmaxf(sqrtf(s1), 1e-12f);
  float i2 = 1.0f / fmaxf(sqrtf(s2), 1e-12f);
  u16* o1 = n1b + (long long)r*CD;
  u16* o2 = n2b + (long long)r*CD;
  o1[lane] = f2bf(a0*i1); o1[lane+64] = f2bf(a1*i1);
  o2[lane] = f2bf(b0*i2); o2[lane+64] = f2bf(b1*i2);
  if (lane == 0) atomicAdd(pos_acc, s12*i1*i2*2.0f);
}

// alls[i] += sum_j exp(2 * n1_i . n2_j) via MFMA; 4 j-tiles in flight (independent acc chains).
__global__ void k_alls(const u16* __restrict__ n1b, const u16* __restrict__ n2b,
                       float* __restrict__ alls){
  int wv = threadIdx.x >> 6;
  int lane = threadIdx.x & 63;
  int i0 = (blockIdx.x*4 + wv)*16;
  int m = lane & 15, kq = lane >> 4;
  bf16x8 a[4];
  #pragma unroll
  for (int t = 0; t < 4; ++t){
    uint4 q = *(const uint4*)(n1b + (long long)(i0+m)*CD + t*32 + kq*8);
    a[t] = *(bf16x8*)&q;
  }
  float es0=0.f, es1=0.f, es2=0.f, es3=0.f;
  int j0s = blockIdx.y*1024;
  for (int jt = 0; jt < 64; jt += 4){
    f32x4 ac0 = {0.f,0.f,0.f,0.f}, ac1 = ac0, ac2 = ac0, ac3 = ac0;
    const u16* base0 = n2b + (long long)(j0s + (jt+0)*16 + m)*CD + kq*8;
    const u16* base1 = n2b + (long long)(j0s + (jt+1)*16 + m)*CD + kq*8;
    const u16* base2 = n2b + (long long)(j0s + (jt+2)*16 + m)*CD + kq*8;
    const u16* base3 = n2b + (long long)(j0s + (jt+3)*16 + m)*CD + kq*8;
    #pragma unroll
    for (int t = 0; t < 4; ++t){
      uint4 q0 = *(const uint4*)(base0 + t*32);
      uint4 q1 = *(const uint4*)(base1 + t*32);
      uint4 q2 = *(const uint4*)(base2 + t*32);
      uint4 q3 = *(const uint4*)(base3 + t*32);
      ac0 = __builtin_amdgcn_mfma_f32_16x16x32_bf16(a[t], *(bf16x8*)&q0, ac0, 0, 0, 0);
      ac1 = __builtin_amdgcn_mfma_f32_16x16x32_bf16(a[t], *(bf16x8*)&q1, ac1, 0, 0, 0);
      ac2 = __builtin_amdgcn_mfma_f32_16x16x32_bf16(a[t], *(bf16x8*)&q2, ac2, 0, 0, 0);
      ac3 = __builtin_amdgcn_mfma_f32_16x16x32_bf16(a[t], *(bf16x8*)&q3, ac3, 0, 0, 0);
    }
    es0 += __expf(ac0[0]*2.f) + __expf(ac1[0]*2.f) + __expf(ac2[0]*2.f) + __expf(ac3[0]*2.f);
    es1 += __expf(ac0[1]*2.f) + __expf(ac1[1]*2.f) + __expf(ac2[1]*2.f) + __expf(ac3[1]*2.f);
    es2 += __expf(ac0[2]*2.f) + __expf(ac1[2]*2.f) + __expf(ac2[2]*2.f) + __expf(ac3[2]*2.f);
    es3 += __expf(ac0[3]*2.f) + __expf(ac1[3]*2.f) + __expf(ac2[3]*2.f) + __expf(ac3[3]*2.f);
  }
  #pragma unroll
  for (int msk = 1; msk <= 8; msk <<= 1){
    es0 += __shfl_xor(es0, msk);
    es1 += __shfl_xor(es1, msk);
    es2 += __shfl_xor(es2, msk);
    es3 += __shfl_xor(es3, msk);
  }
  if (m == 0){
    int rb = i0 + kq*4;
    atomicAdd(&alls[rb+0], es0);
    atomicAdd(&alls[rb+1], es1);
    atomicAdd(&alls[rb+2], es2);
    atomicAdd(&alls[rb+3], es3);
  }
}

__global__ void k_logsum(const float* __restrict__ alls, float* __restrict__ misc){
  int i = blockIdx.x*256 + threadIdx.x;
  float v = logf(alls[i]);
  for (int off = 32; off > 0; off >>= 1) v += __shfl_down(v, off);
  if ((threadIdx.x & 63) == 0) atomicAdd(&misc[(i < CB) ? 13 : 15], v);
}

__global__ void k_final(const u16* __restrict__ emb, const int* __restrict__ idx,
                        const float* __restrict__ W, const float* __restrict__ bias,
                        const float* __restrict__ lg, const float* __restrict__ lb,
                        float* __restrict__ outp){
  __shared__ float A[8][128];
  __shared__ float red[8][4];
  int j = threadIdx.x;
  int r0 = blockIdx.x*8;
  for (int r = 0; r < 8; ++r){
    int g = idx[r0 + r];
    A[r][j] = bf2f(emb[(long long)g*CD + j]);
  }
  __syncthreads();
  float acc[8];
  #pragma unroll
  for (int r = 0; r < 8; ++r) acc[r] = 0.f;
  for (int k = 0; k < 128; k += 4){
    float w0 = W[(k+0)*128 + j];
    float w1 = W[(k+1)*128 + j];
    float w2 = W[(k+2)*128 + j];
    float w3 = W[(k+3)*128 + j];
    #pragma unroll
    for (int r = 0; r < 8; ++r){
      float4 a = *(const float4*)&A[r][k];
      acc[r] += a.x*w0 + a.y*w1 + a.z*w2 + a.w*w3;
    }
  }
  float bb = bias[j];
  #pragma unroll
  for (int r = 0; r < 8; ++r){
    float v = acc[r] + bb;
    acc[r] = (v < 0.f) ? 0.f : v;
  }
  int wid = j >> 6, lane = j & 63;
  #pragma unroll
  for (int r = 0; r < 8; ++r){
    float s = acc[r], q = acc[r]*acc[r];
    for (int off = 32; off > 0; off >>= 1){
      s += __shfl_down(s, off); q += __shfl_down(q, off);
    }
    if (lane == 0){ red[r][wid*2] = s; red[r][wid*2+1] = q; }
  }
  __syncthreads();
  float gg = lg[j], be = lb[j];
  #pragma unroll
  for (int r = 0; r < 8; ++r){
    float mu = (red[r][0] + red[r][2]) * (1.0f/128.0f);
    float ms = (red[r][1] + red[r][3]) * (1.0f/128.0f);
    float var = ms - mu*mu;
    float y = (acc[r] - mu) * rsqrtf(var + 1e-5f) * gg + be;
    outp[(long long)(r0 + r)*CD + j] = y;
  }
}

__global__ void k_loss(const float* __restrict__ misc, float* __restrict__ o){
  float lu = (misc[13] - misc[12]) * (1.0f/CB);
  float li = (misc[15] - misc[14]) * (1.0f/CB);
  o[0] = 0.4f*(lu + li);
}

extern "C" void kernel_launch(void* const* d_in, const int* in_sizes, int n_in,
                              void* d_out, int out_size, void* d_ws, size_t ws_size,
                              hipStream_t stream){
  (void)in_sizes; (void)n_in; (void)out_size; (void)ws_size;
  const float* feat_user = (const float*)d_in[0];
  const float* feat_item = (const float*)d_in[1];
  const float* u_W1 = (const float*)d_in[2];
  const float* u_b1 = (const float*)d_in[3];
  const float* u_W2 = (const float*)d_in[4];
  const float* i_W1 = (const float*)d_in[5];
  const float* i_b1 = (const float*)d_in[6];
  const float* i_W2 = (const float*)d_in[7];
  const float* user_W = (const float*)d_in[8];
  const float* user_b = (const float*)d_in[9];
  const float* item_W = (const float*)d_in[10];
  const float* item_b = (const float*)d_in[11];
  const float* ln_g = (const float*)d_in[12];
  const float* ln_b = (const float*)d_in[13];
  const int* ump0s = (const int*)d_in[14]; const int* ump0d = (const int*)d_in[15];
  const int* ump1s = (const int*)d_in[16]; const int* ump1d = (const int*)d_in[17];
  const int* imp0s = (const int*)d_in[18]; const int* imp0d = (const int*)d_in[19];
  const int* imp1s = (const int*)d_in[20]; const int* imp1d = (const int*)d_in[21];
  const int* ui_row = (const int*)d_in[22]; const int* ui_col = (const int*)d_in[23];
  const int* user_idx = (const int*)d_in[24]; const int* item_idx = (const int*)d_in[25];
  const int* neg_idx = (const int*)d_in[26];

  u16* W  = (u16*)d_ws;
  u16* fb = W;                      // 10,240,000 bf16
  u16* hu = W + 10240000LL;
  u16* hi = W + 15360000LL;
  u16* xb = W + 20480000LL;
  u16* x2 = W + 30720000LL;
  u16* z0 = W + 40960000LL;
  u16* z1 = W + 46080000LL;
  float* F   = (float*)(W + 51200000LL);
  float* rs  = F;                   // 320,000
  float* dinv= F + 320000;          // 80,000
  float* alls= F + 400000;          // 16,384
  float* misc= F + 416384;          // 64
  int* I     = (int*)(F + 416448);
  int* mp_p0 = I;                   // 40,001
  int* mp_p1 = I + 40001;           // 40,001
  int* mp_cur= I + 80002;           // 40,000
  int* mp_c0 = I + 120002;          // 640,000
  int* mp_c1 = I + 760002;          // 640,000
  int* scanb = I + 1400002;         // 64
  u16* w1tu  = (u16*)(I + 1400128); // 16,384 bf16 (W1^T user)
  u16* w1ti  = w1tu + 16384;        // 16,384 bf16 (W1^T item)
  int* ui_ptr    = (int*)hu;        // overlay (hu/hi dead until first combine)
  int* ui_cursor = ui_ptr + 80001;
  int* ui_csr    = ui_cursor + 80000;
  u16* n1ub = xb;                   // overlay (xb dead after UI hop 3)
  u16* n2ub = xb + (long long)CB*CD;
  u16* n1ib = xb + 2LL*CB*CD;
  u16* n2ib = xb + 3LL*CB*CD;
  float* out = (float*)d_out;

  k_zero<<<(400000 + 255)/256, 256, 0, stream>>>(rs, 400000);
  k_zero<<<(16448 + 255)/256, 256, 0, stream>>>(alls, 16448);

  k_initb<<<40000, 256, 0, stream>>>(feat_user, feat_item, fb);
  k_w1t<<<64, 256, 0, stream>>>(u_W1, i_W1, w1tu, w1ti);

  k_deg<<<2500, 256, 0, stream>>>(ump0s, ump0d, rs + 0,      rs + 40000,  CEMP);
  k_deg<<<2500, 256, 0, stream>>>(ump1s, ump1d, rs + 80000,  rs + 120000, CEMP);
  k_deg<<<2500, 256, 0, stream>>>(imp0s, imp0d, rs + 160000, rs + 200000, CEMP);
  k_deg<<<2500, 256, 0, stream>>>(imp1s, imp1d, rs + 240000, rs + 280000, CEMP);
  k_rs<<<1250, 256, 0, stream>>>(rs, 320000);
  k_degui<<<6250, 256, 0, stream>>>(ui_row, dinv, CEUI);
  k_dinv<<<(CNN + 255)/256, 256, 0, stream>>>(dinv, CNN);

  // UI CSR build
  k_izero<<<(80000 + 255)/256, 256, 0, stream>>>(ui_cursor, 80000);
  k_hist<<<6250, 256, 0, stream>>>(ui_row, ui_cursor, CEUI);
  k_scan_part<<<40, 256, 0, stream>>>(ui_cursor, scanb, 80000);
  k_scan_top<<<1, 64, 0, stream>>>(scanb, 40);
  k_scan_down<<<40, 256, 0, stream>>>(ui_cursor, scanb, ui_ptr, 80000, CEUI);
  k_fill<<<6250, 256, 0, stream>>>(ui_col, ui_row, ui_cursor, ui_csr, CEUI);

  // UI propagation: fb -> x2 -> xb -> x2
  k_gather_ui<<<20000, 256, 0, stream>>>(fb, ui_ptr, ui_csr, dinv, x2, CNN);
  k_gather_ui<<<20000, 256, 0, stream>>>(x2, ui_ptr, ui_csr, dinv, xb, CNN);
  k_gather_ui<<<20000, 256, 0, stream>>>(xb, ui_ptr, ui_csr, dinv, x2, CNN);

  // HAN user CSRs
  k_izero<<<(40000 + 255)/256, 256, 0, stream>>>(mp_cur, 40000);
  k_hist<<<2500, 256, 0, stream>>>(ump0d, mp_cur, CEMP);
  k_scan_part<<<20, 256, 0, stream>>>(mp_cur, scanb, 40000);
  k_scan_top<<<1, 64, 0, stream>>>(scanb, 20);
  k_scan_down<<<20, 256, 0, stream>>>(mp_cur, scanb, mp_p0, 40000, CEMP);
  k_fill<<<2500, 256, 0, stream>>>(ump0s, ump0d, mp_cur, mp_c0, CEMP);
  k_izero<<<(40000 + 255)/256, 256, 0, stream>>>(mp_cur, 40000);
  k_hist<<<2500, 256, 0, stream>>>(ump1d, mp_cur, CEMP);
  k_scan_part<<<20, 256, 0, stream>>>(mp_cur, scanb, 40000);
  k_scan_top<<<1, 64, 0, stream>>>(scanb, 20);
  k_scan_down<<<20, 256, 0, stream>>>(mp_cur, scanb, mp_p1, 40000, CEMP);
  k_fill<<<2500, 256, 0, stream>>>(ump1s, ump1d, mp_cur, mp_c1, CEMP);
  for (int L = 0; L < 3; ++L){
    const u16* hin = (L == 0) ? fb : hu;
    k_gather_mp<<<10000, 256, 0, stream>>>(hin, mp_p0, mp_c0, rs + 0,     z0, CNU);
    k_gather_mp<<<10000, 256, 0, stream>>>(hin, mp_p1, mp_c1, rs + 80000, z1, CNU);
    k_att<<<1250, 256, 0, stream>>>(z0, z1, rs + 40000, rs + 120000,
                                    w1tu, u_b1, u_W2, misc + 2*L, CNU);
    k_combine<<<20000, 256, 0, stream>>>(z0, z1, rs + 40000, rs + 120000,
                                         misc + 2*L, hu, CNU);
  }
  // HAN item CSRs
  k_izero<<<(40000 + 255)/256, 256, 0, stream>>>(mp_cur, 40000);
  k_hist<<<2500, 256, 0, stream>>>(imp0d, mp_cur, CEMP);
  k_scan_part<<<20, 256, 0, stream>>>(mp_cur, scanb, 40000);
  k_scan_top<<<1, 64, 0, stream>>>(scanb, 20);
  k_scan_down<<<20, 256, 0, stream>>>(mp_cur, scanb, mp_p0, 40000, CEMP);
  k_fill<<<2500, 256, 0, stream>>>(imp0s, imp0d, mp_cur, mp_c0, CEMP);
  k_izero<<<(40000 + 255)/256, 256, 0, stream>>>(mp_cur, 40000);
  k_hist<<<2500, 256, 0, stream>>>(imp1d, mp_cur, CEMP);
  k_scan_part<<<20, 256, 0, stream>>>(mp_cur, scanb, 40000);
  k_scan_top<<<1, 64, 0, stream>>>(scanb, 20);
  k_scan_down<<<20, 256, 0, stream>>>(mp_cur, scanb, mp_p1, 40000, CEMP);
  k_fill<<<2500, 256, 0, stream>>>(imp1s, imp1d, mp_cur, mp_c1, CEMP);
  for (int L = 0; L < 3; ++L){
    const u16* hin = (L == 0) ? (fb + (long long)CNU*CD) : hi;
    k_gather_mp<<<10000, 256, 0, stream>>>(hin, mp_p0, mp_c0, rs + 160000, z0, CNU);
    k_gather_mp<<<10000, 256, 0, stream>>>(hin, mp_p1, mp_c1, rs + 240000, z1, CNU);
    k_att<<<1250, 256, 0, stream>>>(z0, z1, rs + 200000, rs + 280000,
                                    w1ti, i_b1, i_W2, misc + 6 + 2*L, CNU);
    k_combine<<<20000, 256, 0, stream>>>(z0, z1, rs + 200000, rs + 280000,
                                         misc + 6 + 2*L, hi, CNU);
  }

  k_emb<<<40000, 256, 0, stream>>>(x2, hu, hi);

  // SSL
  k_sslnorm<<<CB/4, 256, 0, stream>>>(x2, hu, user_idx, 0,   n1ub, n2ub, misc + 12);
  k_sslnorm<<<CB/4, 256, 0, stream>>>(x2, hi, item_idx, CNU, n1ib, n2ib, misc + 14);
  k_alls<<<dim3(128, 8), 256, 0, stream>>>(n1ub, n2ub, alls);
  k_alls<<<dim3(128, 8), 256, 0, stream>>>(n1ib, n2ib, alls + CB);
  k_logsum<<<64, 256, 0, stream>>>(alls, misc);

  k_final<<<1024, 128, 0, stream>>>(hu, user_idx, user_W, user_b, ln_g, ln_b, out);
  k_final<<<1024, 128, 0, stream>>>(hi, item_idx, item_W, item_b, ln_g, ln_b, out + (long long)CB*CD);
  k_final<<<1024, 128, 0, stream>>>(hi, neg_idx,  item_W, item_b, ln_g, ln_b, out + 2LL*CB*CD);
  k_loss<<<1, 1, 0, stream>>>(misc, out + 3LL*CB*CD);
}